// Round 2
// baseline (1061.785 us; speedup 1.0000x reference)
//
#include <hip/hip_runtime.h>
#include <hip/hip_bf16.h>
#include <cstdint>
#include <cstddef>

static inline size_t align_up(size_t x, size_t a) { return (x + a - 1) & ~(a - 1); }

typedef __attribute__((ext_vector_type(4))) float f32x4;
typedef __attribute__((ext_vector_type(2))) float f32x2;
typedef __attribute__((ext_vector_type(8))) short bf16x8;

__device__ inline float bf2f(unsigned int u16) {        // low 16 bits hold bf16
    return __uint_as_float(u16 << 16);
}
__device__ inline unsigned short f2bf(float f) {        // round-to-nearest-even
    unsigned int u = __float_as_uint(f);
    u = (u + 0x7fffu + ((u >> 16) & 1u)) >> 16;
    return (unsigned short)u;
}

#define GLD_LDS(gp, lp) \
    __builtin_amdgcn_global_load_lds( \
        (const __attribute__((address_space(1))) unsigned int*)(gp), \
        (__attribute__((address_space(3))) unsigned int*)(lp), 16, 0, 0)

// ---------------------------------------------------------------------------
__global__ void zero_kernel(int* __restrict__ p, int n) {
    int i = blockIdx.x * 256 + threadIdx.x;
    if (i < n) p[i] = 0;
}

// Edge-encoding detection, single block, sampled, no atomics.
__global__ void detect_kernel(const int* __restrict__ e, int* __restrict__ nz, int E) {
    int t = threadIdx.x;  // 0..255, one block
    long long stride = (long long)E / 4096;
    if (stride < 1) stride = 1;
    int any = 0;
    for (int k = 0; k < 16; ++k) {
        long long idx = (long long)(t * 16 + k) * stride;
        if (idx < E && e[2 * idx + 1] != 0) any = 1;
    }
    if (any) nz[0] = 1;  // same-value race is benign
}

__global__ void conv_count_kernel(const int* __restrict__ eraw, const int* __restrict__ nz,
                                  int* __restrict__ src32, int* __restrict__ dst32,
                                  int* __restrict__ cnt, int E) {
    int i = blockIdx.x * blockDim.x + threadIdx.x;
    if (i >= E) return;
    int s, d;
    if (*nz == 0) {  // int64 storage
        const long long* e64 = (const long long*)eraw;
        s = (int)e64[i];
        d = (int)e64[i + E];
    } else {         // int32 storage
        s = eraw[i];
        d = eraw[i + E];
    }
    src32[i] = s;
    dst32[i] = d;
    atomicAdd(&cnt[d], 1);
}

// 3-kernel exclusive scan over cnt[0..n) -> offs[0..n]
__global__ void scan1_kernel(const int* __restrict__ cnt, int* __restrict__ partial,
                             int n, int C) {
    int t = blockIdx.x * 256 + threadIdx.x;  // 0..1023
    int s = 0;
    int base = t * C;
    for (int i = 0; i < C; ++i) {
        int idx = base + i;
        if (idx < n) s += cnt[idx];
    }
    partial[t] = s;
}

__global__ void __launch_bounds__(1024) scan2_kernel(int* __restrict__ partial) {
    __shared__ int sh[1024];
    int t = threadIdx.x;
    sh[t] = partial[t];
    __syncthreads();
    for (int off = 1; off < 1024; off <<= 1) {
        int v = (t >= off) ? sh[t - off] : 0;
        __syncthreads();
        sh[t] += v;
        __syncthreads();
    }
    partial[t] = (t == 0) ? 0 : sh[t - 1];  // exclusive
}

__global__ void scan3_kernel(const int* __restrict__ cnt, const int* __restrict__ partial,
                             int* __restrict__ offs, int n, int C, int E) {
    int t = blockIdx.x * 256 + threadIdx.x;
    int run = partial[t];
    int base = t * C;
    for (int i = 0; i < C; ++i) {
        int idx = base + i;
        if (idx < n) {
            offs[idx] = run;
            run += cnt[idx];
        }
    }
    if (t == 0) offs[n] = E;
}

__global__ void inv_kernel(const int* __restrict__ cnt, float* __restrict__ inv, int n) {
    int i = blockIdx.x * 256 + threadIdx.x;
    if (i < n) inv[i] = 1.0f / (float)max(cnt[i], 1);
}

__global__ void fill_kernel(const int* __restrict__ src32, const int* __restrict__ dst32,
                            const int* __restrict__ offs, int* __restrict__ cursor,
                            int* __restrict__ sorted, int E) {
    int i = blockIdx.x * 256 + threadIdx.x;
    if (i >= E) return;
    int d = dst32[i];
    int p = offs[d] + atomicAdd(&cursor[d], 1);
    sorted[p] = src32[i];
}

// fp32 -> bf16, vectorized x4
__global__ void cvt_bf16_kernel(const float* __restrict__ x, unsigned short* __restrict__ xb,
                                int n4) {
    int i = blockIdx.x * 256 + threadIdx.x;
    if (i >= n4) return;
    float4 v = *(const float4*)(x + (size_t)i * 4);
    uint2 o;
    o.x = (unsigned int)f2bf(v.x) | ((unsigned int)f2bf(v.y) << 16);
    o.y = (unsigned int)f2bf(v.z) | ((unsigned int)f2bf(v.w) << 16);
    *(uint2*)(xb + (size_t)i * 4) = o;
}

// fp32 x [N][128] -> bf16 slice-permuted xp [4][N][32]
__global__ void cvt_perm_kernel(const float* __restrict__ x, unsigned short* __restrict__ xp,
                                int nNodes) {
    int i = blockIdx.x * 256 + threadIdx.x;   // one per 2 dims
    if (i >= nNodes * 64) return;
    int n = i >> 6;
    int d = (i & 63) * 2;
    float2 v = *(const float2*)(x + (size_t)n * 128 + d);
    unsigned int o = (unsigned int)f2bf(v.x) | ((unsigned int)f2bf(v.y) << 16);
    *(unsigned int*)(xp + (size_t)(d >> 5) * nNodes * 32 + (size_t)n * 32 + (d & 31)) = o;
}

// ---------------------------------------------------------------------------
// Slice-permuted gather kernels (round-2 design).
//
// Round-1 post-mortem: 64 B slices of a row-major table split 128 B lines ->
// per-XCD line footprint 6.4 MB > 4 MB L2 -> FETCH rose to 476 MB. Fix: store
// the gather table SLICE-MAJOR: [S][node][32 dims]. Slice s is then a
// CONTIGUOUS 50000*64 B = 3.2 MB block < 4 MB L2 -> hard-resident on its XCD
// (blockIdx%8 -> XCD round-robin), independent of wave phase. Lines hold two
// NODES of the same slice, so 128 B granularity never leaves the working set.
// D=512 runs as two sequential launches of 8 slices so each XCD holds exactly
// one slice at a time. Gather: 16 lanes x uint (64 B/edge, full line use),
// 4 edges/wave, unroll 4 (16 loads in flight), shfl_xor reduce over edge
// subgroups. Streaming traffic (srt, Q) is non-temporal to protect the
// resident slice.
// ---------------------------------------------------------------------------

// Layer-0: aggx[node][s*32+dp] = inv * sum xp_s[src]
__global__ void __launch_bounds__(256) aggx_slice_kernel(
    const unsigned short* __restrict__ XP,  // [4][N][32]
    const int* __restrict__ srt, const int* __restrict__ offs,
    const float* __restrict__ invc, unsigned short* __restrict__ aggx,
    int nNodes) {
    const int b = blockIdx.x;
    const int slice = b & 3;        // XCD x consistently sees slice x&3
    const int nb = b >> 2;
    const int wave = threadIdx.x >> 6;
    const int node = nb * 4 + wave;
    if (node >= nNodes) return;
    const int lane = threadIdx.x & 63;
    const int g = lane >> 4;
    const int dp = (lane & 15) * 2;
    const unsigned short* pp = XP + (size_t)slice * nNodes * 32 + dp;
    int beg = offs[node], end = offs[node + 1];
    float sc = invc[node];
    float a0 = 0.f, a1 = 0.f;
    int e = beg + g;
    for (; e + 12 < end; e += 16) {
        int s0 = __builtin_nontemporal_load(srt + e);
        int s1 = __builtin_nontemporal_load(srt + e + 4);
        int s2 = __builtin_nontemporal_load(srt + e + 8);
        int s3 = __builtin_nontemporal_load(srt + e + 12);
        unsigned int v0 = *(const unsigned int*)(pp + (size_t)s0 * 32);
        unsigned int v1 = *(const unsigned int*)(pp + (size_t)s1 * 32);
        unsigned int v2 = *(const unsigned int*)(pp + (size_t)s2 * 32);
        unsigned int v3 = *(const unsigned int*)(pp + (size_t)s3 * 32);
        a0 += bf2f(v0 & 0xffffu); a1 += bf2f(v0 >> 16);
        a0 += bf2f(v1 & 0xffffu); a1 += bf2f(v1 >> 16);
        a0 += bf2f(v2 & 0xffffu); a1 += bf2f(v2 >> 16);
        a0 += bf2f(v3 & 0xffffu); a1 += bf2f(v3 >> 16);
    }
    for (; e < end; e += 4) {
        int s = __builtin_nontemporal_load(srt + e);
        unsigned int v = *(const unsigned int*)(pp + (size_t)s * 32);
        a0 += bf2f(v & 0xffffu); a1 += bf2f(v >> 16);
    }
    a0 += __shfl_xor(a0, 16, 64); a0 += __shfl_xor(a0, 32, 64);
    a1 += __shfl_xor(a1, 16, 64); a1 += __shfl_xor(a1, 32, 64);
    if (g == 0) {
        unsigned int o = (unsigned int)f2bf(a0 * sc) | ((unsigned int)f2bf(a1 * sc) << 16);
        *(unsigned int*)(aggx + (size_t)node * 128 + slice * 32 + dp) = o;  // row-major (GEMM A)
    }
}

// Layer-1: h1[node][s*32+dp] = relu(inv * sum P_s[src] + Q_s[node]); P,Q [16][Mpad][32]
__global__ void __launch_bounds__(256) aggslice512_v2(
    const unsigned short* __restrict__ P, const unsigned short* __restrict__ Q,
    const int* __restrict__ srt, const int* __restrict__ offs,
    const float* __restrict__ invc, unsigned short* __restrict__ out,
    int nNodes, int Mpad, int sliceBase) {
    const int b = blockIdx.x;
    const int slice = sliceBase + (b & 7);
    const int nb = b >> 3;
    const int wave = threadIdx.x >> 6;
    const int node = nb * 4 + wave;
    if (node >= nNodes) return;
    const int lane = threadIdx.x & 63;
    const int g = lane >> 4;
    const int dp = (lane & 15) * 2;
    const unsigned short* pp = P + (size_t)slice * Mpad * 32 + dp;
    int beg = offs[node], end = offs[node + 1];
    float sc = invc[node];
    float a0 = 0.f, a1 = 0.f;
    int e = beg + g;
    for (; e + 12 < end; e += 16) {
        int s0 = __builtin_nontemporal_load(srt + e);
        int s1 = __builtin_nontemporal_load(srt + e + 4);
        int s2 = __builtin_nontemporal_load(srt + e + 8);
        int s3 = __builtin_nontemporal_load(srt + e + 12);
        unsigned int v0 = *(const unsigned int*)(pp + (size_t)s0 * 32);
        unsigned int v1 = *(const unsigned int*)(pp + (size_t)s1 * 32);
        unsigned int v2 = *(const unsigned int*)(pp + (size_t)s2 * 32);
        unsigned int v3 = *(const unsigned int*)(pp + (size_t)s3 * 32);
        a0 += bf2f(v0 & 0xffffu); a1 += bf2f(v0 >> 16);
        a0 += bf2f(v1 & 0xffffu); a1 += bf2f(v1 >> 16);
        a0 += bf2f(v2 & 0xffffu); a1 += bf2f(v2 >> 16);
        a0 += bf2f(v3 & 0xffffu); a1 += bf2f(v3 >> 16);
    }
    for (; e < end; e += 4) {
        int s = __builtin_nontemporal_load(srt + e);
        unsigned int v = *(const unsigned int*)(pp + (size_t)s * 32);
        a0 += bf2f(v & 0xffffu); a1 += bf2f(v >> 16);
    }
    a0 += __shfl_xor(a0, 16, 64); a0 += __shfl_xor(a0, 32, 64);
    a1 += __shfl_xor(a1, 16, 64); a1 += __shfl_xor(a1, 32, 64);
    if (g == 0) {
        unsigned int q = __builtin_nontemporal_load(
            (const unsigned int*)(Q + (size_t)slice * Mpad * 32 + (size_t)node * 32 + dp));
        float r0 = fmaxf(a0 * sc + bf2f(q & 0xffffu), 0.f);
        float r1 = fmaxf(a1 * sc + bf2f(q >> 16), 0.f);
        unsigned int o = (unsigned int)f2bf(r0) | ((unsigned int)f2bf(r1) << 16);
        *(unsigned int*)(out + (size_t)node * 512 + slice * 32 + dp) = o;  // row-major (GEMM A)
    }
}

// Layer-2: out[node][s*32+dp] = inv * sum P_s[src] + Qf[node] (fp32, no relu)
// P [8][Mpad][32] bf16; Qf row-major fp32 (32-dim fp32 slice = exactly one line).
__global__ void __launch_bounds__(256) aggslice256_v2(
    const unsigned short* __restrict__ P, const float* __restrict__ Qf,
    const int* __restrict__ srt, const int* __restrict__ offs,
    const float* __restrict__ invc, float* __restrict__ out, int nNodes, int Mpad) {
    const int b = blockIdx.x;
    const int slice = b & 7;
    const int nb = b >> 3;
    const int wave = threadIdx.x >> 6;
    const int node = nb * 4 + wave;
    if (node >= nNodes) return;
    const int lane = threadIdx.x & 63;
    const int g = lane >> 4;
    const int dp = (lane & 15) * 2;
    const unsigned short* pp = P + (size_t)slice * Mpad * 32 + dp;
    int beg = offs[node], end = offs[node + 1];
    float sc = invc[node];
    float a0 = 0.f, a1 = 0.f;
    int e = beg + g;
    for (; e + 12 < end; e += 16) {
        int s0 = __builtin_nontemporal_load(srt + e);
        int s1 = __builtin_nontemporal_load(srt + e + 4);
        int s2 = __builtin_nontemporal_load(srt + e + 8);
        int s3 = __builtin_nontemporal_load(srt + e + 12);
        unsigned int v0 = *(const unsigned int*)(pp + (size_t)s0 * 32);
        unsigned int v1 = *(const unsigned int*)(pp + (size_t)s1 * 32);
        unsigned int v2 = *(const unsigned int*)(pp + (size_t)s2 * 32);
        unsigned int v3 = *(const unsigned int*)(pp + (size_t)s3 * 32);
        a0 += bf2f(v0 & 0xffffu); a1 += bf2f(v0 >> 16);
        a0 += bf2f(v1 & 0xffffu); a1 += bf2f(v1 >> 16);
        a0 += bf2f(v2 & 0xffffu); a1 += bf2f(v2 >> 16);
        a0 += bf2f(v3 & 0xffffu); a1 += bf2f(v3 >> 16);
    }
    for (; e < end; e += 4) {
        int s = __builtin_nontemporal_load(srt + e);
        unsigned int v = *(const unsigned int*)(pp + (size_t)s * 32);
        a0 += bf2f(v & 0xffffu); a1 += bf2f(v >> 16);
    }
    a0 += __shfl_xor(a0, 16, 64); a0 += __shfl_xor(a0, 32, 64);
    a1 += __shfl_xor(a1, 16, 64); a1 += __shfl_xor(a1, 32, 64);
    if (g == 0) {
        int cb = slice * 32 + dp;
        f32x2 q = __builtin_nontemporal_load((const f32x2*)(Qf + (size_t)node * 256 + cb));
        f32x2 r;
        r.x = a0 * sc + q.x;
        r.y = a1 * sc + q.y;
        __builtin_nontemporal_store(r, (f32x2*)(out + (size_t)node * 256 + cb));
    }
}

// ---------------------------------------------------------------------------
// Coalesced bf16 epilogue. permM == 0: row-major [m][N]. permM != 0: slice-
// permuted [n>>5][permM rows][32] (the uint4 chunk n..n+8 stays inside one
// 32-dim slice since n is 8-aligned).
// ---------------------------------------------------------------------------
__device__ __forceinline__ void epilogue_bf16(
    f32x4 (&acc)[4][8], const float* bvj, int relu, int permM,
    unsigned short* smem, int wave, int lane,
    unsigned short* Cout, int m0, int n0, int wm, int wn, int M, int N) {
    unsigned short* stg = smem + wave * 2304;  // 128 cols * 18 shorts
    const int colc = lane & 15;
    const int rgrp = (lane >> 4) * 4;
    for (int i = 0; i < 4; ++i) {
        __syncthreads();
#pragma unroll
        for (int j = 0; j < 8; ++j) {
            float v0 = acc[i][j][0] + bvj[j];
            float v1 = acc[i][j][1] + bvj[j];
            float v2 = acc[i][j][2] + bvj[j];
            float v3 = acc[i][j][3] + bvj[j];
            if (relu) {
                v0 = fmaxf(v0, 0.f); v1 = fmaxf(v1, 0.f);
                v2 = fmaxf(v2, 0.f); v3 = fmaxf(v3, 0.f);
            }
            int c = j * 16 + colc;
            *(unsigned int*)&stg[c * 18 + rgrp] =
                (unsigned int)f2bf(v0) | ((unsigned int)f2bf(v1) << 16);
            *(unsigned int*)&stg[c * 18 + rgrp + 2] =
                (unsigned int)f2bf(v2) | ((unsigned int)f2bf(v3) << 16);
        }
        __syncthreads();
#pragma unroll
        for (int p = 0; p < 2; ++p) {
            int colg = lane & 15;                  // 8-col group
            int rp = p * 4 + (lane >> 4);          // row pair 0..7
            unsigned int w[8];
#pragma unroll
            for (int t = 0; t < 8; ++t)
                w[t] = *(const unsigned int*)&stg[(colg * 8 + t) * 18 + rp * 2];
            uint4 lo, hi;
            lo.x = (w[0] & 0xffffu) | (w[1] << 16);
            lo.y = (w[2] & 0xffffu) | (w[3] << 16);
            lo.z = (w[4] & 0xffffu) | (w[5] << 16);
            lo.w = (w[6] & 0xffffu) | (w[7] << 16);
            hi.x = (w[0] >> 16) | (w[1] & 0xffff0000u);
            hi.y = (w[2] >> 16) | (w[3] & 0xffff0000u);
            hi.z = (w[4] >> 16) | (w[5] & 0xffff0000u);
            hi.w = (w[6] >> 16) | (w[7] & 0xffff0000u);
            int mlo = m0 + wm * 64 + i * 16 + rp * 2;
            int n = n0 + wn * 128 + colg * 8;
            if (permM) {
                size_t base = (size_t)(n >> 5) * ((size_t)permM * 32) +
                              (size_t)mlo * 32 + (n & 31);
                if (mlo < M)     *(uint4*)&Cout[base] = lo;
                if (mlo + 1 < M) *(uint4*)&Cout[base + 32] = hi;
            } else {
                if (mlo < M)     *(uint4*)&Cout[(size_t)mlo * N + n] = lo;
                if (mlo + 1 < M) *(uint4*)&Cout[(size_t)(mlo + 1) * N + n] = hi;
            }
        }
    }
}

// ---------------------------------------------------------------------------
// MFMA SAGE GEMM (layer 0): C = relu( Aagg @ Wl^T + Aself @ Wr^T + bias )
// Tile 128x256, BK=32, 4 waves of 4x8 frags. Coalesced bf16 epilogue.
// ---------------------------------------------------------------------------
__global__ void __launch_bounds__(256, 2) sage_gemm_mfma(
    const unsigned short* __restrict__ Aagg, const unsigned short* __restrict__ Aself,
    const unsigned short* __restrict__ Wlb, const unsigned short* __restrict__ Wrb,
    const float* __restrict__ bias, unsigned short* __restrict__ Cout,
    int M, int N, int K) {
    __shared__ __attribute__((aligned(16))) unsigned short smem[12288];  // 24 KB
    unsigned short* As = smem;            // 128*32
    unsigned short* Bs = smem + 4096;     // 256*32
    const int tid = threadIdx.x;
    const int lane = tid & 63;
    const int wave = tid >> 6;
    const int wm = wave >> 1, wn = wave & 1;
    const int m0 = blockIdx.y * 128, n0 = blockIdx.x * 256;

    f32x4 acc[4][8];
#pragma unroll
    for (int i = 0; i < 4; ++i)
#pragma unroll
        for (int j = 0; j < 8; ++j) acc[i][j] = (f32x4){0.f, 0.f, 0.f, 0.f};

    const int srow = wave * 16 + (lane >> 2);
    const int kE = (lane & 3) * 8;
    const int frow = lane & 15;
    const int kk = (lane >> 4) * 8;

    for (int pass = 0; pass < 2; ++pass) {
        const unsigned short* A = pass ? Aself : Aagg;
        const unsigned short* W = pass ? Wrb : Wlb;
        for (int k0 = 0; k0 < K; k0 += 32) {
            __syncthreads();
            GLD_LDS(A + (size_t)(m0 + 0 * 64 + srow) * K + k0 + kE, &As[0 * 2048 + wave * 512]);
            GLD_LDS(A + (size_t)(m0 + 1 * 64 + srow) * K + k0 + kE, &As[1 * 2048 + wave * 512]);
            GLD_LDS(W + (size_t)(n0 + 0 * 64 + srow) * K + k0 + kE, &Bs[0 * 2048 + wave * 512]);
            GLD_LDS(W + (size_t)(n0 + 1 * 64 + srow) * K + k0 + kE, &Bs[1 * 2048 + wave * 512]);
            GLD_LDS(W + (size_t)(n0 + 2 * 64 + srow) * K + k0 + kE, &Bs[2 * 2048 + wave * 512]);
            GLD_LDS(W + (size_t)(n0 + 3 * 64 + srow) * K + k0 + kE, &Bs[3 * 2048 + wave * 512]);
            __syncthreads();
            bf16x8 af[4], bfr[8];
#pragma unroll
            for (int t = 0; t < 4; ++t)
                af[t] = *(const bf16x8*)&As[(wm * 64 + t * 16 + frow) * 32 + kk];
#pragma unroll
            for (int t = 0; t < 8; ++t)
                bfr[t] = *(const bf16x8*)&Bs[(wn * 128 + t * 16 + frow) * 32 + kk];
#pragma unroll
            for (int i = 0; i < 4; ++i)
#pragma unroll
                for (int j = 0; j < 8; ++j)
                    acc[i][j] = __builtin_amdgcn_mfma_f32_16x16x32_bf16(
                        af[i], bfr[j], acc[i][j], 0, 0, 0);
        }
    }

    float bvj[8];
#pragma unroll
    for (int j = 0; j < 8; ++j) bvj[j] = bias[n0 + wn * 128 + j * 16 + (lane & 15)];
    epilogue_bf16(acc, bvj, 1, 0, smem, wave, lane, Cout, m0, n0, wm, wn, M, N);
}

// ---------------------------------------------------------------------------
// Dual-output MFMA GEMM (layers 1-2): P = A@Wl^T ; Q = A@Wr^T + bias.
// grid.x covers 2N in 256-col blocks (first half P, second half Q).
// P (and optionally bf16 Q) written slice-permuted for the gather kernels.
// ---------------------------------------------------------------------------
__global__ void __launch_bounds__(256, 2) dual_gemm_mfma(
    const unsigned short* __restrict__ A,
    const unsigned short* __restrict__ Wlb, const unsigned short* __restrict__ Wrb,
    const float* __restrict__ bias, unsigned short* __restrict__ P,
    void* __restrict__ Q, int M, int N, int K, int q_fp32, int permM) {
    __shared__ __attribute__((aligned(16))) unsigned short smem[12288];  // 24 KB
    unsigned short* As = smem;
    unsigned short* Bs = smem + 4096;
    const int tid = threadIdx.x;
    const int lane = tid & 63;
    const int wave = tid >> 6;
    const int wm = wave >> 1, wn = wave & 1;
    const int m0 = blockIdx.y * 128;
    const int n0s = blockIdx.x * 256;          // in [0, 2N)
    const int isQ = n0s >= N;
    const int n0 = isQ ? n0s - N : n0s;
    const unsigned short* W = isQ ? Wrb : Wlb;

    f32x4 acc[4][8];
#pragma unroll
    for (int i = 0; i < 4; ++i)
#pragma unroll
        for (int j = 0; j < 8; ++j) acc[i][j] = (f32x4){0.f, 0.f, 0.f, 0.f};

    const int srow = wave * 16 + (lane >> 2);
    const int kE = (lane & 3) * 8;
    const int frow = lane & 15;
    const int kk = (lane >> 4) * 8;

    for (int k0 = 0; k0 < K; k0 += 32) {
        __syncthreads();
        GLD_LDS(A + (size_t)(m0 + 0 * 64 + srow) * K + k0 + kE, &As[0 * 2048 + wave * 512]);
        GLD_LDS(A + (size_t)(m0 + 1 * 64 + srow) * K + k0 + kE, &As[1 * 2048 + wave * 512]);
        GLD_LDS(W + (size_t)(n0 + 0 * 64 + srow) * K + k0 + kE, &Bs[0 * 2048 + wave * 512]);
        GLD_LDS(W + (size_t)(n0 + 1 * 64 + srow) * K + k0 + kE, &Bs[1 * 2048 + wave * 512]);
        GLD_LDS(W + (size_t)(n0 + 2 * 64 + srow) * K + k0 + kE, &Bs[2 * 2048 + wave * 512]);
        GLD_LDS(W + (size_t)(n0 + 3 * 64 + srow) * K + k0 + kE, &Bs[3 * 2048 + wave * 512]);
        __syncthreads();
        bf16x8 af[4], bfr[8];
#pragma unroll
        for (int t = 0; t < 4; ++t)
            af[t] = *(const bf16x8*)&As[(wm * 64 + t * 16 + frow) * 32 + kk];
#pragma unroll
        for (int t = 0; t < 8; ++t)
            bfr[t] = *(const bf16x8*)&Bs[(wn * 128 + t * 16 + frow) * 32 + kk];
#pragma unroll
        for (int i = 0; i < 4; ++i)
#pragma unroll
            for (int j = 0; j < 8; ++j)
                acc[i][j] = __builtin_amdgcn_mfma_f32_16x16x32_bf16(
                    af[i], bfr[j], acc[i][j], 0, 0, 0);
    }

    if (!isQ || !q_fp32) {
        float bvj[8];
#pragma unroll
        for (int j = 0; j < 8; ++j)
            bvj[j] = isQ ? bias[n0 + wn * 128 + j * 16 + (lane & 15)] : 0.f;
        unsigned short* Cout = isQ ? (unsigned short*)Q : P;
        epilogue_bf16(acc, bvj, 0, permM, smem, wave, lane, Cout, m0, n0, wm, wn, M, N);
    } else {
        // fp32 Q: scalar stores are 64 B per quarter-wave -> already coalesced
        const int col = lane & 15;
        const int rgrp = (lane >> 4) * 4;
        float* Qf = (float*)Q;
#pragma unroll
        for (int j = 0; j < 8; ++j) {
            int n = n0 + wn * 128 + j * 16 + col;
            float bv = bias[n];
#pragma unroll
            for (int i = 0; i < 4; ++i) {
                int mBase = m0 + wm * 64 + i * 16 + rgrp;
#pragma unroll
                for (int r = 0; r < 4; ++r) {
                    int m = mBase + r;
                    if (m >= M) continue;
                    Qf[(size_t)m * N + n] = acc[i][j][r] + bv;
                }
            }
        }
    }
}

// ---------------------------------------------------------------------------
extern "C" void kernel_launch(void* const* d_in, const int* in_sizes, int n_in,
                              void* d_out, int out_size, void* d_ws, size_t ws_size,
                              hipStream_t stream) {
    const float* x   = (const float*)d_in[0];
    const int*   e   = (const int*)d_in[1];
    const float* Wl0 = (const float*)d_in[2];
    const float* bl0 = (const float*)d_in[3];
    const float* Wr0 = (const float*)d_in[4];
    const float* Wl1 = (const float*)d_in[5];
    const float* bl1 = (const float*)d_in[6];
    const float* Wr1 = (const float*)d_in[7];
    const float* Wl2 = (const float*)d_in[8];
    const float* bl2 = (const float*)d_in[9];
    const float* Wr2 = (const float*)d_in[10];
    float* out = (float*)d_out;

    const int N = in_sizes[0] / 128;           // 50000 nodes
    const int E = in_sizes[1] / 2;             // 800000 edges
    const int Mpad = ((N + 127) / 128) * 128;  // 50048: GEMM staging never OOB

    char* ws = (char*)d_ws;
    size_t off = 0;
    auto alloc = [&](size_t bytes) { size_t o = off; off = align_up(off + bytes, 512); return o; };

    size_t o_nz     = alloc(4);
    size_t o_cnt    = alloc((size_t)N * 4);
    size_t o_cursor = alloc((size_t)N * 4);
    size_t zero_end = off;                       // [0, zero_end) zeroed each call
    size_t o_part   = alloc(1024 * 4);
    size_t o_offs   = alloc((size_t)(N + 1) * 4);
    size_t o_inv    = alloc((size_t)N * 4);
    size_t o_src    = alloc((size_t)E * 4);
    size_t o_dst    = alloc((size_t)E * 4);
    size_t o_sort   = alloc((size_t)E * 4);
    size_t o_xb     = alloc((size_t)Mpad * 128 * 2);   // bf16 x row-major
    size_t o_xp     = alloc((size_t)N * 128 * 2);      // bf16 x slice-permuted [4][N][32]
    size_t o_aggx   = alloc((size_t)Mpad * 128 * 2);   // bf16 agg(x) row-major
    size_t o_h      = alloc((size_t)Mpad * 512 * 2);   // h0, then h1 (row-major)
    size_t o_P      = alloc((size_t)Mpad * 512 * 2);   // P1 [16][Mpad][32], then P2 [8][Mpad][32]
    size_t o_Q      = alloc((size_t)Mpad * 512 * 2);   // Q1 [16][Mpad][32] bf16, then Q2 fp32 row-major
    size_t o_wl0    = alloc((size_t)512 * 128 * 2);
    size_t o_wr0    = alloc((size_t)512 * 128 * 2);
    size_t o_wl1    = alloc((size_t)512 * 512 * 2);
    size_t o_wr1    = alloc((size_t)512 * 512 * 2);
    size_t o_wl2    = alloc((size_t)256 * 512 * 2);
    size_t o_wr2    = alloc((size_t)256 * 512 * 2);
    (void)ws_size; (void)n_in; (void)out_size;

    int*            nz     = (int*)(ws + o_nz);
    int*            cnt    = (int*)(ws + o_cnt);
    int*            cursor = (int*)(ws + o_cursor);
    int*            part   = (int*)(ws + o_part);
    int*            offs   = (int*)(ws + o_offs);
    float*          inv    = (float*)(ws + o_inv);
    int*            src32  = (int*)(ws + o_src);
    int*            dst32  = (int*)(ws + o_dst);
    int*            sorted = (int*)(ws + o_sort);
    unsigned short* xb     = (unsigned short*)(ws + o_xb);
    unsigned short* xp     = (unsigned short*)(ws + o_xp);
    unsigned short* aggx   = (unsigned short*)(ws + o_aggx);
    unsigned short* hbuf   = (unsigned short*)(ws + o_h);
    unsigned short* Pbuf   = (unsigned short*)(ws + o_P);
    unsigned short* Qbuf   = (unsigned short*)(ws + o_Q);   // bf16 view (layer 1, permuted)
    float*          Qf     = (float*)(ws + o_Q);            // fp32 view (layer 2, row-major)
    unsigned short* wl0b   = (unsigned short*)(ws + o_wl0);
    unsigned short* wr0b   = (unsigned short*)(ws + o_wr0);
    unsigned short* wl1b   = (unsigned short*)(ws + o_wl1);
    unsigned short* wr1b   = (unsigned short*)(ws + o_wr1);
    unsigned short* wl2b   = (unsigned short*)(ws + o_wl2);
    unsigned short* wr2b   = (unsigned short*)(ws + o_wr2);

    // zero nz/cnt/cursor (ws poisoned 0xAA before every call)
    int zn = (int)(zero_end / 4);
    zero_kernel<<<(zn + 255) / 256, 256, 0, stream>>>((int*)ws, zn);

    int eb = (E + 255) / 256;
    detect_kernel<<<1, 256, 0, stream>>>(e, nz, E);
    conv_count_kernel<<<eb, 256, 0, stream>>>(e, nz, src32, dst32, cnt, E);

    const int C = (N + 1023) / 1024;
    scan1_kernel<<<4, 256, 0, stream>>>(cnt, part, N, C);
    scan2_kernel<<<1, 1024, 0, stream>>>(part);
    scan3_kernel<<<4, 256, 0, stream>>>(cnt, part, offs, N, C, E);
    inv_kernel<<<(N + 255) / 256, 256, 0, stream>>>(cnt, inv, N);
    fill_kernel<<<eb, 256, 0, stream>>>(src32, dst32, offs, cursor, sorted, E);

    // conversions to bf16
    int n4 = N * 128 / 4;
    cvt_bf16_kernel<<<(n4 + 255) / 256, 256, 0, stream>>>(x, xb, n4);
    cvt_perm_kernel<<<(N * 64 + 255) / 256, 256, 0, stream>>>(x, xp, N);
    cvt_bf16_kernel<<<(512 * 128 / 4 + 255) / 256, 256, 0, stream>>>(Wl0, wl0b, 512 * 128 / 4);
    cvt_bf16_kernel<<<(512 * 128 / 4 + 255) / 256, 256, 0, stream>>>(Wr0, wr0b, 512 * 128 / 4);
    cvt_bf16_kernel<<<(512 * 512 / 4 + 255) / 256, 256, 0, stream>>>(Wl1, wl1b, 512 * 512 / 4);
    cvt_bf16_kernel<<<(512 * 512 / 4 + 255) / 256, 256, 0, stream>>>(Wr1, wr1b, 512 * 512 / 4);
    cvt_bf16_kernel<<<(256 * 512 / 4 + 255) / 256, 256, 0, stream>>>(Wl2, wl2b, 256 * 512 / 4);
    cvt_bf16_kernel<<<(256 * 512 / 4 + 255) / 256, 256, 0, stream>>>(Wr2, wr2b, 256 * 512 / 4);

    const int mBlocks = Mpad / 128;
    const int nbBlocks = (N + 3) / 4;          // 4 nodes per block (one per wave)

    // Layer 0: slice-gather agg(x) (4 slices, XCD-pinned), then SAGE GEMM.
    aggx_slice_kernel<<<nbBlocks * 4, 256, 0, stream>>>(xp, sorted, offs, inv, aggx, N);
    sage_gemm_mfma<<<dim3(2, mBlocks), 256, 0, stream>>>(
        aggx, xb, wl0b, wr0b, bl0, hbuf, N, 512, 128);

    // Layer 1: GEMM-then-agg: P1/Q1 slice-permuted [16][Mpad][32];
    // h1 = relu(inv*sum P1[src] + Q1)  (two launches: slices 0-7, then 8-15)
    dual_gemm_mfma<<<dim3(4, mBlocks), 256, 0, stream>>>(
        hbuf, wl1b, wr1b, bl1, Pbuf, Qbuf, N, 512, 512, 0, Mpad);
    aggslice512_v2<<<nbBlocks * 8, 256, 0, stream>>>(
        Pbuf, Qbuf, sorted, offs, inv, hbuf, N, Mpad, 0);
    aggslice512_v2<<<nbBlocks * 8, 256, 0, stream>>>(
        Pbuf, Qbuf, sorted, offs, inv, hbuf, N, Mpad, 8);

    // Layer 2: GEMM-then-agg at 256-dim; P2 slice-permuted [8][Mpad][32],
    // Q2 fp32 row-major; out = inv*sum P2[src] + Q2 (fp32, no relu)
    dual_gemm_mfma<<<dim3(2, mBlocks), 256, 0, stream>>>(
        hbuf, wl2b, wr2b, bl2, Pbuf, (void*)Qf, N, 256, 512, 1, Mpad);
    aggslice256_v2<<<nbBlocks * 8, 256, 0, stream>>>(
        Pbuf, Qf, sorted, offs, inv, out, N, Mpad);
}

// Round 3
// 1018.407 us; speedup vs baseline: 1.0426x; 1.0426x over previous
//
#include <hip/hip_runtime.h>
#include <hip/hip_bf16.h>
#include <cstdint>
#include <cstddef>

static inline size_t align_up(size_t x, size_t a) { return (x + a - 1) & ~(a - 1); }

typedef __attribute__((ext_vector_type(4))) float f32x4;
typedef __attribute__((ext_vector_type(8))) short bf16x8;

__device__ inline float bf2f(unsigned int u16) {        // low 16 bits hold bf16
    return __uint_as_float(u16 << 16);
}
__device__ inline unsigned short f2bf(float f) {        // round-to-nearest-even
    unsigned int u = __float_as_uint(f);
    u = (u + 0x7fffu + ((u >> 16) & 1u)) >> 16;
    return (unsigned short)u;
}
__device__ inline unsigned int pack2(float lo, float hi) {
    return (unsigned int)f2bf(lo) | ((unsigned int)f2bf(hi) << 16);
}

#define GLD_LDS(gp, lp) \
    __builtin_amdgcn_global_load_lds( \
        (const __attribute__((address_space(1))) unsigned int*)(gp), \
        (__attribute__((address_space(3))) unsigned int*)(lp), 16, 0, 0)

// ---------------------------------------------------------------------------
__global__ void zero_kernel(int* __restrict__ p, int n) {
    int i = blockIdx.x * 256 + threadIdx.x;
    if (i < n) p[i] = 0;
}

// Edge-encoding detection, single block, sampled, no atomics.
__global__ void detect_kernel(const int* __restrict__ e, int* __restrict__ nz, int E) {
    int t = threadIdx.x;  // 0..255, one block
    long long stride = (long long)E / 4096;
    if (stride < 1) stride = 1;
    int any = 0;
    for (int k = 0; k < 16; ++k) {
        long long idx = (long long)(t * 16 + k) * stride;
        if (idx < E && e[2 * idx + 1] != 0) any = 1;
    }
    if (any) nz[0] = 1;  // same-value race is benign
}

__global__ void conv_count_kernel(const int* __restrict__ eraw, const int* __restrict__ nz,
                                  int* __restrict__ src32, int* __restrict__ dst32,
                                  int* __restrict__ cnt, int E) {
    int i = blockIdx.x * blockDim.x + threadIdx.x;
    if (i >= E) return;
    int s, d;
    if (*nz == 0) {  // int64 storage
        const long long* e64 = (const long long*)eraw;
        s = (int)e64[i];
        d = (int)e64[i + E];
    } else {         // int32 storage
        s = eraw[i];
        d = eraw[i + E];
    }
    src32[i] = s;
    dst32[i] = d;
    atomicAdd(&cnt[d], 1);
}

// 3-kernel exclusive scan over cnt[0..n) -> offs[0..n]
__global__ void scan1_kernel(const int* __restrict__ cnt, int* __restrict__ partial,
                             int n, int C) {
    int t = blockIdx.x * 256 + threadIdx.x;  // 0..1023
    int s = 0;
    int base = t * C;
    for (int i = 0; i < C; ++i) {
        int idx = base + i;
        if (idx < n) s += cnt[idx];
    }
    partial[t] = s;
}

__global__ void __launch_bounds__(1024) scan2_kernel(int* __restrict__ partial) {
    __shared__ int sh[1024];
    int t = threadIdx.x;
    sh[t] = partial[t];
    __syncthreads();
    for (int off = 1; off < 1024; off <<= 1) {
        int v = (t >= off) ? sh[t - off] : 0;
        __syncthreads();
        sh[t] += v;
        __syncthreads();
    }
    partial[t] = (t == 0) ? 0 : sh[t - 1];  // exclusive
}

__global__ void scan3_kernel(const int* __restrict__ cnt, const int* __restrict__ partial,
                             int* __restrict__ offs, int n, int C, int E) {
    int t = blockIdx.x * 256 + threadIdx.x;
    int run = partial[t];
    int base = t * C;
    for (int i = 0; i < C; ++i) {
        int idx = base + i;
        if (idx < n) {
            offs[idx] = run;
            run += cnt[idx];
        }
    }
    if (t == 0) offs[n] = E;
}

__global__ void inv_kernel(const int* __restrict__ cnt, float* __restrict__ inv, int n) {
    int i = blockIdx.x * 256 + threadIdx.x;
    if (i < n) inv[i] = 1.0f / (float)max(cnt[i], 1);
}

__global__ void fill_kernel(const int* __restrict__ src32, const int* __restrict__ dst32,
                            const int* __restrict__ offs, int* __restrict__ cursor,
                            int* __restrict__ sorted, int E) {
    int i = blockIdx.x * 256 + threadIdx.x;
    if (i >= E) return;
    int d = dst32[i];
    int p = offs[d] + atomicAdd(&cursor[d], 1);
    sorted[p] = src32[i];
}

// ---------------------------------------------------------------------------
// Degree-sorted node permutation (counting sort, 256 bins). Round-3: waves
// co-schedule 16 nodes; sorting by degree makes the 16 degrees near-equal so
// the ballot loop wastes <10% masked iterations (vs ~60% unsorted).
// ---------------------------------------------------------------------------
__global__ void hist_kernel(const int* __restrict__ cnt, int* __restrict__ hist, int n) {
    int i = blockIdx.x * 256 + threadIdx.x;
    if (i < n) atomicAdd(&hist[min(cnt[i], 255)], 1);
}

__global__ void __launch_bounds__(256) scanhist_kernel(const int* __restrict__ hist,
                                                       int* __restrict__ hoffs) {
    __shared__ int sh[256];
    int t = threadIdx.x;
    sh[t] = hist[t];
    __syncthreads();
    for (int off = 1; off < 256; off <<= 1) {
        int v = (t >= off) ? sh[t - off] : 0;
        __syncthreads();
        sh[t] += v;
        __syncthreads();
    }
    hoffs[t] = (t == 0) ? 0 : sh[t - 1];  // exclusive
}

__global__ void place_kernel(const int* __restrict__ cnt, const int* __restrict__ hoffs,
                             int* __restrict__ hcur, int* __restrict__ perm, int n) {
    int i = blockIdx.x * 256 + threadIdx.x;
    if (i >= n) return;
    int d = min(cnt[i], 255);
    int r = atomicAdd(&hcur[d], 1);
    perm[hoffs[d] + r] = i;
}

// fp32 -> bf16, vectorized x4
__global__ void cvt_bf16_kernel(const float* __restrict__ x, unsigned short* __restrict__ xb,
                                int n4) {
    int i = blockIdx.x * 256 + threadIdx.x;
    if (i >= n4) return;
    float4 v = *(const float4*)(x + (size_t)i * 4);
    uint2 o;
    o.x = pack2(v.x, v.y);
    o.y = pack2(v.z, v.w);
    *(uint2*)(xb + (size_t)i * 4) = o;
}

// fp32 x [N][128] -> bf16 slice-permuted xp [4][N][32]
__global__ void cvt_perm_kernel(const float* __restrict__ x, unsigned short* __restrict__ xp,
                                int nNodes) {
    int i = blockIdx.x * 256 + threadIdx.x;   // one per 2 dims
    if (i >= nNodes * 64) return;
    int n = i >> 6;
    int d = (i & 63) * 2;
    float2 v = *(const float2*)(x + (size_t)n * 128 + d);
    *(unsigned int*)(xp + (size_t)(d >> 5) * nNodes * 32 + (size_t)n * 32 + (d & 31)) =
        pack2(v.x, v.y);
}

// ---------------------------------------------------------------------------
// Sliced gather v3 (round-3 design).
//
// Round-2 counters PROVED the slice-major layout + blockIdx%8 XCD pinning
// keeps a 3.2 MB slice L2-resident (gather contributed ~0 HBM fetch). What
// killed v2 was (a) nontemporal srt/Q = uncached latency on the critical
// chain, (b) 4 B/lane gathers = 16x per-edge bookkeeping. v3 keeps the
// layout, rebuilds compute:
//  - wave = 16 nodes x 4 lanes; lane loads uint4 (16 B) -> one gather instr
//    moves 16 x 64 B = 1 KB of L2-resident data (round-0 instruction economy).
//  - each 4-lane group OWNS its node: accumulators are final dims, no
//    cross-lane reduce; exec-masked predication for ragged degrees.
//  - nodes walked in degree-sorted perm order; unroll-2 keeps two srt->gather
//    chains in flight; all loads normally cached.
// MODE 0: out bf16 row-major, scale only            (layer-0 x aggregation)
// MODE 1: out bf16 row-major, relu(a*sc + Qperm)    (layer-1)
// MODE 2: out fp32 row-major, a*sc + Qf32           (layer-2, final)
// ---------------------------------------------------------------------------
template <int MODE>
__global__ void __launch_bounds__(256) aggslice_v3(
    const unsigned short* __restrict__ P, const unsigned short* __restrict__ Qb,
    const float* __restrict__ Qf,
    const int* __restrict__ srt, const int* __restrict__ offs,
    const float* __restrict__ invc, const int* __restrict__ perm,
    unsigned short* __restrict__ outb, float* __restrict__ outf,
    int nNodes, int tabM, int sliceBase, int S, int D) {
    const int b = blockIdx.x;
    const int x = b & 7;                       // XCD id (round-robin dispatch)
    const int R = 8 / S;                       // XCD replicas per slice
    const int slice = sliceBase + (x % S);
    const int tile = (b >> 3) * R + (x / S);
    const int lane = threadIdx.x & 63;
    const int wave = threadIdx.x >> 6;
    const int g = lane >> 2;                   // node group 0..15
    const int j = lane & 3;                    // 16-byte chunk within 64 B slice
    const int rank = tile * 64 + wave * 16 + g;
    int node = 0, beg = 0, end = 0;
    float sc = 0.f;
    if (rank < nNodes) {
        node = perm[rank];
        beg = offs[node];
        end = offs[node + 1];
        sc = invc[node];
    }
    const unsigned short* ps = P + (size_t)slice * tabM * 32 + j * 8;
    float a0 = 0.f, a1 = 0.f, a2 = 0.f, a3 = 0.f;
    float a4 = 0.f, a5 = 0.f, a6 = 0.f, a7 = 0.f;
#define ACC8(v)                                   \
    do {                                          \
        a0 += bf2f((v).x & 0xffffu);              \
        a1 += bf2f((v).x >> 16);                  \
        a2 += bf2f((v).y & 0xffffu);              \
        a3 += bf2f((v).y >> 16);                  \
        a4 += bf2f((v).z & 0xffffu);              \
        a5 += bf2f((v).z >> 16);                  \
        a6 += bf2f((v).w & 0xffffu);              \
        a7 += bf2f((v).w >> 16);                  \
    } while (0)
    int cur = beg;
    while (__ballot(cur < end)) {
        bool actA = cur < end;
        bool actB = cur + 1 < end;
        int ea = actA ? cur : 0;
        int eb = actB ? cur + 1 : 0;
        int sa = srt[ea];
        int sb = srt[eb];
        uint4 va = *(const uint4*)(ps + (unsigned)sa * 32u);
        uint4 vb = *(const uint4*)(ps + (unsigned)sb * 32u);
        if (actA) ACC8(va);
        if (actB) ACC8(vb);
        cur += 2;
    }
#undef ACC8
    if (rank >= nNodes) return;
    a0 *= sc; a1 *= sc; a2 *= sc; a3 *= sc;
    a4 *= sc; a5 *= sc; a6 *= sc; a7 *= sc;
    if (MODE == 0) {
        uint4 o;
        o.x = pack2(a0, a1); o.y = pack2(a2, a3);
        o.z = pack2(a4, a5); o.w = pack2(a6, a7);
        *(uint4*)(outb + (size_t)node * D + slice * 32 + j * 8) = o;
    } else if (MODE == 1) {
        uint4 q = *(const uint4*)(Qb + (size_t)slice * tabM * 32 + (size_t)node * 32 + j * 8);
        float r0 = fmaxf(a0 + bf2f(q.x & 0xffffu), 0.f);
        float r1 = fmaxf(a1 + bf2f(q.x >> 16), 0.f);
        float r2 = fmaxf(a2 + bf2f(q.y & 0xffffu), 0.f);
        float r3 = fmaxf(a3 + bf2f(q.y >> 16), 0.f);
        float r4 = fmaxf(a4 + bf2f(q.z & 0xffffu), 0.f);
        float r5 = fmaxf(a5 + bf2f(q.z >> 16), 0.f);
        float r6 = fmaxf(a6 + bf2f(q.w & 0xffffu), 0.f);
        float r7 = fmaxf(a7 + bf2f(q.w >> 16), 0.f);
        uint4 o;
        o.x = pack2(r0, r1); o.y = pack2(r2, r3);
        o.z = pack2(r4, r5); o.w = pack2(r6, r7);
        *(uint4*)(outb + (size_t)node * D + slice * 32 + j * 8) = o;
    } else {
        size_t qo = (size_t)node * D + slice * 32 + j * 8;
        float4 qa = *(const float4*)(Qf + qo);
        float4 qb4 = *(const float4*)(Qf + qo + 4);
        float4 ra = make_float4(a0 + qa.x, a1 + qa.y, a2 + qa.z, a3 + qa.w);
        float4 rb = make_float4(a4 + qb4.x, a5 + qb4.y, a6 + qb4.z, a7 + qb4.w);
        *(float4*)(outf + qo) = ra;
        *(float4*)(outf + qo + 4) = rb;
    }
}

// ---------------------------------------------------------------------------
// Coalesced bf16 epilogue. permM == 0: row-major [m][N]. permM != 0: slice-
// permuted [n>>5][permM rows][32] (the uint4 chunk n..n+8 stays inside one
// 32-dim slice since n is 8-aligned).
// ---------------------------------------------------------------------------
__device__ __forceinline__ void epilogue_bf16(
    f32x4 (&acc)[4][8], const float* bvj, int relu, int permM,
    unsigned short* smem, int wave, int lane,
    unsigned short* Cout, int m0, int n0, int wm, int wn, int M, int N) {
    unsigned short* stg = smem + wave * 2304;  // 128 cols * 18 shorts
    const int colc = lane & 15;
    const int rgrp = (lane >> 4) * 4;
    for (int i = 0; i < 4; ++i) {
        __syncthreads();
#pragma unroll
        for (int j = 0; j < 8; ++j) {
            float v0 = acc[i][j][0] + bvj[j];
            float v1 = acc[i][j][1] + bvj[j];
            float v2 = acc[i][j][2] + bvj[j];
            float v3 = acc[i][j][3] + bvj[j];
            if (relu) {
                v0 = fmaxf(v0, 0.f); v1 = fmaxf(v1, 0.f);
                v2 = fmaxf(v2, 0.f); v3 = fmaxf(v3, 0.f);
            }
            int c = j * 16 + colc;
            *(unsigned int*)&stg[c * 18 + rgrp] = pack2(v0, v1);
            *(unsigned int*)&stg[c * 18 + rgrp + 2] = pack2(v2, v3);
        }
        __syncthreads();
#pragma unroll
        for (int p = 0; p < 2; ++p) {
            int colg = lane & 15;                  // 8-col group
            int rp = p * 4 + (lane >> 4);          // row pair 0..7
            unsigned int w[8];
#pragma unroll
            for (int t = 0; t < 8; ++t)
                w[t] = *(const unsigned int*)&stg[(colg * 8 + t) * 18 + rp * 2];
            uint4 lo, hi;
            lo.x = (w[0] & 0xffffu) | (w[1] << 16);
            lo.y = (w[2] & 0xffffu) | (w[3] << 16);
            lo.z = (w[4] & 0xffffu) | (w[5] << 16);
            lo.w = (w[6] & 0xffffu) | (w[7] << 16);
            hi.x = (w[0] >> 16) | (w[1] & 0xffff0000u);
            hi.y = (w[2] >> 16) | (w[3] & 0xffff0000u);
            hi.z = (w[4] >> 16) | (w[5] & 0xffff0000u);
            hi.w = (w[6] >> 16) | (w[7] & 0xffff0000u);
            int mlo = m0 + wm * 64 + i * 16 + rp * 2;
            int n = n0 + wn * 128 + colg * 8;
            if (permM) {
                size_t base = (size_t)(n >> 5) * ((size_t)permM * 32) +
                              (size_t)mlo * 32 + (n & 31);
                if (mlo < M)     *(uint4*)&Cout[base] = lo;
                if (mlo + 1 < M) *(uint4*)&Cout[base + 32] = hi;
            } else {
                if (mlo < M)     *(uint4*)&Cout[(size_t)mlo * N + n] = lo;
                if (mlo + 1 < M) *(uint4*)&Cout[(size_t)(mlo + 1) * N + n] = hi;
            }
        }
    }
}

// ---------------------------------------------------------------------------
// MFMA SAGE GEMM (layer 0): C = relu( Aagg @ Wl^T + Aself @ Wr^T + bias )
// Tile 128x256, BK=32, 4 waves of 4x8 frags. Coalesced bf16 epilogue.
// ---------------------------------------------------------------------------
__global__ void __launch_bounds__(256, 2) sage_gemm_mfma(
    const unsigned short* __restrict__ Aagg, const unsigned short* __restrict__ Aself,
    const unsigned short* __restrict__ Wlb, const unsigned short* __restrict__ Wrb,
    const float* __restrict__ bias, unsigned short* __restrict__ Cout,
    int M, int N, int K) {
    __shared__ __attribute__((aligned(16))) unsigned short smem[12288];  // 24 KB
    unsigned short* As = smem;            // 128*32
    unsigned short* Bs = smem + 4096;     // 256*32
    const int tid = threadIdx.x;
    const int lane = tid & 63;
    const int wave = tid >> 6;
    const int wm = wave >> 1, wn = wave & 1;
    const int m0 = blockIdx.y * 128, n0 = blockIdx.x * 256;

    f32x4 acc[4][8];
#pragma unroll
    for (int i = 0; i < 4; ++i)
#pragma unroll
        for (int j = 0; j < 8; ++j) acc[i][j] = (f32x4){0.f, 0.f, 0.f, 0.f};

    const int srow = wave * 16 + (lane >> 2);
    const int kE = (lane & 3) * 8;
    const int frow = lane & 15;
    const int kk = (lane >> 4) * 8;

    for (int pass = 0; pass < 2; ++pass) {
        const unsigned short* A = pass ? Aself : Aagg;
        const unsigned short* W = pass ? Wrb : Wlb;
        for (int k0 = 0; k0 < K; k0 += 32) {
            __syncthreads();
            GLD_LDS(A + (size_t)(m0 + 0 * 64 + srow) * K + k0 + kE, &As[0 * 2048 + wave * 512]);
            GLD_LDS(A + (size_t)(m0 + 1 * 64 + srow) * K + k0 + kE, &As[1 * 2048 + wave * 512]);
            GLD_LDS(W + (size_t)(n0 + 0 * 64 + srow) * K + k0 + kE, &Bs[0 * 2048 + wave * 512]);
            GLD_LDS(W + (size_t)(n0 + 1 * 64 + srow) * K + k0 + kE, &Bs[1 * 2048 + wave * 512]);
            GLD_LDS(W + (size_t)(n0 + 2 * 64 + srow) * K + k0 + kE, &Bs[2 * 2048 + wave * 512]);
            GLD_LDS(W + (size_t)(n0 + 3 * 64 + srow) * K + k0 + kE, &Bs[3 * 2048 + wave * 512]);
            __syncthreads();
            bf16x8 af[4], bfr[8];
#pragma unroll
            for (int t = 0; t < 4; ++t)
                af[t] = *(const bf16x8*)&As[(wm * 64 + t * 16 + frow) * 32 + kk];
#pragma unroll
            for (int t = 0; t < 8; ++t)
                bfr[t] = *(const bf16x8*)&Bs[(wn * 128 + t * 16 + frow) * 32 + kk];
#pragma unroll
            for (int i = 0; i < 4; ++i)
#pragma unroll
                for (int j = 0; j < 8; ++j)
                    acc[i][j] = __builtin_amdgcn_mfma_f32_16x16x32_bf16(
                        af[i], bfr[j], acc[i][j], 0, 0, 0);
        }
    }

    float bvj[8];
#pragma unroll
    for (int j = 0; j < 8; ++j) bvj[j] = bias[n0 + wn * 128 + j * 16 + (lane & 15)];
    epilogue_bf16(acc, bvj, 1, 0, smem, wave, lane, Cout, m0, n0, wm, wn, M, N);
}

// ---------------------------------------------------------------------------
// Dual-output MFMA GEMM (layers 1-2): P = A@Wl^T ; Q = A@Wr^T + bias.
// grid.x covers 2N in 256-col blocks (first half P, second half Q).
// P (and optionally bf16 Q) written slice-permuted for the gather kernels.
// ---------------------------------------------------------------------------
__global__ void __launch_bounds__(256, 2) dual_gemm_mfma(
    const unsigned short* __restrict__ A,
    const unsigned short* __restrict__ Wlb, const unsigned short* __restrict__ Wrb,
    const float* __restrict__ bias, unsigned short* __restrict__ P,
    void* __restrict__ Q, int M, int N, int K, int q_fp32, int permM) {
    __shared__ __attribute__((aligned(16))) unsigned short smem[12288];  // 24 KB
    unsigned short* As = smem;
    unsigned short* Bs = smem + 4096;
    const int tid = threadIdx.x;
    const int lane = tid & 63;
    const int wave = tid >> 6;
    const int wm = wave >> 1, wn = wave & 1;
    const int m0 = blockIdx.y * 128;
    const int n0s = blockIdx.x * 256;          // in [0, 2N)
    const int isQ = n0s >= N;
    const int n0 = isQ ? n0s - N : n0s;
    const unsigned short* W = isQ ? Wrb : Wlb;

    f32x4 acc[4][8];
#pragma unroll
    for (int i = 0; i < 4; ++i)
#pragma unroll
        for (int j = 0; j < 8; ++j) acc[i][j] = (f32x4){0.f, 0.f, 0.f, 0.f};

    const int srow = wave * 16 + (lane >> 2);
    const int kE = (lane & 3) * 8;
    const int frow = lane & 15;
    const int kk = (lane >> 4) * 8;

    for (int k0 = 0; k0 < K; k0 += 32) {
        __syncthreads();
        GLD_LDS(A + (size_t)(m0 + 0 * 64 + srow) * K + k0 + kE, &As[0 * 2048 + wave * 512]);
        GLD_LDS(A + (size_t)(m0 + 1 * 64 + srow) * K + k0 + kE, &As[1 * 2048 + wave * 512]);
        GLD_LDS(W + (size_t)(n0 + 0 * 64 + srow) * K + k0 + kE, &Bs[0 * 2048 + wave * 512]);
        GLD_LDS(W + (size_t)(n0 + 1 * 64 + srow) * K + k0 + kE, &Bs[1 * 2048 + wave * 512]);
        GLD_LDS(W + (size_t)(n0 + 2 * 64 + srow) * K + k0 + kE, &Bs[2 * 2048 + wave * 512]);
        GLD_LDS(W + (size_t)(n0 + 3 * 64 + srow) * K + k0 + kE, &Bs[3 * 2048 + wave * 512]);
        __syncthreads();
        bf16x8 af[4], bfr[8];
#pragma unroll
        for (int t = 0; t < 4; ++t)
            af[t] = *(const bf16x8*)&As[(wm * 64 + t * 16 + frow) * 32 + kk];
#pragma unroll
        for (int t = 0; t < 8; ++t)
            bfr[t] = *(const bf16x8*)&Bs[(wn * 128 + t * 16 + frow) * 32 + kk];
#pragma unroll
        for (int i = 0; i < 4; ++i)
#pragma unroll
            for (int j = 0; j < 8; ++j)
                acc[i][j] = __builtin_amdgcn_mfma_f32_16x16x32_bf16(
                    af[i], bfr[j], acc[i][j], 0, 0, 0);
    }

    if (!isQ || !q_fp32) {
        float bvj[8];
#pragma unroll
        for (int j = 0; j < 8; ++j)
            bvj[j] = isQ ? bias[n0 + wn * 128 + j * 16 + (lane & 15)] : 0.f;
        unsigned short* Cout = isQ ? (unsigned short*)Q : P;
        epilogue_bf16(acc, bvj, 0, permM, smem, wave, lane, Cout, m0, n0, wm, wn, M, N);
    } else {
        // fp32 Q: scalar stores are 64 B per quarter-wave -> already coalesced
        const int col = lane & 15;
        const int rgrp = (lane >> 4) * 4;
        float* Qf = (float*)Q;
#pragma unroll
        for (int j = 0; j < 8; ++j) {
            int n = n0 + wn * 128 + j * 16 + col;
            float bv = bias[n];
#pragma unroll
            for (int i = 0; i < 4; ++i) {
                int mBase = m0 + wm * 64 + i * 16 + rgrp;
#pragma unroll
                for (int r = 0; r < 4; ++r) {
                    int m = mBase + r;
                    if (m >= M) continue;
                    Qf[(size_t)m * N + n] = acc[i][j][r] + bv;
                }
            }
        }
    }
}

// ---------------------------------------------------------------------------
extern "C" void kernel_launch(void* const* d_in, const int* in_sizes, int n_in,
                              void* d_out, int out_size, void* d_ws, size_t ws_size,
                              hipStream_t stream) {
    const float* x   = (const float*)d_in[0];
    const int*   e   = (const int*)d_in[1];
    const float* Wl0 = (const float*)d_in[2];
    const float* bl0 = (const float*)d_in[3];
    const float* Wr0 = (const float*)d_in[4];
    const float* Wl1 = (const float*)d_in[5];
    const float* bl1 = (const float*)d_in[6];
    const float* Wr1 = (const float*)d_in[7];
    const float* Wl2 = (const float*)d_in[8];
    const float* bl2 = (const float*)d_in[9];
    const float* Wr2 = (const float*)d_in[10];
    float* out = (float*)d_out;

    const int N = in_sizes[0] / 128;           // 50000 nodes
    const int E = in_sizes[1] / 2;             // 800000 edges
    const int Mpad = ((N + 127) / 128) * 128;  // 50048: GEMM staging never OOB

    char* ws = (char*)d_ws;
    size_t off = 0;
    auto alloc = [&](size_t bytes) { size_t o = off; off = align_up(off + bytes, 512); return o; };

    size_t o_nz     = alloc(4);
    size_t o_cnt    = alloc((size_t)N * 4);
    size_t o_cursor = alloc((size_t)N * 4);
    size_t o_hist   = alloc(256 * 4);
    size_t o_hcur   = alloc(256 * 4);
    size_t zero_end = off;                       // [0, zero_end) zeroed each call
    size_t o_hoffs  = alloc(256 * 4);
    size_t o_part   = alloc(1024 * 4);
    size_t o_offs   = alloc((size_t)(N + 1) * 4);
    size_t o_inv    = alloc((size_t)N * 4);
    size_t o_perm   = alloc((size_t)N * 4);
    size_t o_src    = alloc((size_t)E * 4);
    size_t o_dst    = alloc((size_t)E * 4);
    size_t o_sort   = alloc((size_t)E * 4);
    size_t o_xb     = alloc((size_t)Mpad * 128 * 2);   // bf16 x row-major
    size_t o_xp     = alloc((size_t)N * 128 * 2);      // bf16 x slice-permuted [4][N][32]
    size_t o_aggx   = alloc((size_t)Mpad * 128 * 2);   // bf16 agg(x) row-major
    size_t o_h      = alloc((size_t)Mpad * 512 * 2);   // h0, then h1 (row-major)
    size_t o_P      = alloc((size_t)Mpad * 512 * 2);   // P1 [16][Mpad][32], then P2 [8][Mpad][32]
    size_t o_Q      = alloc((size_t)Mpad * 512 * 2);   // Q1 [16][Mpad][32] bf16, then Q2 fp32 row-major
    size_t o_wl0    = alloc((size_t)512 * 128 * 2);
    size_t o_wr0    = alloc((size_t)512 * 128 * 2);
    size_t o_wl1    = alloc((size_t)512 * 512 * 2);
    size_t o_wr1    = alloc((size_t)512 * 512 * 2);
    size_t o_wl2    = alloc((size_t)256 * 512 * 2);
    size_t o_wr2    = alloc((size_t)256 * 512 * 2);
    (void)ws_size; (void)n_in; (void)out_size;

    int*            nz     = (int*)(ws + o_nz);
    int*            cnt    = (int*)(ws + o_cnt);
    int*            cursor = (int*)(ws + o_cursor);
    int*            hist   = (int*)(ws + o_hist);
    int*            hcur   = (int*)(ws + o_hcur);
    int*            hoffs  = (int*)(ws + o_hoffs);
    int*            part   = (int*)(ws + o_part);
    int*            offs   = (int*)(ws + o_offs);
    float*          inv    = (float*)(ws + o_inv);
    int*            perm   = (int*)(ws + o_perm);
    int*            src32  = (int*)(ws + o_src);
    int*            dst32  = (int*)(ws + o_dst);
    int*            sorted = (int*)(ws + o_sort);
    unsigned short* xb     = (unsigned short*)(ws + o_xb);
    unsigned short* xp     = (unsigned short*)(ws + o_xp);
    unsigned short* aggx   = (unsigned short*)(ws + o_aggx);
    unsigned short* hbuf   = (unsigned short*)(ws + o_h);
    unsigned short* Pbuf   = (unsigned short*)(ws + o_P);
    unsigned short* Qbuf   = (unsigned short*)(ws + o_Q);   // bf16 view (layer 1, permuted)
    float*          Qf     = (float*)(ws + o_Q);            // fp32 view (layer 2, row-major)
    unsigned short* wl0b   = (unsigned short*)(ws + o_wl0);
    unsigned short* wr0b   = (unsigned short*)(ws + o_wr0);
    unsigned short* wl1b   = (unsigned short*)(ws + o_wl1);
    unsigned short* wr1b   = (unsigned short*)(ws + o_wr1);
    unsigned short* wl2b   = (unsigned short*)(ws + o_wl2);
    unsigned short* wr2b   = (unsigned short*)(ws + o_wr2);

    // zero nz/cnt/cursor/hist/hcur (ws poisoned 0xAA before every call)
    int zn = (int)(zero_end / 4);
    zero_kernel<<<(zn + 255) / 256, 256, 0, stream>>>((int*)ws, zn);

    int eb = (E + 255) / 256;
    detect_kernel<<<1, 256, 0, stream>>>(e, nz, E);
    conv_count_kernel<<<eb, 256, 0, stream>>>(e, nz, src32, dst32, cnt, E);

    const int C = (N + 1023) / 1024;
    scan1_kernel<<<4, 256, 0, stream>>>(cnt, part, N, C);
    scan2_kernel<<<1, 1024, 0, stream>>>(part);
    scan3_kernel<<<4, 256, 0, stream>>>(cnt, part, offs, N, C, E);
    inv_kernel<<<(N + 255) / 256, 256, 0, stream>>>(cnt, inv, N);
    fill_kernel<<<eb, 256, 0, stream>>>(src32, dst32, offs, cursor, sorted, E);

    // degree-sorted node permutation (counting sort on cnt)
    int nb256 = (N + 255) / 256;
    hist_kernel<<<nb256, 256, 0, stream>>>(cnt, hist, N);
    scanhist_kernel<<<1, 256, 0, stream>>>(hist, hoffs);
    place_kernel<<<nb256, 256, 0, stream>>>(cnt, hoffs, hcur, perm, N);

    // conversions to bf16
    int n4 = N * 128 / 4;
    cvt_bf16_kernel<<<(n4 + 255) / 256, 256, 0, stream>>>(x, xb, n4);
    cvt_perm_kernel<<<(N * 64 + 255) / 256, 256, 0, stream>>>(x, xp, N);
    cvt_bf16_kernel<<<(512 * 128 / 4 + 255) / 256, 256, 0, stream>>>(Wl0, wl0b, 512 * 128 / 4);
    cvt_bf16_kernel<<<(512 * 128 / 4 + 255) / 256, 256, 0, stream>>>(Wr0, wr0b, 512 * 128 / 4);
    cvt_bf16_kernel<<<(512 * 512 / 4 + 255) / 256, 256, 0, stream>>>(Wl1, wl1b, 512 * 512 / 4);
    cvt_bf16_kernel<<<(512 * 512 / 4 + 255) / 256, 256, 0, stream>>>(Wr1, wr1b, 512 * 512 / 4);
    cvt_bf16_kernel<<<(256 * 512 / 4 + 255) / 256, 256, 0, stream>>>(Wl2, wl2b, 256 * 512 / 4);
    cvt_bf16_kernel<<<(256 * 512 / 4 + 255) / 256, 256, 0, stream>>>(Wr2, wr2b, 256 * 512 / 4);

    const int mBlocks = Mpad / 128;
    const int T = (N + 63) / 64;               // 64 nodes per tile (16/wave x 4 waves)

    // Layer 0: sliced gather of x (4 slices, 2 XCDs each), then SAGE GEMM.
    aggslice_v3<0><<<8 * ((T + 1) / 2), 256, 0, stream>>>(
        xp, nullptr, nullptr, sorted, offs, inv, perm, aggx, nullptr, N, N, 0, 4, 128);
    sage_gemm_mfma<<<dim3(2, mBlocks), 256, 0, stream>>>(
        aggx, xb, wl0b, wr0b, bl0, hbuf, N, 512, 128);

    // Layer 1: GEMM-then-agg: P1/Q1 slice-permuted [16][Mpad][32];
    // h1 = relu(inv*sum P1[src] + Q1)  (two launches: slices 0-7, then 8-15)
    dual_gemm_mfma<<<dim3(4, mBlocks), 256, 0, stream>>>(
        hbuf, wl1b, wr1b, bl1, Pbuf, Qbuf, N, 512, 512, 0, Mpad);
    aggslice_v3<1><<<8 * T, 256, 0, stream>>>(
        Pbuf, Qbuf, nullptr, sorted, offs, inv, perm, hbuf, nullptr, N, Mpad, 0, 8, 512);
    aggslice_v3<1><<<8 * T, 256, 0, stream>>>(
        Pbuf, Qbuf, nullptr, sorted, offs, inv, perm, hbuf, nullptr, N, Mpad, 8, 8, 512);

    // Layer 2: GEMM-then-agg at 256-dim; P2 slice-permuted [8][Mpad][32],
    // Q2 fp32 row-major; out = inv*sum P2[src] + Q2 (fp32, no relu)
    dual_gemm_mfma<<<dim3(2, mBlocks), 256, 0, stream>>>(
        hbuf, wl2b, wr2b, bl2, Pbuf, (void*)Qf, N, 256, 512, 1, Mpad);
    aggslice_v3<2><<<8 * T, 256, 0, stream>>>(
        Pbuf, nullptr, Qf, sorted, offs, inv, perm, nullptr, out, N, Mpad, 0, 8, 256);
}

// Round 5
// 795.919 us; speedup vs baseline: 1.3340x; 1.2795x over previous
//
#include <hip/hip_runtime.h>
#include <hip/hip_bf16.h>
#include <cstdint>
#include <cstddef>

static inline size_t align_up(size_t x, size_t a) { return (x + a - 1) & ~(a - 1); }

typedef __attribute__((ext_vector_type(4))) float f32x4;
typedef __attribute__((ext_vector_type(4))) unsigned int u32x4;
typedef __attribute__((ext_vector_type(8))) short bf16x8;

__device__ inline float bf2f(unsigned int u16) {        // low 16 bits hold bf16
    return __uint_as_float(u16 << 16);
}
__device__ inline float bflo(unsigned int v) { return __uint_as_float(v << 16); }
__device__ inline float bfhi(unsigned int v) { return __uint_as_float(v & 0xffff0000u); }
__device__ inline unsigned short f2bf(float f) {        // round-to-nearest-even
    unsigned int u = __float_as_uint(f);
    u = (u + 0x7fffu + ((u >> 16) & 1u)) >> 16;
    return (unsigned short)u;
}
__device__ inline unsigned int pack2(float lo, float hi) {
    return (unsigned int)f2bf(lo) | ((unsigned int)f2bf(hi) << 16);
}

#define GLD_LDS(gp, lp) \
    __builtin_amdgcn_global_load_lds( \
        (const __attribute__((address_space(1))) unsigned int*)(gp), \
        (__attribute__((address_space(3))) unsigned int*)(lp), 16, 0, 0)

// ---------------------------------------------------------------------------
__global__ void zero_kernel(int* __restrict__ p, int n) {
    int i = blockIdx.x * 256 + threadIdx.x;
    if (i < n) p[i] = 0;
}

// Edge-encoding detection, single block, sampled, no atomics.
__global__ void detect_kernel(const int* __restrict__ e, int* __restrict__ nz, int E) {
    int t = threadIdx.x;  // 0..255, one block
    long long stride = (long long)E / 4096;
    if (stride < 1) stride = 1;
    int any = 0;
    for (int k = 0; k < 16; ++k) {
        long long idx = (long long)(t * 16 + k) * stride;
        if (idx < E && e[2 * idx + 1] != 0) any = 1;
    }
    if (any) nz[0] = 1;  // same-value race is benign
}

__global__ void conv_count_kernel(const int* __restrict__ eraw, const int* __restrict__ nz,
                                  int* __restrict__ src32, int* __restrict__ dst32,
                                  int* __restrict__ cnt, int E) {
    int i = blockIdx.x * blockDim.x + threadIdx.x;
    if (i >= E) return;
    int s, d;
    if (*nz == 0) {  // int64 storage
        const long long* e64 = (const long long*)eraw;
        s = (int)e64[i];
        d = (int)e64[i + E];
    } else {         // int32 storage
        s = eraw[i];
        d = eraw[i + E];
    }
    src32[i] = s;
    dst32[i] = d;
    atomicAdd(&cnt[d], 1);
}

// 3-kernel exclusive scan over cnt[0..n) -> offs[0..n]
__global__ void scan1_kernel(const int* __restrict__ cnt, int* __restrict__ partial,
                             int n, int C) {
    int t = blockIdx.x * 256 + threadIdx.x;  // 0..1023
    int s = 0;
    int base = t * C;
    for (int i = 0; i < C; ++i) {
        int idx = base + i;
        if (idx < n) s += cnt[idx];
    }
    partial[t] = s;
}

__global__ void __launch_bounds__(1024) scan2_kernel(int* __restrict__ partial) {
    __shared__ int sh[1024];
    int t = threadIdx.x;
    sh[t] = partial[t];
    __syncthreads();
    for (int off = 1; off < 1024; off <<= 1) {
        int v = (t >= off) ? sh[t - off] : 0;
        __syncthreads();
        sh[t] += v;
        __syncthreads();
    }
    partial[t] = (t == 0) ? 0 : sh[t - 1];  // exclusive
}

__global__ void scan3_kernel(const int* __restrict__ cnt, const int* __restrict__ partial,
                             int* __restrict__ offs, int n, int C, int E) {
    int t = blockIdx.x * 256 + threadIdx.x;
    int run = partial[t];
    int base = t * C;
    for (int i = 0; i < C; ++i) {
        int idx = base + i;
        if (idx < n) {
            offs[idx] = run;
            run += cnt[idx];
        }
    }
    if (t == 0) offs[n] = E;
}

__global__ void inv_kernel(const int* __restrict__ cnt, float* __restrict__ inv, int n) {
    int i = blockIdx.x * 256 + threadIdx.x;
    if (i < n) inv[i] = 1.0f / (float)max(cnt[i], 1);
}

__global__ void fill_kernel(const int* __restrict__ src32, const int* __restrict__ dst32,
                            const int* __restrict__ offs, int* __restrict__ cursor,
                            int* __restrict__ sorted, int E) {
    int i = blockIdx.x * 256 + threadIdx.x;
    if (i >= E) return;
    int d = dst32[i];
    int p = offs[d] + atomicAdd(&cursor[d], 1);
    sorted[p] = src32[i];
}

// fp32 -> bf16, vectorized x4
__global__ void cvt_bf16_kernel(const float* __restrict__ x, unsigned short* __restrict__ xb,
                                int n4) {
    int i = blockIdx.x * 256 + threadIdx.x;
    if (i >= n4) return;
    float4 v = *(const float4*)(x + (size_t)i * 4);
    uint2 o;
    o.x = pack2(v.x, v.y);
    o.y = pack2(v.z, v.w);
    *(uint2*)(xb + (size_t)i * 4) = o;
}

// fp32 x [N][128] -> bf16 slice-permuted xp [4][N][32]
__global__ void cvt_perm_kernel(const float* __restrict__ x, unsigned short* __restrict__ xp,
                                int nNodes) {
    int i = blockIdx.x * 256 + threadIdx.x;   // one per 2 dims
    if (i >= nNodes * 64) return;
    int n = i >> 6;
    int d = (i & 63) * 2;
    float2 v = *(const float2*)(x + (size_t)n * 128 + d);
    *(unsigned int*)(xp + (size_t)(d >> 5) * nNodes * 32 + (size_t)n * 32 + (d & 31)) =
        pack2(v.x, v.y);
}

// ---------------------------------------------------------------------------
// Sliced gather v4 (round-4 design; round-5 = type-fixed compile).
//
// Validated across rounds 1-3: slice-major table [S][node][32dims] (64 B,
// contiguous 3.2 MB/slice) + blockIdx%8 XCD pinning keeps the gather table
// L2-resident (round-2 FETCH 401->49 MB). Round-3 losses and their fixes:
//  - degree-sort place_kernel = 133 us of atomic-return serialization ->
//    sort DELETED; identity node order (srt ranges of a wave's 16 groups are
//    then contiguous; out rows contiguous).
//  - v3 inner loop had MLP=2 (dependent srt->gather) -> latency-bound. v4
//    batches 8 edges: 8 independent srt nt-loads, then 8 independent 16 B
//    gathers in flight, unpack via 0/1-masked fmaf (no remainder loop,
//    clamped-safe index 0 for inactive edges). Ballot per 8-edge chunk.
//  - cached srt (3.2 MB) evicted the resident slice (3.2 MB) from 4 MB L2 ->
//    srt/Q loads and out stores NON-TEMPORAL (streaming; protect the slice).
//    With MLP=8 the nt latency is covered by issue work (round-2's nt mistake
//    was nt on an MLP=2 critical chain).
// wave = 16 nodes x 4 lanes; lane owns 16 B of the 64 B slice row.
// MODE 0: out bf16 row-major, scale only            (layer-0 x aggregation)
// MODE 1: out bf16 row-major, relu(a*sc + Qperm)    (layer-1)
// MODE 2: out fp32 row-major, a*sc + Qf32           (layer-2, final)
// ---------------------------------------------------------------------------
template <int MODE>
__global__ void __launch_bounds__(256) aggslice_v4(
    const unsigned short* __restrict__ P, const unsigned short* __restrict__ Qb,
    const float* __restrict__ Qf,
    const int* __restrict__ srt, const int* __restrict__ offs,
    const float* __restrict__ invc,
    unsigned short* __restrict__ outb, float* __restrict__ outf,
    int nNodes, int tabM, int sliceBase, int S, int D) {
    const int b = blockIdx.x;
    const int x = b & 7;                       // XCD id (round-robin dispatch)
    const int R = 8 / S;                       // XCD replicas per slice
    const int slice = sliceBase + (x % S);
    const int tile = (b >> 3) * R + (x / S);
    const int lane = threadIdx.x & 63;
    const int wave = threadIdx.x >> 6;
    const int g = lane >> 2;                   // node group 0..15
    const int j = lane & 3;                    // 16-byte chunk within 64 B slice
    const int node = tile * 64 + wave * 16 + g;
    int beg = 0, end = 0;
    float sc = 0.f;
    if (node < nNodes) {
        beg = offs[node];
        end = offs[node + 1];
        sc = invc[node];
    }
    const unsigned short* ps = P + (size_t)slice * tabM * 32 + j * 8;
    float a0 = 0.f, a1 = 0.f, a2 = 0.f, a3 = 0.f;
    float a4 = 0.f, a5 = 0.f, a6 = 0.f, a7 = 0.f;
    int cur = beg;
    while (__ballot(cur < end)) {
        int e[8];
        float m[8];
#pragma unroll
        for (int k = 0; k < 8; ++k) {
            bool act = (cur + k) < end;
            e[k] = act ? cur + k : 0;          // srt[0] always valid (E >= 1)
            m[k] = act ? 1.f : 0.f;
        }
        int s[8];
#pragma unroll
        for (int k = 0; k < 8; ++k) s[k] = __builtin_nontemporal_load(srt + e[k]);
        u32x4 v[8];
#pragma unroll
        for (int k = 0; k < 8; ++k)
            v[k] = *(const u32x4*)(ps + (size_t)(unsigned)s[k] * 32u);
#pragma unroll
        for (int k = 0; k < 8; ++k) {
            a0 = fmaf(bflo(v[k].x), m[k], a0);
            a1 = fmaf(bfhi(v[k].x), m[k], a1);
            a2 = fmaf(bflo(v[k].y), m[k], a2);
            a3 = fmaf(bfhi(v[k].y), m[k], a3);
            a4 = fmaf(bflo(v[k].z), m[k], a4);
            a5 = fmaf(bfhi(v[k].z), m[k], a5);
            a6 = fmaf(bflo(v[k].w), m[k], a6);
            a7 = fmaf(bfhi(v[k].w), m[k], a7);
        }
        cur += 8;
    }
    if (node >= nNodes) return;
    a0 *= sc; a1 *= sc; a2 *= sc; a3 *= sc;
    a4 *= sc; a5 *= sc; a6 *= sc; a7 *= sc;
    if (MODE == 0) {
        u32x4 o;
        o.x = pack2(a0, a1); o.y = pack2(a2, a3);
        o.z = pack2(a4, a5); o.w = pack2(a6, a7);
        __builtin_nontemporal_store(o, (u32x4*)(outb + (size_t)node * D + slice * 32 + j * 8));
    } else if (MODE == 1) {
        u32x4 q = __builtin_nontemporal_load(
            (const u32x4*)(Qb + (size_t)slice * tabM * 32 + (size_t)node * 32 + j * 8));
        float r0 = fmaxf(a0 + bflo(q.x), 0.f);
        float r1 = fmaxf(a1 + bfhi(q.x), 0.f);
        float r2 = fmaxf(a2 + bflo(q.y), 0.f);
        float r3 = fmaxf(a3 + bfhi(q.y), 0.f);
        float r4 = fmaxf(a4 + bflo(q.z), 0.f);
        float r5 = fmaxf(a5 + bfhi(q.z), 0.f);
        float r6 = fmaxf(a6 + bflo(q.w), 0.f);
        float r7 = fmaxf(a7 + bfhi(q.w), 0.f);
        u32x4 o;
        o.x = pack2(r0, r1); o.y = pack2(r2, r3);
        o.z = pack2(r4, r5); o.w = pack2(r6, r7);
        __builtin_nontemporal_store(o, (u32x4*)(outb + (size_t)node * D + slice * 32 + j * 8));
    } else {
        size_t qo = (size_t)node * D + slice * 32 + j * 8;
        f32x4 qa = __builtin_nontemporal_load((const f32x4*)(Qf + qo));
        f32x4 qb4 = __builtin_nontemporal_load((const f32x4*)(Qf + qo + 4));
        f32x4 ra, rb;
        ra.x = a0 + qa.x; ra.y = a1 + qa.y; ra.z = a2 + qa.z; ra.w = a3 + qa.w;
        rb.x = a4 + qb4.x; rb.y = a5 + qb4.y; rb.z = a6 + qb4.z; rb.w = a7 + qb4.w;
        __builtin_nontemporal_store(ra, (f32x4*)(outf + qo));
        __builtin_nontemporal_store(rb, (f32x4*)(outf + qo + 4));
    }
}

// ---------------------------------------------------------------------------
// Coalesced bf16 epilogue. permM == 0: row-major [m][N]. permM != 0: slice-
// permuted [n>>5][permM rows][32] (the uint4 chunk n..n+8 stays inside one
// 32-dim slice since n is 8-aligned).
// ---------------------------------------------------------------------------
__device__ __forceinline__ void epilogue_bf16(
    f32x4 (&acc)[4][8], const float* bvj, int relu, int permM,
    unsigned short* smem, int wave, int lane,
    unsigned short* Cout, int m0, int n0, int wm, int wn, int M, int N) {
    unsigned short* stg = smem + wave * 2304;  // 128 cols * 18 shorts
    const int colc = lane & 15;
    const int rgrp = (lane >> 4) * 4;
    for (int i = 0; i < 4; ++i) {
        __syncthreads();
#pragma unroll
        for (int j = 0; j < 8; ++j) {
            float v0 = acc[i][j][0] + bvj[j];
            float v1 = acc[i][j][1] + bvj[j];
            float v2 = acc[i][j][2] + bvj[j];
            float v3 = acc[i][j][3] + bvj[j];
            if (relu) {
                v0 = fmaxf(v0, 0.f); v1 = fmaxf(v1, 0.f);
                v2 = fmaxf(v2, 0.f); v3 = fmaxf(v3, 0.f);
            }
            int c = j * 16 + colc;
            *(unsigned int*)&stg[c * 18 + rgrp] = pack2(v0, v1);
            *(unsigned int*)&stg[c * 18 + rgrp + 2] = pack2(v2, v3);
        }
        __syncthreads();
#pragma unroll
        for (int p = 0; p < 2; ++p) {
            int colg = lane & 15;                  // 8-col group
            int rp = p * 4 + (lane >> 4);          // row pair 0..7
            unsigned int w[8];
#pragma unroll
            for (int t = 0; t < 8; ++t)
                w[t] = *(const unsigned int*)&stg[(colg * 8 + t) * 18 + rp * 2];
            uint4 lo, hi;
            lo.x = (w[0] & 0xffffu) | (w[1] << 16);
            lo.y = (w[2] & 0xffffu) | (w[3] << 16);
            lo.z = (w[4] & 0xffffu) | (w[5] << 16);
            lo.w = (w[6] & 0xffffu) | (w[7] << 16);
            hi.x = (w[0] >> 16) | (w[1] & 0xffff0000u);
            hi.y = (w[2] >> 16) | (w[3] & 0xffff0000u);
            hi.z = (w[4] >> 16) | (w[5] & 0xffff0000u);
            hi.w = (w[6] >> 16) | (w[7] & 0xffff0000u);
            int mlo = m0 + wm * 64 + i * 16 + rp * 2;
            int n = n0 + wn * 128 + colg * 8;
            if (permM) {
                size_t base = (size_t)(n >> 5) * ((size_t)permM * 32) +
                              (size_t)mlo * 32 + (n & 31);
                if (mlo < M)     *(uint4*)&Cout[base] = lo;
                if (mlo + 1 < M) *(uint4*)&Cout[base + 32] = hi;
            } else {
                if (mlo < M)     *(uint4*)&Cout[(size_t)mlo * N + n] = lo;
                if (mlo + 1 < M) *(uint4*)&Cout[(size_t)(mlo + 1) * N + n] = hi;
            }
        }
    }
}

// ---------------------------------------------------------------------------
// MFMA SAGE GEMM (layer 0): C = relu( Aagg @ Wl^T + Aself @ Wr^T + bias )
// Tile 128x256, BK=32, 4 waves of 4x8 frags. Coalesced bf16 epilogue.
// ---------------------------------------------------------------------------
__global__ void __launch_bounds__(256, 2) sage_gemm_mfma(
    const unsigned short* __restrict__ Aagg, const unsigned short* __restrict__ Aself,
    const unsigned short* __restrict__ Wlb, const unsigned short* __restrict__ Wrb,
    const float* __restrict__ bias, unsigned short* __restrict__ Cout,
    int M, int N, int K) {
    __shared__ __attribute__((aligned(16))) unsigned short smem[12288];  // 24 KB
    unsigned short* As = smem;            // 128*32
    unsigned short* Bs = smem + 4096;     // 256*32
    const int tid = threadIdx.x;
    const int lane = tid & 63;
    const int wave = tid >> 6;
    const int wm = wave >> 1, wn = wave & 1;
    const int m0 = blockIdx.y * 128, n0 = blockIdx.x * 256;

    f32x4 acc[4][8];
#pragma unroll
    for (int i = 0; i < 4; ++i)
#pragma unroll
        for (int j = 0; j < 8; ++j) acc[i][j] = (f32x4){0.f, 0.f, 0.f, 0.f};

    const int srow = wave * 16 + (lane >> 2);
    const int kE = (lane & 3) * 8;
    const int frow = lane & 15;
    const int kk = (lane >> 4) * 8;

    for (int pass = 0; pass < 2; ++pass) {
        const unsigned short* A = pass ? Aself : Aagg;
        const unsigned short* W = pass ? Wrb : Wlb;
        for (int k0 = 0; k0 < K; k0 += 32) {
            __syncthreads();
            GLD_LDS(A + (size_t)(m0 + 0 * 64 + srow) * K + k0 + kE, &As[0 * 2048 + wave * 512]);
            GLD_LDS(A + (size_t)(m0 + 1 * 64 + srow) * K + k0 + kE, &As[1 * 2048 + wave * 512]);
            GLD_LDS(W + (size_t)(n0 + 0 * 64 + srow) * K + k0 + kE, &Bs[0 * 2048 + wave * 512]);
            GLD_LDS(W + (size_t)(n0 + 1 * 64 + srow) * K + k0 + kE, &Bs[1 * 2048 + wave * 512]);
            GLD_LDS(W + (size_t)(n0 + 2 * 64 + srow) * K + k0 + kE, &Bs[2 * 2048 + wave * 512]);
            GLD_LDS(W + (size_t)(n0 + 3 * 64 + srow) * K + k0 + kE, &Bs[3 * 2048 + wave * 512]);
            __syncthreads();
            bf16x8 af[4], bfr[8];
#pragma unroll
            for (int t = 0; t < 4; ++t)
                af[t] = *(const bf16x8*)&As[(wm * 64 + t * 16 + frow) * 32 + kk];
#pragma unroll
            for (int t = 0; t < 8; ++t)
                bfr[t] = *(const bf16x8*)&Bs[(wn * 128 + t * 16 + frow) * 32 + kk];
#pragma unroll
            for (int i = 0; i < 4; ++i)
#pragma unroll
                for (int j = 0; j < 8; ++j)
                    acc[i][j] = __builtin_amdgcn_mfma_f32_16x16x32_bf16(
                        af[i], bfr[j], acc[i][j], 0, 0, 0);
        }
    }

    float bvj[8];
#pragma unroll
    for (int j = 0; j < 8; ++j) bvj[j] = bias[n0 + wn * 128 + j * 16 + (lane & 15)];
    epilogue_bf16(acc, bvj, 1, 0, smem, wave, lane, Cout, m0, n0, wm, wn, M, N);
}

// ---------------------------------------------------------------------------
// Dual-output MFMA GEMM (layers 1-2): P = A@Wl^T ; Q = A@Wr^T + bias.
// grid.x covers 2N in 256-col blocks (first half P, second half Q).
// P (and optionally bf16 Q) written slice-permuted for the gather kernels.
// ---------------------------------------------------------------------------
__global__ void __launch_bounds__(256, 2) dual_gemm_mfma(
    const unsigned short* __restrict__ A,
    const unsigned short* __restrict__ Wlb, const unsigned short* __restrict__ Wrb,
    const float* __restrict__ bias, unsigned short* __restrict__ P,
    void* __restrict__ Q, int M, int N, int K, int q_fp32, int permM) {
    __shared__ __attribute__((aligned(16))) unsigned short smem[12288];  // 24 KB
    unsigned short* As = smem;
    unsigned short* Bs = smem + 4096;
    const int tid = threadIdx.x;
    const int lane = tid & 63;
    const int wave = tid >> 6;
    const int wm = wave >> 1, wn = wave & 1;
    const int m0 = blockIdx.y * 128;
    const int n0s = blockIdx.x * 256;          // in [0, 2N)
    const int isQ = n0s >= N;
    const int n0 = isQ ? n0s - N : n0s;
    const unsigned short* W = isQ ? Wrb : Wlb;

    f32x4 acc[4][8];
#pragma unroll
    for (int i = 0; i < 4; ++i)
#pragma unroll
        for (int j = 0; j < 8; ++j) acc[i][j] = (f32x4){0.f, 0.f, 0.f, 0.f};

    const int srow = wave * 16 + (lane >> 2);
    const int kE = (lane & 3) * 8;
    const int frow = lane & 15;
    const int kk = (lane >> 4) * 8;

    for (int k0 = 0; k0 < K; k0 += 32) {
        __syncthreads();
        GLD_LDS(A + (size_t)(m0 + 0 * 64 + srow) * K + k0 + kE, &As[0 * 2048 + wave * 512]);
        GLD_LDS(A + (size_t)(m0 + 1 * 64 + srow) * K + k0 + kE, &As[1 * 2048 + wave * 512]);
        GLD_LDS(W + (size_t)(n0 + 0 * 64 + srow) * K + k0 + kE, &Bs[0 * 2048 + wave * 512]);
        GLD_LDS(W + (size_t)(n0 + 1 * 64 + srow) * K + k0 + kE, &Bs[1 * 2048 + wave * 512]);
        GLD_LDS(W + (size_t)(n0 + 2 * 64 + srow) * K + k0 + kE, &Bs[2 * 2048 + wave * 512]);
        GLD_LDS(W + (size_t)(n0 + 3 * 64 + srow) * K + k0 + kE, &Bs[3 * 2048 + wave * 512]);
        __syncthreads();
        bf16x8 af[4], bfr[8];
#pragma unroll
        for (int t = 0; t < 4; ++t)
            af[t] = *(const bf16x8*)&As[(wm * 64 + t * 16 + frow) * 32 + kk];
#pragma unroll
        for (int t = 0; t < 8; ++t)
            bfr[t] = *(const bf16x8*)&Bs[(wn * 128 + t * 16 + frow) * 32 + kk];
#pragma unroll
        for (int i = 0; i < 4; ++i)
#pragma unroll
            for (int j = 0; j < 8; ++j)
                acc[i][j] = __builtin_amdgcn_mfma_f32_16x16x32_bf16(
                    af[i], bfr[j], acc[i][j], 0, 0, 0);
    }

    if (!isQ || !q_fp32) {
        float bvj[8];
#pragma unroll
        for (int j = 0; j < 8; ++j)
            bvj[j] = isQ ? bias[n0 + wn * 128 + j * 16 + (lane & 15)] : 0.f;
        unsigned short* Cout = isQ ? (unsigned short*)Q : P;
        epilogue_bf16(acc, bvj, 0, permM, smem, wave, lane, Cout, m0, n0, wm, wn, M, N);
    } else {
        // fp32 Q: scalar stores are 64 B per quarter-wave -> already coalesced
        const int col = lane & 15;
        const int rgrp = (lane >> 4) * 4;
        float* Qf = (float*)Q;
#pragma unroll
        for (int j = 0; j < 8; ++j) {
            int n = n0 + wn * 128 + j * 16 + col;
            float bv = bias[n];
#pragma unroll
            for (int i = 0; i < 4; ++i) {
                int mBase = m0 + wm * 64 + i * 16 + rgrp;
#pragma unroll
                for (int r = 0; r < 4; ++r) {
                    int m = mBase + r;
                    if (m >= M) continue;
                    Qf[(size_t)m * N + n] = acc[i][j][r] + bv;
                }
            }
        }
    }
}

// ---------------------------------------------------------------------------
extern "C" void kernel_launch(void* const* d_in, const int* in_sizes, int n_in,
                              void* d_out, int out_size, void* d_ws, size_t ws_size,
                              hipStream_t stream) {
    const float* x   = (const float*)d_in[0];
    const int*   e   = (const int*)d_in[1];
    const float* Wl0 = (const float*)d_in[2];
    const float* bl0 = (const float*)d_in[3];
    const float* Wr0 = (const float*)d_in[4];
    const float* Wl1 = (const float*)d_in[5];
    const float* bl1 = (const float*)d_in[6];
    const float* Wr1 = (const float*)d_in[7];
    const float* Wl2 = (const float*)d_in[8];
    const float* bl2 = (const float*)d_in[9];
    const float* Wr2 = (const float*)d_in[10];
    float* out = (float*)d_out;

    const int N = in_sizes[0] / 128;           // 50000 nodes
    const int E = in_sizes[1] / 2;             // 800000 edges
    const int Mpad = ((N + 127) / 128) * 128;  // 50048: GEMM staging never OOB

    char* ws = (char*)d_ws;
    size_t off = 0;
    auto alloc = [&](size_t bytes) { size_t o = off; off = align_up(off + bytes, 512); return o; };

    size_t o_nz     = alloc(4);
    size_t o_cnt    = alloc((size_t)N * 4);
    size_t o_cursor = alloc((size_t)N * 4);
    size_t zero_end = off;                       // [0, zero_end) zeroed each call
    size_t o_part   = alloc(1024 * 4);
    size_t o_offs   = alloc((size_t)(N + 1) * 4);
    size_t o_inv    = alloc((size_t)N * 4);
    size_t o_src    = alloc((size_t)E * 4);
    size_t o_dst    = alloc((size_t)E * 4);
    size_t o_sort   = alloc((size_t)E * 4);
    size_t o_xb     = alloc((size_t)Mpad * 128 * 2);   // bf16 x row-major
    size_t o_xp     = alloc((size_t)N * 128 * 2);      // bf16 x slice-permuted [4][N][32]
    size_t o_aggx   = alloc((size_t)Mpad * 128 * 2);   // bf16 agg(x) row-major
    size_t o_h      = alloc((size_t)Mpad * 512 * 2);   // h0, then h1 (row-major)
    size_t o_P      = alloc((size_t)Mpad * 512 * 2);   // P1 [16][Mpad][32], then P2 [8][Mpad][32]
    size_t o_Q      = alloc((size_t)Mpad * 512 * 2);   // Q1 [16][Mpad][32] bf16, then Q2 fp32 row-major
    size_t o_wl0    = alloc((size_t)512 * 128 * 2);
    size_t o_wr0    = alloc((size_t)512 * 128 * 2);
    size_t o_wl1    = alloc((size_t)512 * 512 * 2);
    size_t o_wr1    = alloc((size_t)512 * 512 * 2);
    size_t o_wl2    = alloc((size_t)256 * 512 * 2);
    size_t o_wr2    = alloc((size_t)256 * 512 * 2);
    (void)ws_size; (void)n_in; (void)out_size;

    int*            nz     = (int*)(ws + o_nz);
    int*            cnt    = (int*)(ws + o_cnt);
    int*            cursor = (int*)(ws + o_cursor);
    int*            part   = (int*)(ws + o_part);
    int*            offs   = (int*)(ws + o_offs);
    float*          inv    = (float*)(ws + o_inv);
    int*            src32  = (int*)(ws + o_src);
    int*            dst32  = (int*)(ws + o_dst);
    int*            sorted = (int*)(ws + o_sort);
    unsigned short* xb     = (unsigned short*)(ws + o_xb);
    unsigned short* xp     = (unsigned short*)(ws + o_xp);
    unsigned short* aggx   = (unsigned short*)(ws + o_aggx);
    unsigned short* hbuf   = (unsigned short*)(ws + o_h);
    unsigned short* Pbuf   = (unsigned short*)(ws + o_P);
    unsigned short* Qbuf   = (unsigned short*)(ws + o_Q);   // bf16 view (layer 1, permuted)
    float*          Qf     = (float*)(ws + o_Q);            // fp32 view (layer 2, row-major)
    unsigned short* wl0b   = (unsigned short*)(ws + o_wl0);
    unsigned short* wr0b   = (unsigned short*)(ws + o_wr0);
    unsigned short* wl1b   = (unsigned short*)(ws + o_wl1);
    unsigned short* wr1b   = (unsigned short*)(ws + o_wr1);
    unsigned short* wl2b   = (unsigned short*)(ws + o_wl2);
    unsigned short* wr2b   = (unsigned short*)(ws + o_wr2);

    // zero nz/cnt/cursor (ws poisoned 0xAA before every call)
    int zn = (int)(zero_end / 4);
    zero_kernel<<<(zn + 255) / 256, 256, 0, stream>>>((int*)ws, zn);

    int eb = (E + 255) / 256;
    detect_kernel<<<1, 256, 0, stream>>>(e, nz, E);
    conv_count_kernel<<<eb, 256, 0, stream>>>(e, nz, src32, dst32, cnt, E);

    const int C = (N + 1023) / 1024;
    scan1_kernel<<<4, 256, 0, stream>>>(cnt, part, N, C);
    scan2_kernel<<<1, 1024, 0, stream>>>(part);
    scan3_kernel<<<4, 256, 0, stream>>>(cnt, part, offs, N, C, E);
    inv_kernel<<<(N + 255) / 256, 256, 0, stream>>>(cnt, inv, N);
    fill_kernel<<<eb, 256, 0, stream>>>(src32, dst32, offs, cursor, sorted, E);

    // conversions to bf16
    int n4 = N * 128 / 4;
    cvt_bf16_kernel<<<(n4 + 255) / 256, 256, 0, stream>>>(x, xb, n4);
    cvt_perm_kernel<<<(N * 64 + 255) / 256, 256, 0, stream>>>(x, xp, N);
    cvt_bf16_kernel<<<(512 * 128 / 4 + 255) / 256, 256, 0, stream>>>(Wl0, wl0b, 512 * 128 / 4);
    cvt_bf16_kernel<<<(512 * 128 / 4 + 255) / 256, 256, 0, stream>>>(Wr0, wr0b, 512 * 128 / 4);
    cvt_bf16_kernel<<<(512 * 512 / 4 + 255) / 256, 256, 0, stream>>>(Wl1, wl1b, 512 * 512 / 4);
    cvt_bf16_kernel<<<(512 * 512 / 4 + 255) / 256, 256, 0, stream>>>(Wr1, wr1b, 512 * 512 / 4);
    cvt_bf16_kernel<<<(256 * 512 / 4 + 255) / 256, 256, 0, stream>>>(Wl2, wl2b, 256 * 512 / 4);
    cvt_bf16_kernel<<<(256 * 512 / 4 + 255) / 256, 256, 0, stream>>>(Wr2, wr2b, 256 * 512 / 4);

    const int mBlocks = Mpad / 128;
    const int T = (N + 63) / 64;               // 64 nodes per tile (16/wave x 4 waves)

    // Layer 0: sliced gather of x (4 slices, 2 XCDs each), then SAGE GEMM.
    aggslice_v4<0><<<8 * ((T + 1) / 2), 256, 0, stream>>>(
        xp, nullptr, nullptr, sorted, offs, inv, aggx, nullptr, N, N, 0, 4, 128);
    sage_gemm_mfma<<<dim3(2, mBlocks), 256, 0, stream>>>(
        aggx, xb, wl0b, wr0b, bl0, hbuf, N, 512, 128);

    // Layer 1: GEMM-then-agg: P1/Q1 slice-permuted [16][Mpad][32];
    // h1 = relu(inv*sum P1[src] + Q1)  (two launches: slices 0-7, then 8-15)
    dual_gemm_mfma<<<dim3(4, mBlocks), 256, 0, stream>>>(
        hbuf, wl1b, wr1b, bl1, Pbuf, Qbuf, N, 512, 512, 0, Mpad);
    aggslice_v4<1><<<8 * T, 256, 0, stream>>>(
        Pbuf, Qbuf, nullptr, sorted, offs, inv, hbuf, nullptr, N, Mpad, 0, 8, 512);
    aggslice_v4<1><<<8 * T, 256, 0, stream>>>(
        Pbuf, Qbuf, nullptr, sorted, offs, inv, hbuf, nullptr, N, Mpad, 8, 8, 512);

    // Layer 2: GEMM-then-agg at 256-dim; P2 slice-permuted [8][Mpad][32],
    // Q2 fp32 row-major; out = inv*sum P2[src] + Q2 (fp32, no relu)
    dual_gemm_mfma<<<dim3(2, mBlocks), 256, 0, stream>>>(
        hbuf, wl2b, wr2b, bl2, Pbuf, (void*)Qf, N, 256, 512, 1, Mpad);
    aggslice_v4<2><<<8 * T, 256, 0, stream>>>(
        Pbuf, nullptr, Qf, sorted, offs, inv, nullptr, out, N, Mpad, 0, 8, 256);
}

// Round 6
// 643.030 us; speedup vs baseline: 1.6512x; 1.2378x over previous
//
#include <hip/hip_runtime.h>
#include <hip/hip_bf16.h>
#include <cstdint>
#include <cstddef>

static inline size_t align_up(size_t x, size_t a) { return (x + a - 1) & ~(a - 1); }

typedef __attribute__((ext_vector_type(4))) float f32x4;
typedef __attribute__((ext_vector_type(8))) short bf16x8;

__device__ inline float bf2f(unsigned int u16) {        // low 16 bits hold bf16
    return __uint_as_float(u16 << 16);
}
__device__ inline float bflo(unsigned int v) { return __uint_as_float(v << 16); }
__device__ inline float bfhi(unsigned int v) { return __uint_as_float(v & 0xffff0000u); }
__device__ inline unsigned short f2bf(float f) {        // round-to-nearest-even
    unsigned int u = __float_as_uint(f);
    u = (u + 0x7fffu + ((u >> 16) & 1u)) >> 16;
    return (unsigned short)u;
}

#define GLD_LDS(gp, lp) \
    __builtin_amdgcn_global_load_lds( \
        (const __attribute__((address_space(1))) unsigned int*)(gp), \
        (__attribute__((address_space(3))) unsigned int*)(lp), 16, 0, 0)

// ---------------------------------------------------------------------------
__global__ void zero_kernel(int* __restrict__ p, int n) {
    int i = blockIdx.x * 256 + threadIdx.x;
    if (i < n) p[i] = 0;
}

// Edge-encoding detection, single block, sampled, no atomics.
__global__ void detect_kernel(const int* __restrict__ e, int* __restrict__ nz, int E) {
    int t = threadIdx.x;  // 0..255, one block
    long long stride = (long long)E / 4096;
    if (stride < 1) stride = 1;
    int any = 0;
    for (int k = 0; k < 16; ++k) {
        long long idx = (long long)(t * 16 + k) * stride;
        if (idx < E && e[2 * idx + 1] != 0) any = 1;
    }
    if (any) nz[0] = 1;  // same-value race is benign
}

__global__ void conv_count_kernel(const int* __restrict__ eraw, const int* __restrict__ nz,
                                  int* __restrict__ src32, int* __restrict__ dst32,
                                  int* __restrict__ cnt, int E) {
    int i = blockIdx.x * blockDim.x + threadIdx.x;
    if (i >= E) return;
    int s, d;
    if (*nz == 0) {  // int64 storage
        const long long* e64 = (const long long*)eraw;
        s = (int)e64[i];
        d = (int)e64[i + E];
    } else {         // int32 storage
        s = eraw[i];
        d = eraw[i + E];
    }
    src32[i] = s;
    dst32[i] = d;
    atomicAdd(&cnt[d], 1);
}

// 3-kernel exclusive scan over cnt[0..n) -> offs[0..n]
__global__ void scan1_kernel(const int* __restrict__ cnt, int* __restrict__ partial,
                             int n, int C) {
    int t = blockIdx.x * 256 + threadIdx.x;  // 0..1023
    int s = 0;
    int base = t * C;
    for (int i = 0; i < C; ++i) {
        int idx = base + i;
        if (idx < n) s += cnt[idx];
    }
    partial[t] = s;
}

__global__ void __launch_bounds__(1024) scan2_kernel(int* __restrict__ partial) {
    __shared__ int sh[1024];
    int t = threadIdx.x;
    sh[t] = partial[t];
    __syncthreads();
    for (int off = 1; off < 1024; off <<= 1) {
        int v = (t >= off) ? sh[t - off] : 0;
        __syncthreads();
        sh[t] += v;
        __syncthreads();
    }
    partial[t] = (t == 0) ? 0 : sh[t - 1];  // exclusive
}

__global__ void scan3_kernel(const int* __restrict__ cnt, const int* __restrict__ partial,
                             int* __restrict__ offs, int n, int C, int E) {
    int t = blockIdx.x * 256 + threadIdx.x;
    int run = partial[t];
    int base = t * C;
    for (int i = 0; i < C; ++i) {
        int idx = base + i;
        if (idx < n) {
            offs[idx] = run;
            run += cnt[idx];
        }
    }
    if (t == 0) offs[n] = E;
}

__global__ void inv_kernel(const int* __restrict__ cnt, float* __restrict__ inv, int n) {
    int i = blockIdx.x * 256 + threadIdx.x;
    if (i < n) inv[i] = 1.0f / (float)max(cnt[i], 1);
}

__global__ void fill_kernel(const int* __restrict__ src32, const int* __restrict__ dst32,
                            const int* __restrict__ offs, int* __restrict__ cursor,
                            int* __restrict__ sorted, int E) {
    int i = blockIdx.x * 256 + threadIdx.x;
    if (i >= E) return;
    int d = dst32[i];
    int p = offs[d] + atomicAdd(&cursor[d], 1);
    sorted[p] = src32[i];
}

// fp32 -> bf16, vectorized x4
__global__ void cvt_bf16_kernel(const float* __restrict__ x, unsigned short* __restrict__ xb,
                                int n4) {
    int i = blockIdx.x * 256 + threadIdx.x;
    if (i >= n4) return;
    float4 v = *(const float4*)(x + (size_t)i * 4);
    uint2 o;
    o.x = (unsigned int)f2bf(v.x) | ((unsigned int)f2bf(v.y) << 16);
    o.y = (unsigned int)f2bf(v.z) | ((unsigned int)f2bf(v.w) << 16);
    *(uint2*)(xb + (size_t)i * 4) = o;
}

// ---------------------------------------------------------------------------
// Layer-0 aggregation: 128-dim row-major gather, row-major out. 8-edge unroll.
// Round-6: scalar remainder replaced with ONE masked 8-edge batch (the scalar
// tail was up to 7 serial MLP=1 latency chains per node; masked batch keeps
// MLP=8 on every node). Masked lanes add exact 0 -> identical sums.
// ---------------------------------------------------------------------------
__global__ void __launch_bounds__(256) agg128_kernel(
    const unsigned short* __restrict__ X, const int* __restrict__ srt,
    const int* __restrict__ offs, const float* __restrict__ invc,
    unsigned short* __restrict__ out, int nNodes) {
    int node = blockIdx.x * 4 + (threadIdx.x >> 6);
    if (node >= nNodes) return;
    int lane = threadIdx.x & 63;
    const unsigned short* xp = X + (size_t)lane * 2;
    int beg = offs[node], end = offs[node + 1];
    float sc = invc[node];
    float a0 = 0.f, a1 = 0.f;
    int e = beg;
    for (; e + 8 <= end; e += 8) {
        unsigned int v[8];
#pragma unroll
        for (int u = 0; u < 8; ++u)
            v[u] = *(const unsigned int*)(xp + (size_t)srt[e + u] * 128);
#pragma unroll
        for (int u = 0; u < 8; ++u) {
            a0 += bflo(v[u]);
            a1 += bfhi(v[u]);
        }
    }
    if (e < end) {  // masked final batch (no serial scalar tail)
        unsigned int v[8];
        float m[8];
#pragma unroll
        for (int u = 0; u < 8; ++u) {
            bool act = (e + u) < end;
            int idx = act ? srt[e + u] : srt[beg];
            m[u] = act ? 1.f : 0.f;
            v[u] = *(const unsigned int*)(xp + (size_t)idx * 128);
        }
#pragma unroll
        for (int u = 0; u < 8; ++u) {
            a0 = fmaf(bflo(v[u]), m[u], a0);
            a1 = fmaf(bfhi(v[u]), m[u], a1);
        }
    }
    unsigned int o = (unsigned int)f2bf(a0 * sc) | ((unsigned int)f2bf(a1 * sc) << 16);
    *(unsigned int*)(out + (size_t)node * 128 + lane * 2) = o;
}

// ---------------------------------------------------------------------------
// Fused aggregation + add + relu: out[dst] = relu(inv*sum P[src] + Q[dst]).
// D=512, 8-edge unroll + masked tail batch, one wave per node.
// (Row-gather structure: 1 KB/edge in one wave-wide uint4 load -> 6.9 TB/s
// effective logical BW through L2/L3; verified superior to 64 B slicing in
// rounds 1-5.)
// ---------------------------------------------------------------------------
__global__ void __launch_bounds__(256) aggfuse512_kernel(
    const unsigned short* __restrict__ P, const unsigned short* __restrict__ Q,
    const int* __restrict__ srt, const int* __restrict__ offs,
    const float* __restrict__ invc, unsigned short* __restrict__ out, int nNodes) {
    int node = blockIdx.x * 4 + (threadIdx.x >> 6);
    if (node >= nNodes) return;
    int lane = threadIdx.x & 63;
    const unsigned short* pp = P + (size_t)lane * 8;
    int beg = offs[node], end = offs[node + 1];
    float sc = invc[node];
    float a0 = 0.f, a1 = 0.f, a2 = 0.f, a3 = 0.f, a4 = 0.f, a5 = 0.f, a6 = 0.f, a7 = 0.f;
#define ACC8(v)                                \
    do {                                       \
        a0 += bflo((v).x);                     \
        a1 += bfhi((v).x);                     \
        a2 += bflo((v).y);                     \
        a3 += bfhi((v).y);                     \
        a4 += bflo((v).z);                     \
        a5 += bfhi((v).z);                     \
        a6 += bflo((v).w);                     \
        a7 += bfhi((v).w);                     \
    } while (0)
#define ACC8M(v, mm)                           \
    do {                                       \
        a0 = fmaf(bflo((v).x), (mm), a0);      \
        a1 = fmaf(bfhi((v).x), (mm), a1);      \
        a2 = fmaf(bflo((v).y), (mm), a2);      \
        a3 = fmaf(bfhi((v).y), (mm), a3);      \
        a4 = fmaf(bflo((v).z), (mm), a4);      \
        a5 = fmaf(bfhi((v).z), (mm), a5);      \
        a6 = fmaf(bflo((v).w), (mm), a6);      \
        a7 = fmaf(bfhi((v).w), (mm), a7);      \
    } while (0)
    int e = beg;
    for (; e + 8 <= end; e += 8) {
        uint4 v[8];
#pragma unroll
        for (int u = 0; u < 8; ++u)
            v[u] = *(const uint4*)(pp + (size_t)srt[e + u] * 512);
#pragma unroll
        for (int u = 0; u < 8; ++u) ACC8(v[u]);
    }
    if (e < end) {  // masked final batch (no serial scalar tail)
        uint4 v[8];
        float m[8];
#pragma unroll
        for (int u = 0; u < 8; ++u) {
            bool act = (e + u) < end;
            int idx = act ? srt[e + u] : srt[beg];
            m[u] = act ? 1.f : 0.f;
            v[u] = *(const uint4*)(pp + (size_t)idx * 512);
        }
#pragma unroll
        for (int u = 0; u < 8; ++u) ACC8M(v[u], m[u]);
    }
#undef ACC8
#undef ACC8M
    uint4 q = *(const uint4*)(Q + (size_t)node * 512 + lane * 8);
    float r0 = fmaxf(a0 * sc + bflo(q.x), 0.f);
    float r1 = fmaxf(a1 * sc + bfhi(q.x), 0.f);
    float r2 = fmaxf(a2 * sc + bflo(q.y), 0.f);
    float r3 = fmaxf(a3 * sc + bfhi(q.y), 0.f);
    float r4 = fmaxf(a4 * sc + bflo(q.z), 0.f);
    float r5 = fmaxf(a5 * sc + bfhi(q.z), 0.f);
    float r6 = fmaxf(a6 * sc + bflo(q.w), 0.f);
    float r7 = fmaxf(a7 * sc + bfhi(q.w), 0.f);
    uint4 o;
    o.x = (unsigned int)f2bf(r0) | ((unsigned int)f2bf(r1) << 16);
    o.y = (unsigned int)f2bf(r2) | ((unsigned int)f2bf(r3) << 16);
    o.z = (unsigned int)f2bf(r4) | ((unsigned int)f2bf(r5) << 16);
    o.w = (unsigned int)f2bf(r6) | ((unsigned int)f2bf(r7) << 16);
    *(uint4*)(out + (size_t)node * 512 + lane * 8) = o;
}

// D=256 variant, fp32 Q and fp32 out (final layer, no relu). 8-edge unroll +
// masked tail batch.
__global__ void __launch_bounds__(256) aggfuse256_kernel(
    const unsigned short* __restrict__ P, const float* __restrict__ Q,
    const int* __restrict__ srt, const int* __restrict__ offs,
    const float* __restrict__ invc, float* __restrict__ out, int nNodes) {
    int node = blockIdx.x * 4 + (threadIdx.x >> 6);
    if (node >= nNodes) return;
    int lane = threadIdx.x & 63;
    const unsigned short* pp = P + (size_t)lane * 4;
    int beg = offs[node], end = offs[node + 1];
    float sc = invc[node];
    float a0 = 0.f, a1 = 0.f, a2 = 0.f, a3 = 0.f;
#define ACC4(v)                              \
    do {                                     \
        a0 += bflo((v).x);                   \
        a1 += bfhi((v).x);                   \
        a2 += bflo((v).y);                   \
        a3 += bfhi((v).y);                   \
    } while (0)
#define ACC4M(v, mm)                         \
    do {                                     \
        a0 = fmaf(bflo((v).x), (mm), a0);    \
        a1 = fmaf(bfhi((v).x), (mm), a1);    \
        a2 = fmaf(bflo((v).y), (mm), a2);    \
        a3 = fmaf(bfhi((v).y), (mm), a3);    \
    } while (0)
    int e = beg;
    for (; e + 8 <= end; e += 8) {
        uint2 v[8];
#pragma unroll
        for (int u = 0; u < 8; ++u)
            v[u] = *(const uint2*)(pp + (size_t)srt[e + u] * 256);
#pragma unroll
        for (int u = 0; u < 8; ++u) ACC4(v[u]);
    }
    if (e < end) {  // masked final batch (no serial scalar tail)
        uint2 v[8];
        float m[8];
#pragma unroll
        for (int u = 0; u < 8; ++u) {
            bool act = (e + u) < end;
            int idx = act ? srt[e + u] : srt[beg];
            m[u] = act ? 1.f : 0.f;
            v[u] = *(const uint2*)(pp + (size_t)idx * 256);
        }
#pragma unroll
        for (int u = 0; u < 8; ++u) ACC4M(v[u], m[u]);
    }
#undef ACC4
#undef ACC4M
    float4 q = *(const float4*)(Q + (size_t)node * 256 + lane * 4);
    float4 r = make_float4(a0 * sc + q.x, a1 * sc + q.y, a2 * sc + q.z, a3 * sc + q.w);
    *(float4*)(out + (size_t)node * 256 + lane * 4) = r;
}

// ---------------------------------------------------------------------------
// Coalesced bf16 epilogue: per wave stage the 16x128 sub-tile column-major in
// LDS (stride 18 shorts: b32-aligned, <=4-way conflicts), read back row-major,
// store uint4 (8 bf16) -> 256 B contiguous per 16-lane group.
// ---------------------------------------------------------------------------
__device__ __forceinline__ void epilogue_bf16(
    f32x4 (&acc)[4][8], const float* bvj, int relu,
    unsigned short* smem, int wave, int lane,
    unsigned short* Cout, int m0, int n0, int wm, int wn, int M, int N) {
    unsigned short* stg = smem + wave * 2304;  // 128 cols * 18 shorts
    const int colc = lane & 15;
    const int rgrp = (lane >> 4) * 4;
    for (int i = 0; i < 4; ++i) {
        __syncthreads();
#pragma unroll
        for (int j = 0; j < 8; ++j) {
            float v0 = acc[i][j][0] + bvj[j];
            float v1 = acc[i][j][1] + bvj[j];
            float v2 = acc[i][j][2] + bvj[j];
            float v3 = acc[i][j][3] + bvj[j];
            if (relu) {
                v0 = fmaxf(v0, 0.f); v1 = fmaxf(v1, 0.f);
                v2 = fmaxf(v2, 0.f); v3 = fmaxf(v3, 0.f);
            }
            int c = j * 16 + colc;
            *(unsigned int*)&stg[c * 18 + rgrp] =
                (unsigned int)f2bf(v0) | ((unsigned int)f2bf(v1) << 16);
            *(unsigned int*)&stg[c * 18 + rgrp + 2] =
                (unsigned int)f2bf(v2) | ((unsigned int)f2bf(v3) << 16);
        }
        __syncthreads();
#pragma unroll
        for (int p = 0; p < 2; ++p) {
            int colg = lane & 15;                  // 8-col group
            int rp = p * 4 + (lane >> 4);          // row pair 0..7
            unsigned int w[8];
#pragma unroll
            for (int t = 0; t < 8; ++t)
                w[t] = *(const unsigned int*)&stg[(colg * 8 + t) * 18 + rp * 2];
            uint4 lo, hi;
            lo.x = (w[0] & 0xffffu) | (w[1] << 16);
            lo.y = (w[2] & 0xffffu) | (w[3] << 16);
            lo.z = (w[4] & 0xffffu) | (w[5] << 16);
            lo.w = (w[6] & 0xffffu) | (w[7] << 16);
            hi.x = (w[0] >> 16) | (w[1] & 0xffff0000u);
            hi.y = (w[2] >> 16) | (w[3] & 0xffff0000u);
            hi.z = (w[4] >> 16) | (w[5] & 0xffff0000u);
            hi.w = (w[6] >> 16) | (w[7] & 0xffff0000u);
            int mlo = m0 + wm * 64 + i * 16 + rp * 2;
            int n = n0 + wn * 128 + colg * 8;
            if (mlo < M)     *(uint4*)&Cout[(size_t)mlo * N + n] = lo;
            if (mlo + 1 < M) *(uint4*)&Cout[(size_t)(mlo + 1) * N + n] = hi;
        }
    }
}

// ---------------------------------------------------------------------------
// MFMA SAGE GEMM (layer 0): C = relu( Aagg @ Wl^T + Aself @ Wr^T + bias )
// Tile 128x256, BK=32, 4 waves of 4x8 frags. Coalesced bf16 epilogue.
// ---------------------------------------------------------------------------
__global__ void __launch_bounds__(256, 2) sage_gemm_mfma(
    const unsigned short* __restrict__ Aagg, const unsigned short* __restrict__ Aself,
    const unsigned short* __restrict__ Wlb, const unsigned short* __restrict__ Wrb,
    const float* __restrict__ bias, unsigned short* __restrict__ Cout,
    int M, int N, int K) {
    __shared__ __attribute__((aligned(16))) unsigned short smem[12288];  // 24 KB
    unsigned short* As = smem;            // 128*32
    unsigned short* Bs = smem + 4096;     // 256*32
    const int tid = threadIdx.x;
    const int lane = tid & 63;
    const int wave = tid >> 6;
    const int wm = wave >> 1, wn = wave & 1;
    const int m0 = blockIdx.y * 128, n0 = blockIdx.x * 256;

    f32x4 acc[4][8];
#pragma unroll
    for (int i = 0; i < 4; ++i)
#pragma unroll
        for (int j = 0; j < 8; ++j) acc[i][j] = (f32x4){0.f, 0.f, 0.f, 0.f};

    const int srow = wave * 16 + (lane >> 2);
    const int kE = (lane & 3) * 8;
    const int frow = lane & 15;
    const int kk = (lane >> 4) * 8;

    for (int pass = 0; pass < 2; ++pass) {
        const unsigned short* A = pass ? Aself : Aagg;
        const unsigned short* W = pass ? Wrb : Wlb;
        for (int k0 = 0; k0 < K; k0 += 32) {
            __syncthreads();
            GLD_LDS(A + (size_t)(m0 + 0 * 64 + srow) * K + k0 + kE, &As[0 * 2048 + wave * 512]);
            GLD_LDS(A + (size_t)(m0 + 1 * 64 + srow) * K + k0 + kE, &As[1 * 2048 + wave * 512]);
            GLD_LDS(W + (size_t)(n0 + 0 * 64 + srow) * K + k0 + kE, &Bs[0 * 2048 + wave * 512]);
            GLD_LDS(W + (size_t)(n0 + 1 * 64 + srow) * K + k0 + kE, &Bs[1 * 2048 + wave * 512]);
            GLD_LDS(W + (size_t)(n0 + 2 * 64 + srow) * K + k0 + kE, &Bs[2 * 2048 + wave * 512]);
            GLD_LDS(W + (size_t)(n0 + 3 * 64 + srow) * K + k0 + kE, &Bs[3 * 2048 + wave * 512]);
            __syncthreads();
            bf16x8 af[4], bfr[8];
#pragma unroll
            for (int t = 0; t < 4; ++t)
                af[t] = *(const bf16x8*)&As[(wm * 64 + t * 16 + frow) * 32 + kk];
#pragma unroll
            for (int t = 0; t < 8; ++t)
                bfr[t] = *(const bf16x8*)&Bs[(wn * 128 + t * 16 + frow) * 32 + kk];
#pragma unroll
            for (int i = 0; i < 4; ++i)
#pragma unroll
                for (int j = 0; j < 8; ++j)
                    acc[i][j] = __builtin_amdgcn_mfma_f32_16x16x32_bf16(
                        af[i], bfr[j], acc[i][j], 0, 0, 0);
        }
    }

    float bvj[8];
#pragma unroll
    for (int j = 0; j < 8; ++j) bvj[j] = bias[n0 + wn * 128 + j * 16 + (lane & 15)];
    epilogue_bf16(acc, bvj, 1, smem, wave, lane, Cout, m0, n0, wm, wn, M, N);
}

// ---------------------------------------------------------------------------
// Dual-output MFMA GEMM (layers 1-2): P = A@Wl^T ; Q = A@Wr^T + bias.
// grid.x covers 2N in 256-col blocks (first half P, second half Q).
// bf16 outputs via coalesced epilogue; fp32 Q direct (already coalesced).
// ---------------------------------------------------------------------------
__global__ void __launch_bounds__(256, 2) dual_gemm_mfma(
    const unsigned short* __restrict__ A,
    const unsigned short* __restrict__ Wlb, const unsigned short* __restrict__ Wrb,
    const float* __restrict__ bias, unsigned short* __restrict__ P,
    void* __restrict__ Q, int M, int N, int K, int q_fp32) {
    __shared__ __attribute__((aligned(16))) unsigned short smem[12288];  // 24 KB
    unsigned short* As = smem;
    unsigned short* Bs = smem + 4096;
    const int tid = threadIdx.x;
    const int lane = tid & 63;
    const int wave = tid >> 6;
    const int wm = wave >> 1, wn = wave & 1;
    const int m0 = blockIdx.y * 128;
    const int n0s = blockIdx.x * 256;          // in [0, 2N)
    const int isQ = n0s >= N;
    const int n0 = isQ ? n0s - N : n0s;
    const unsigned short* W = isQ ? Wrb : Wlb;

    f32x4 acc[4][8];
#pragma unroll
    for (int i = 0; i < 4; ++i)
#pragma unroll
        for (int j = 0; j < 8; ++j) acc[i][j] = (f32x4){0.f, 0.f, 0.f, 0.f};

    const int srow = wave * 16 + (lane >> 2);
    const int kE = (lane & 3) * 8;
    const int frow = lane & 15;
    const int kk = (lane >> 4) * 8;

    for (int k0 = 0; k0 < K; k0 += 32) {
        __syncthreads();
        GLD_LDS(A + (size_t)(m0 + 0 * 64 + srow) * K + k0 + kE, &As[0 * 2048 + wave * 512]);
        GLD_LDS(A + (size_t)(m0 + 1 * 64 + srow) * K + k0 + kE, &As[1 * 2048 + wave * 512]);
        GLD_LDS(W + (size_t)(n0 + 0 * 64 + srow) * K + k0 + kE, &Bs[0 * 2048 + wave * 512]);
        GLD_LDS(W + (size_t)(n0 + 1 * 64 + srow) * K + k0 + kE, &Bs[1 * 2048 + wave * 512]);
        GLD_LDS(W + (size_t)(n0 + 2 * 64 + srow) * K + k0 + kE, &Bs[2 * 2048 + wave * 512]);
        GLD_LDS(W + (size_t)(n0 + 3 * 64 + srow) * K + k0 + kE, &Bs[3 * 2048 + wave * 512]);
        __syncthreads();
        bf16x8 af[4], bfr[8];
#pragma unroll
        for (int t = 0; t < 4; ++t)
            af[t] = *(const bf16x8*)&As[(wm * 64 + t * 16 + frow) * 32 + kk];
#pragma unroll
        for (int t = 0; t < 8; ++t)
            bfr[t] = *(const bf16x8*)&Bs[(wn * 128 + t * 16 + frow) * 32 + kk];
#pragma unroll
        for (int i = 0; i < 4; ++i)
#pragma unroll
            for (int j = 0; j < 8; ++j)
                acc[i][j] = __builtin_amdgcn_mfma_f32_16x16x32_bf16(
                    af[i], bfr[j], acc[i][j], 0, 0, 0);
    }

    if (!isQ || !q_fp32) {
        float bvj[8];
#pragma unroll
        for (int j = 0; j < 8; ++j)
            bvj[j] = isQ ? bias[n0 + wn * 128 + j * 16 + (lane & 15)] : 0.f;
        unsigned short* Cout = isQ ? (unsigned short*)Q : P;
        epilogue_bf16(acc, bvj, 0, smem, wave, lane, Cout, m0, n0, wm, wn, M, N);
    } else {
        // fp32 Q: scalar stores are 64 B per quarter-wave -> already coalesced
        const int col = lane & 15;
        const int rgrp = (lane >> 4) * 4;
        float* Qf = (float*)Q;
#pragma unroll
        for (int j = 0; j < 8; ++j) {
            int n = n0 + wn * 128 + j * 16 + col;
            float bv = bias[n];
#pragma unroll
            for (int i = 0; i < 4; ++i) {
                int mBase = m0 + wm * 64 + i * 16 + rgrp;
#pragma unroll
                for (int r = 0; r < 4; ++r) {
                    int m = mBase + r;
                    if (m >= M) continue;
                    Qf[(size_t)m * N + n] = acc[i][j][r] + bv;
                }
            }
        }
    }
}

// ---------------------------------------------------------------------------
extern "C" void kernel_launch(void* const* d_in, const int* in_sizes, int n_in,
                              void* d_out, int out_size, void* d_ws, size_t ws_size,
                              hipStream_t stream) {
    const float* x   = (const float*)d_in[0];
    const int*   e   = (const int*)d_in[1];
    const float* Wl0 = (const float*)d_in[2];
    const float* bl0 = (const float*)d_in[3];
    const float* Wr0 = (const float*)d_in[4];
    const float* Wl1 = (const float*)d_in[5];
    const float* bl1 = (const float*)d_in[6];
    const float* Wr1 = (const float*)d_in[7];
    const float* Wl2 = (const float*)d_in[8];
    const float* bl2 = (const float*)d_in[9];
    const float* Wr2 = (const float*)d_in[10];
    float* out = (float*)d_out;

    const int N = in_sizes[0] / 128;           // 50000 nodes
    const int E = in_sizes[1] / 2;             // 800000 edges
    const int Mpad = ((N + 127) / 128) * 128;  // 50048: GEMM staging never OOB

    char* ws = (char*)d_ws;
    size_t off = 0;
    auto alloc = [&](size_t bytes) { size_t o = off; off = align_up(off + bytes, 512); return o; };

    size_t o_nz     = alloc(4);
    size_t o_cnt    = alloc((size_t)N * 4);
    size_t o_cursor = alloc((size_t)N * 4);
    size_t zero_end = off;                       // [0, zero_end) zeroed each call
    size_t o_part   = alloc(1024 * 4);
    size_t o_offs   = alloc((size_t)(N + 1) * 4);
    size_t o_inv    = alloc((size_t)N * 4);
    size_t o_src    = alloc((size_t)E * 4);
    size_t o_dst    = alloc((size_t)E * 4);
    size_t o_sort   = alloc((size_t)E * 4);
    size_t o_xb     = alloc((size_t)Mpad * 128 * 2);   // bf16 x row-major
    size_t o_aggx   = alloc((size_t)Mpad * 128 * 2);   // bf16 agg(x)
    size_t o_h      = alloc((size_t)Mpad * 512 * 2);   // h0, then h1
    size_t o_P      = alloc((size_t)Mpad * 512 * 2);   // P1 (512), then P2 (256)
    size_t o_Q      = alloc((size_t)Mpad * 512 * 2);   // Q1 bf16 (512), then Q2 fp32 (256)
    size_t o_wl0    = alloc((size_t)512 * 128 * 2);
    size_t o_wr0    = alloc((size_t)512 * 128 * 2);
    size_t o_wl1    = alloc((size_t)512 * 512 * 2);
    size_t o_wr1    = alloc((size_t)512 * 512 * 2);
    size_t o_wl2    = alloc((size_t)256 * 512 * 2);
    size_t o_wr2    = alloc((size_t)256 * 512 * 2);
    (void)ws_size; (void)n_in; (void)out_size;

    int*            nz     = (int*)(ws + o_nz);
    int*            cnt    = (int*)(ws + o_cnt);
    int*            cursor = (int*)(ws + o_cursor);
    int*            part   = (int*)(ws + o_part);
    int*            offs   = (int*)(ws + o_offs);
    float*          inv    = (float*)(ws + o_inv);
    int*            src32  = (int*)(ws + o_src);
    int*            dst32  = (int*)(ws + o_dst);
    int*            sorted = (int*)(ws + o_sort);
    unsigned short* xb     = (unsigned short*)(ws + o_xb);
    unsigned short* aggx   = (unsigned short*)(ws + o_aggx);
    unsigned short* hbuf   = (unsigned short*)(ws + o_h);
    unsigned short* Pbuf   = (unsigned short*)(ws + o_P);
    unsigned short* Qbuf   = (unsigned short*)(ws + o_Q);   // bf16 view (layer 1)
    float*          Qf     = (float*)(ws + o_Q);            // fp32 view (layer 2)
    unsigned short* wl0b   = (unsigned short*)(ws + o_wl0);
    unsigned short* wr0b   = (unsigned short*)(ws + o_wr0);
    unsigned short* wl1b   = (unsigned short*)(ws + o_wl1);
    unsigned short* wr1b   = (unsigned short*)(ws + o_wr1);
    unsigned short* wl2b   = (unsigned short*)(ws + o_wl2);
    unsigned short* wr2b   = (unsigned short*)(ws + o_wr2);

    // zero nz/cnt/cursor (ws poisoned 0xAA before every call)
    int zn = (int)(zero_end / 4);
    zero_kernel<<<(zn + 255) / 256, 256, 0, stream>>>((int*)ws, zn);

    int eb = (E + 255) / 256;
    detect_kernel<<<1, 256, 0, stream>>>(e, nz, E);
    conv_count_kernel<<<eb, 256, 0, stream>>>(e, nz, src32, dst32, cnt, E);

    const int C = (N + 1023) / 1024;
    scan1_kernel<<<4, 256, 0, stream>>>(cnt, part, N, C);
    scan2_kernel<<<1, 1024, 0, stream>>>(part);
    scan3_kernel<<<4, 256, 0, stream>>>(cnt, part, offs, N, C, E);
    inv_kernel<<<(N + 255) / 256, 256, 0, stream>>>(cnt, inv, N);
    fill_kernel<<<eb, 256, 0, stream>>>(src32, dst32, offs, cursor, sorted, E);

    // conversions to bf16
    int n4 = N * 128 / 4;
    cvt_bf16_kernel<<<(n4 + 255) / 256, 256, 0, stream>>>(x, xb, n4);
    cvt_bf16_kernel<<<(512 * 128 / 4 + 255) / 256, 256, 0, stream>>>(Wl0, wl0b, 512 * 128 / 4);
    cvt_bf16_kernel<<<(512 * 128 / 4 + 255) / 256, 256, 0, stream>>>(Wr0, wr0b, 512 * 128 / 4);
    cvt_bf16_kernel<<<(512 * 512 / 4 + 255) / 256, 256, 0, stream>>>(Wl1, wl1b, 512 * 512 / 4);
    cvt_bf16_kernel<<<(512 * 512 / 4 + 255) / 256, 256, 0, stream>>>(Wr1, wr1b, 512 * 512 / 4);
    cvt_bf16_kernel<<<(256 * 512 / 4 + 255) / 256, 256, 0, stream>>>(Wl2, wl2b, 256 * 512 / 4);
    cvt_bf16_kernel<<<(256 * 512 / 4 + 255) / 256, 256, 0, stream>>>(Wr2, wr2b, 256 * 512 / 4);

    const int aggBlocks = (N + 3) / 4;
    const int mBlocks = Mpad / 128;

    // Layer 0: agg-then-GEMM (aggregating 128-dim x is the cheap side).
    agg128_kernel<<<aggBlocks, 256, 0, stream>>>(xb, sorted, offs, inv, aggx, N);
    sage_gemm_mfma<<<dim3(2, mBlocks), 256, 0, stream>>>(
        aggx, xb, wl0b, wr0b, bl0, hbuf, N, 512, 128);

    // Layer 1: GEMM-then-agg: P1=h0@Wl1^T, Q1=h0@Wr1^T+bl1;
    // h1 = relu(inv*sum P1[src] + Q1)
    dual_gemm_mfma<<<dim3(4, mBlocks), 256, 0, stream>>>(
        hbuf, wl1b, wr1b, bl1, Pbuf, Qbuf, N, 512, 512, 0);
    aggfuse512_kernel<<<aggBlocks, 256, 0, stream>>>(
        Pbuf, Qbuf, sorted, offs, inv, hbuf, N);

    // Layer 2: GEMM-then-agg at 256-dim (gather halved vs agg-first);
    // out = inv*sum P2[src] + Q2 (fp32, no relu)
    dual_gemm_mfma<<<dim3(2, mBlocks), 256, 0, stream>>>(
        hbuf, wl2b, wr2b, bl2, Pbuf, (void*)Qf, N, 256, 512, 1);
    aggfuse256_kernel<<<aggBlocks, 256, 0, stream>>>(
        Pbuf, Qf, sorted, offs, inv, out, N);
}

// Round 7
// 630.775 us; speedup vs baseline: 1.6833x; 1.0194x over previous
//
#include <hip/hip_runtime.h>
#include <hip/hip_bf16.h>
#include <cstdint>
#include <cstddef>

static inline size_t align_up(size_t x, size_t a) { return (x + a - 1) & ~(a - 1); }

typedef __attribute__((ext_vector_type(4))) float f32x4;
typedef __attribute__((ext_vector_type(4))) unsigned int u32x4;
typedef __attribute__((ext_vector_type(8))) short bf16x8;

__device__ inline float bf2f(unsigned int u16) {        // low 16 bits hold bf16
    return __uint_as_float(u16 << 16);
}
__device__ inline float bflo(unsigned int v) { return __uint_as_float(v << 16); }
__device__ inline float bfhi(unsigned int v) { return __uint_as_float(v & 0xffff0000u); }
__device__ inline unsigned short f2bf(float f) {        // round-to-nearest-even
    unsigned int u = __float_as_uint(f);
    u = (u + 0x7fffu + ((u >> 16) & 1u)) >> 16;
    return (unsigned short)u;
}

#define GLD_LDS(gp, lp) \
    __builtin_amdgcn_global_load_lds( \
        (const __attribute__((address_space(1))) unsigned int*)(gp), \
        (__attribute__((address_space(3))) unsigned int*)(lp), 16, 0, 0)

// ---------------------------------------------------------------------------
__global__ void zero_kernel(int* __restrict__ p, int n) {
    int i = blockIdx.x * 256 + threadIdx.x;
    if (i < n) p[i] = 0;
}

// Edge-encoding detection, single block, sampled, no atomics.
__global__ void detect_kernel(const int* __restrict__ e, int* __restrict__ nz, int E) {
    int t = threadIdx.x;  // 0..255, one block
    long long stride = (long long)E / 4096;
    if (stride < 1) stride = 1;
    int any = 0;
    for (int k = 0; k < 16; ++k) {
        long long idx = (long long)(t * 16 + k) * stride;
        if (idx < E && e[2 * idx + 1] != 0) any = 1;
    }
    if (any) nz[0] = 1;  // same-value race is benign
}

__global__ void conv_count_kernel(const int* __restrict__ eraw, const int* __restrict__ nz,
                                  int* __restrict__ src32, int* __restrict__ dst32,
                                  int* __restrict__ cnt, int E) {
    int i = blockIdx.x * blockDim.x + threadIdx.x;
    if (i >= E) return;
    int s, d;
    if (*nz == 0) {  // int64 storage
        const long long* e64 = (const long long*)eraw;
        s = (int)e64[i];
        d = (int)e64[i + E];
    } else {         // int32 storage
        s = eraw[i];
        d = eraw[i + E];
    }
    src32[i] = s;
    dst32[i] = d;
    atomicAdd(&cnt[d], 1);
}

// 3-kernel exclusive scan over cnt[0..n) -> offs[0..n]
__global__ void scan1_kernel(const int* __restrict__ cnt, int* __restrict__ partial,
                             int n, int C) {
    int t = blockIdx.x * 256 + threadIdx.x;  // 0..1023
    int s = 0;
    int base = t * C;
    for (int i = 0; i < C; ++i) {
        int idx = base + i;
        if (idx < n) s += cnt[idx];
    }
    partial[t] = s;
}

__global__ void __launch_bounds__(1024) scan2_kernel(int* __restrict__ partial) {
    __shared__ int sh[1024];
    int t = threadIdx.x;
    sh[t] = partial[t];
    __syncthreads();
    for (int off = 1; off < 1024; off <<= 1) {
        int v = (t >= off) ? sh[t - off] : 0;
        __syncthreads();
        sh[t] += v;
        __syncthreads();
    }
    partial[t] = (t == 0) ? 0 : sh[t - 1];  // exclusive
}

__global__ void scan3_kernel(const int* __restrict__ cnt, const int* __restrict__ partial,
                             int* __restrict__ offs, int n, int C, int E) {
    int t = blockIdx.x * 256 + threadIdx.x;
    int run = partial[t];
    int base = t * C;
    for (int i = 0; i < C; ++i) {
        int idx = base + i;
        if (idx < n) {
            offs[idx] = run;
            run += cnt[idx];
        }
    }
    if (t == 0) offs[n] = E;
}

__global__ void inv_kernel(const int* __restrict__ cnt, float* __restrict__ inv, int n) {
    int i = blockIdx.x * 256 + threadIdx.x;
    if (i < n) inv[i] = 1.0f / (float)max(cnt[i], 1);
}

__global__ void fill_kernel(const int* __restrict__ src32, const int* __restrict__ dst32,
                            const int* __restrict__ offs, int* __restrict__ cursor,
                            int* __restrict__ sorted, int E) {
    int i = blockIdx.x * 256 + threadIdx.x;
    if (i >= E) return;
    int d = dst32[i];
    int p = offs[d] + atomicAdd(&cursor[d], 1);
    sorted[p] = src32[i];
}

// fp32 -> bf16, vectorized x4
__global__ void cvt_bf16_kernel(const float* __restrict__ x, unsigned short* __restrict__ xb,
                                int n4) {
    int i = blockIdx.x * 256 + threadIdx.x;
    if (i >= n4) return;
    float4 v = *(const float4*)(x + (size_t)i * 4);
    uint2 o;
    o.x = (unsigned int)f2bf(v.x) | ((unsigned int)f2bf(v.y) << 16);
    o.y = (unsigned int)f2bf(v.z) | ((unsigned int)f2bf(v.w) << 16);
    *(uint2*)(xb + (size_t)i * 4) = o;
}

// ---------------------------------------------------------------------------
// Aggregation kernels (round-7).
// Regime (r0 vs r6 A/B): aggfuse512 is throughput-bound on the beyond-L2
// fetch path at ~3.8 TB/s — dur tracks FETCH bytes exactly (451MB/118.8us vs
// 476MB/126.0us). So: (1) tails use binary 4/2/1 decomposition — exact edge
// bytes (masked-8 added redundant gathers = +5.5% bytes = +6.1% time), <=3
// serial mini-batches; (2) single-use streams (Q read-once, out write-once)
// are NON-TEMPORAL so they don't L2-allocate and evict the hot P rows that
// the 819MB logical gather re-reads. srt stays cached (each 128B line serves
// 4 consecutive batches — r2 lesson).
// ---------------------------------------------------------------------------
__global__ void __launch_bounds__(256) agg128_kernel(
    const unsigned short* __restrict__ X, const int* __restrict__ srt,
    const int* __restrict__ offs, const float* __restrict__ invc,
    unsigned short* __restrict__ out, int nNodes) {
    int node = blockIdx.x * 4 + (threadIdx.x >> 6);
    if (node >= nNodes) return;
    int lane = threadIdx.x & 63;
    const unsigned short* xp = X + (size_t)lane * 2;
    int beg = offs[node], end = offs[node + 1];
    float sc = invc[node];
    float a0 = 0.f, a1 = 0.f;
    int e = beg;
    for (; e + 8 <= end; e += 8) {
        unsigned int v[8];
#pragma unroll
        for (int u = 0; u < 8; ++u)
            v[u] = *(const unsigned int*)(xp + (size_t)srt[e + u] * 128);
#pragma unroll
        for (int u = 0; u < 8; ++u) {
            a0 += bflo(v[u]);
            a1 += bfhi(v[u]);
        }
    }
    int r = end - e;
    if (r & 4) {
        unsigned int v[4];
#pragma unroll
        for (int u = 0; u < 4; ++u)
            v[u] = *(const unsigned int*)(xp + (size_t)srt[e + u] * 128);
#pragma unroll
        for (int u = 0; u < 4; ++u) { a0 += bflo(v[u]); a1 += bfhi(v[u]); }
        e += 4;
    }
    if (r & 2) {
        unsigned int v[2];
#pragma unroll
        for (int u = 0; u < 2; ++u)
            v[u] = *(const unsigned int*)(xp + (size_t)srt[e + u] * 128);
#pragma unroll
        for (int u = 0; u < 2; ++u) { a0 += bflo(v[u]); a1 += bfhi(v[u]); }
        e += 2;
    }
    if (r & 1) {
        unsigned int v = *(const unsigned int*)(xp + (size_t)srt[e] * 128);
        a0 += bflo(v);
        a1 += bfhi(v);
    }
    unsigned int o = (unsigned int)f2bf(a0 * sc) | ((unsigned int)f2bf(a1 * sc) << 16);
    __builtin_nontemporal_store(o, (unsigned int*)(out + (size_t)node * 128 + lane * 2));
}

// ---------------------------------------------------------------------------
// Fused aggregation + add + relu: out[dst] = relu(inv*sum P[src] + Q[dst]).
// D=512, 8-edge unroll + binary tail, one wave per node. Row-gather (1 KB/edge
// wave-wide) proven superior to 64 B slicing in rounds 1-5.
// ---------------------------------------------------------------------------
__global__ void __launch_bounds__(256) aggfuse512_kernel(
    const unsigned short* __restrict__ P, const unsigned short* __restrict__ Q,
    const int* __restrict__ srt, const int* __restrict__ offs,
    const float* __restrict__ invc, unsigned short* __restrict__ out, int nNodes) {
    int node = blockIdx.x * 4 + (threadIdx.x >> 6);
    if (node >= nNodes) return;
    int lane = threadIdx.x & 63;
    const unsigned short* pp = P + (size_t)lane * 8;
    int beg = offs[node], end = offs[node + 1];
    float sc = invc[node];
    float a0 = 0.f, a1 = 0.f, a2 = 0.f, a3 = 0.f, a4 = 0.f, a5 = 0.f, a6 = 0.f, a7 = 0.f;
#define ACC8(v)                                \
    do {                                       \
        a0 += bflo((v).x);                     \
        a1 += bfhi((v).x);                     \
        a2 += bflo((v).y);                     \
        a3 += bfhi((v).y);                     \
        a4 += bflo((v).z);                     \
        a5 += bfhi((v).z);                     \
        a6 += bflo((v).w);                     \
        a7 += bfhi((v).w);                     \
    } while (0)
    int e = beg;
    for (; e + 8 <= end; e += 8) {
        uint4 v[8];
#pragma unroll
        for (int u = 0; u < 8; ++u)
            v[u] = *(const uint4*)(pp + (size_t)srt[e + u] * 512);
#pragma unroll
        for (int u = 0; u < 8; ++u) ACC8(v[u]);
    }
    int r = end - e;
    if (r & 4) {
        uint4 v[4];
#pragma unroll
        for (int u = 0; u < 4; ++u)
            v[u] = *(const uint4*)(pp + (size_t)srt[e + u] * 512);
#pragma unroll
        for (int u = 0; u < 4; ++u) ACC8(v[u]);
        e += 4;
    }
    if (r & 2) {
        uint4 v[2];
#pragma unroll
        for (int u = 0; u < 2; ++u)
            v[u] = *(const uint4*)(pp + (size_t)srt[e + u] * 512);
#pragma unroll
        for (int u = 0; u < 2; ++u) ACC8(v[u]);
        e += 2;
    }
    if (r & 1) {
        uint4 v = *(const uint4*)(pp + (size_t)srt[e] * 512);
        ACC8(v);
    }
#undef ACC8
    u32x4 q = __builtin_nontemporal_load(
        (const u32x4*)(Q + (size_t)node * 512 + lane * 8));
    float r0 = fmaxf(a0 * sc + bflo(q.x), 0.f);
    float r1 = fmaxf(a1 * sc + bfhi(q.x), 0.f);
    float r2 = fmaxf(a2 * sc + bflo(q.y), 0.f);
    float r3 = fmaxf(a3 * sc + bfhi(q.y), 0.f);
    float r4 = fmaxf(a4 * sc + bflo(q.z), 0.f);
    float r5 = fmaxf(a5 * sc + bfhi(q.z), 0.f);
    float r6 = fmaxf(a6 * sc + bflo(q.w), 0.f);
    float r7 = fmaxf(a7 * sc + bfhi(q.w), 0.f);
    u32x4 o;
    o.x = (unsigned int)f2bf(r0) | ((unsigned int)f2bf(r1) << 16);
    o.y = (unsigned int)f2bf(r2) | ((unsigned int)f2bf(r3) << 16);
    o.z = (unsigned int)f2bf(r4) | ((unsigned int)f2bf(r5) << 16);
    o.w = (unsigned int)f2bf(r6) | ((unsigned int)f2bf(r7) << 16);
    __builtin_nontemporal_store(o, (u32x4*)(out + (size_t)node * 512 + lane * 8));
}

// D=256 variant, fp32 Q and fp32 out (final layer, no relu). 8-edge unroll +
// binary tail; nt Q/out.
__global__ void __launch_bounds__(256) aggfuse256_kernel(
    const unsigned short* __restrict__ P, const float* __restrict__ Q,
    const int* __restrict__ srt, const int* __restrict__ offs,
    const float* __restrict__ invc, float* __restrict__ out, int nNodes) {
    int node = blockIdx.x * 4 + (threadIdx.x >> 6);
    if (node >= nNodes) return;
    int lane = threadIdx.x & 63;
    const unsigned short* pp = P + (size_t)lane * 4;
    int beg = offs[node], end = offs[node + 1];
    float sc = invc[node];
    float a0 = 0.f, a1 = 0.f, a2 = 0.f, a3 = 0.f;
#define ACC4(v)                              \
    do {                                     \
        a0 += bflo((v).x);                   \
        a1 += bfhi((v).x);                   \
        a2 += bflo((v).y);                   \
        a3 += bfhi((v).y);                   \
    } while (0)
    int e = beg;
    for (; e + 8 <= end; e += 8) {
        uint2 v[8];
#pragma unroll
        for (int u = 0; u < 8; ++u)
            v[u] = *(const uint2*)(pp + (size_t)srt[e + u] * 256);
#pragma unroll
        for (int u = 0; u < 8; ++u) ACC4(v[u]);
    }
    int r = end - e;
    if (r & 4) {
        uint2 v[4];
#pragma unroll
        for (int u = 0; u < 4; ++u)
            v[u] = *(const uint2*)(pp + (size_t)srt[e + u] * 256);
#pragma unroll
        for (int u = 0; u < 4; ++u) ACC4(v[u]);
        e += 4;
    }
    if (r & 2) {
        uint2 v[2];
#pragma unroll
        for (int u = 0; u < 2; ++u)
            v[u] = *(const uint2*)(pp + (size_t)srt[e + u] * 256);
#pragma unroll
        for (int u = 0; u < 2; ++u) ACC4(v[u]);
        e += 2;
    }
    if (r & 1) {
        uint2 v = *(const uint2*)(pp + (size_t)srt[e] * 256);
        ACC4(v);
    }
#undef ACC4
    f32x4 q = __builtin_nontemporal_load(
        (const f32x4*)(Q + (size_t)node * 256 + lane * 4));
    f32x4 rr;
    rr.x = a0 * sc + q.x;
    rr.y = a1 * sc + q.y;
    rr.z = a2 * sc + q.z;
    rr.w = a3 * sc + q.w;
    __builtin_nontemporal_store(rr, (f32x4*)(out + (size_t)node * 256 + lane * 4));
}

// ---------------------------------------------------------------------------
// Coalesced bf16 epilogue: per wave stage the 16x128 sub-tile column-major in
// LDS (stride 18 shorts: b32-aligned, <=4-way conflicts), read back row-major,
// store uint4 (8 bf16) -> 256 B contiguous per 16-lane group.
// ---------------------------------------------------------------------------
__device__ __forceinline__ void epilogue_bf16(
    f32x4 (&acc)[4][8], const float* bvj, int relu,
    unsigned short* smem, int wave, int lane,
    unsigned short* Cout, int m0, int n0, int wm, int wn, int M, int N) {
    unsigned short* stg = smem + wave * 2304;  // 128 cols * 18 shorts
    const int colc = lane & 15;
    const int rgrp = (lane >> 4) * 4;
    for (int i = 0; i < 4; ++i) {
        __syncthreads();
#pragma unroll
        for (int j = 0; j < 8; ++j) {
            float v0 = acc[i][j][0] + bvj[j];
            float v1 = acc[i][j][1] + bvj[j];
            float v2 = acc[i][j][2] + bvj[j];
            float v3 = acc[i][j][3] + bvj[j];
            if (relu) {
                v0 = fmaxf(v0, 0.f); v1 = fmaxf(v1, 0.f);
                v2 = fmaxf(v2, 0.f); v3 = fmaxf(v3, 0.f);
            }
            int c = j * 16 + colc;
            *(unsigned int*)&stg[c * 18 + rgrp] =
                (unsigned int)f2bf(v0) | ((unsigned int)f2bf(v1) << 16);
            *(unsigned int*)&stg[c * 18 + rgrp + 2] =
                (unsigned int)f2bf(v2) | ((unsigned int)f2bf(v3) << 16);
        }
        __syncthreads();
#pragma unroll
        for (int p = 0; p < 2; ++p) {
            int colg = lane & 15;                  // 8-col group
            int rp = p * 4 + (lane >> 4);          // row pair 0..7
            unsigned int w[8];
#pragma unroll
            for (int t = 0; t < 8; ++t)
                w[t] = *(const unsigned int*)&stg[(colg * 8 + t) * 18 + rp * 2];
            uint4 lo, hi;
            lo.x = (w[0] & 0xffffu) | (w[1] << 16);
            lo.y = (w[2] & 0xffffu) | (w[3] << 16);
            lo.z = (w[4] & 0xffffu) | (w[5] << 16);
            lo.w = (w[6] & 0xffffu) | (w[7] << 16);
            hi.x = (w[0] >> 16) | (w[1] & 0xffff0000u);
            hi.y = (w[2] >> 16) | (w[3] & 0xffff0000u);
            hi.z = (w[4] >> 16) | (w[5] & 0xffff0000u);
            hi.w = (w[6] >> 16) | (w[7] & 0xffff0000u);
            int mlo = m0 + wm * 64 + i * 16 + rp * 2;
            int n = n0 + wn * 128 + colg * 8;
            if (mlo < M)     *(uint4*)&Cout[(size_t)mlo * N + n] = lo;
            if (mlo + 1 < M) *(uint4*)&Cout[(size_t)(mlo + 1) * N + n] = hi;
        }
    }
}

// ---------------------------------------------------------------------------
// MFMA SAGE GEMM (layer 0): C = relu( Aagg @ Wl^T + Aself @ Wr^T + bias )
// Tile 128x256, BK=32, 4 waves of 4x8 frags. Coalesced bf16 epilogue.
// ---------------------------------------------------------------------------
__global__ void __launch_bounds__(256, 2) sage_gemm_mfma(
    const unsigned short* __restrict__ Aagg, const unsigned short* __restrict__ Aself,
    const unsigned short* __restrict__ Wlb, const unsigned short* __restrict__ Wrb,
    const float* __restrict__ bias, unsigned short* __restrict__ Cout,
    int M, int N, int K) {
    __shared__ __attribute__((aligned(16))) unsigned short smem[12288];  // 24 KB
    unsigned short* As = smem;            // 128*32
    unsigned short* Bs = smem + 4096;     // 256*32
    const int tid = threadIdx.x;
    const int lane = tid & 63;
    const int wave = tid >> 6;
    const int wm = wave >> 1, wn = wave & 1;
    const int m0 = blockIdx.y * 128, n0 = blockIdx.x * 256;

    f32x4 acc[4][8];
#pragma unroll
    for (int i = 0; i < 4; ++i)
#pragma unroll
        for (int j = 0; j < 8; ++j) acc[i][j] = (f32x4){0.f, 0.f, 0.f, 0.f};

    const int srow = wave * 16 + (lane >> 2);
    const int kE = (lane & 3) * 8;
    const int frow = lane & 15;
    const int kk = (lane >> 4) * 8;

    for (int pass = 0; pass < 2; ++pass) {
        const unsigned short* A = pass ? Aself : Aagg;
        const unsigned short* W = pass ? Wrb : Wlb;
        for (int k0 = 0; k0 < K; k0 += 32) {
            __syncthreads();
            GLD_LDS(A + (size_t)(m0 + 0 * 64 + srow) * K + k0 + kE, &As[0 * 2048 + wave * 512]);
            GLD_LDS(A + (size_t)(m0 + 1 * 64 + srow) * K + k0 + kE, &As[1 * 2048 + wave * 512]);
            GLD_LDS(W + (size_t)(n0 + 0 * 64 + srow) * K + k0 + kE, &Bs[0 * 2048 + wave * 512]);
            GLD_LDS(W + (size_t)(n0 + 1 * 64 + srow) * K + k0 + kE, &Bs[1 * 2048 + wave * 512]);
            GLD_LDS(W + (size_t)(n0 + 2 * 64 + srow) * K + k0 + kE, &Bs[2 * 2048 + wave * 512]);
            GLD_LDS(W + (size_t)(n0 + 3 * 64 + srow) * K + k0 + kE, &Bs[3 * 2048 + wave * 512]);
            __syncthreads();
            bf16x8 af[4], bfr[8];
#pragma unroll
            for (int t = 0; t < 4; ++t)
                af[t] = *(const bf16x8*)&As[(wm * 64 + t * 16 + frow) * 32 + kk];
#pragma unroll
            for (int t = 0; t < 8; ++t)
                bfr[t] = *(const bf16x8*)&Bs[(wn * 128 + t * 16 + frow) * 32 + kk];
#pragma unroll
            for (int i = 0; i < 4; ++i)
#pragma unroll
                for (int j = 0; j < 8; ++j)
                    acc[i][j] = __builtin_amdgcn_mfma_f32_16x16x32_bf16(
                        af[i], bfr[j], acc[i][j], 0, 0, 0);
        }
    }

    float bvj[8];
#pragma unroll
    for (int j = 0; j < 8; ++j) bvj[j] = bias[n0 + wn * 128 + j * 16 + (lane & 15)];
    epilogue_bf16(acc, bvj, 1, smem, wave, lane, Cout, m0, n0, wm, wn, M, N);
}

// ---------------------------------------------------------------------------
// Dual-output MFMA GEMM (layers 1-2): P = A@Wl^T ; Q = A@Wr^T + bias.
// grid.x covers 2N in 256-col blocks (first half P, second half Q).
// bf16 outputs via coalesced epilogue; fp32 Q direct (already coalesced).
// ---------------------------------------------------------------------------
__global__ void __launch_bounds__(256, 2) dual_gemm_mfma(
    const unsigned short* __restrict__ A,
    const unsigned short* __restrict__ Wlb, const unsigned short* __restrict__ Wrb,
    const float* __restrict__ bias, unsigned short* __restrict__ P,
    void* __restrict__ Q, int M, int N, int K, int q_fp32) {
    __shared__ __attribute__((aligned(16))) unsigned short smem[12288];  // 24 KB
    unsigned short* As = smem;
    unsigned short* Bs = smem + 4096;
    const int tid = threadIdx.x;
    const int lane = tid & 63;
    const int wave = tid >> 6;
    const int wm = wave >> 1, wn = wave & 1;
    const int m0 = blockIdx.y * 128;
    const int n0s = blockIdx.x * 256;          // in [0, 2N)
    const int isQ = n0s >= N;
    const int n0 = isQ ? n0s - N : n0s;
    const unsigned short* W = isQ ? Wrb : Wlb;

    f32x4 acc[4][8];
#pragma unroll
    for (int i = 0; i < 4; ++i)
#pragma unroll
        for (int j = 0; j < 8; ++j) acc[i][j] = (f32x4){0.f, 0.f, 0.f, 0.f};

    const int srow = wave * 16 + (lane >> 2);
    const int kE = (lane & 3) * 8;
    const int frow = lane & 15;
    const int kk = (lane >> 4) * 8;

    for (int k0 = 0; k0 < K; k0 += 32) {
        __syncthreads();
        GLD_LDS(A + (size_t)(m0 + 0 * 64 + srow) * K + k0 + kE, &As[0 * 2048 + wave * 512]);
        GLD_LDS(A + (size_t)(m0 + 1 * 64 + srow) * K + k0 + kE, &As[1 * 2048 + wave * 512]);
        GLD_LDS(W + (size_t)(n0 + 0 * 64 + srow) * K + k0 + kE, &Bs[0 * 2048 + wave * 512]);
        GLD_LDS(W + (size_t)(n0 + 1 * 64 + srow) * K + k0 + kE, &Bs[1 * 2048 + wave * 512]);
        GLD_LDS(W + (size_t)(n0 + 2 * 64 + srow) * K + k0 + kE, &Bs[2 * 2048 + wave * 512]);
        GLD_LDS(W + (size_t)(n0 + 3 * 64 + srow) * K + k0 + kE, &Bs[3 * 2048 + wave * 512]);
        __syncthreads();
        bf16x8 af[4], bfr[8];
#pragma unroll
        for (int t = 0; t < 4; ++t)
            af[t] = *(const bf16x8*)&As[(wm * 64 + t * 16 + frow) * 32 + kk];
#pragma unroll
        for (int t = 0; t < 8; ++t)
            bfr[t] = *(const bf16x8*)&Bs[(wn * 128 + t * 16 + frow) * 32 + kk];
#pragma unroll
        for (int i = 0; i < 4; ++i)
#pragma unroll
            for (int j = 0; j < 8; ++j)
                acc[i][j] = __builtin_amdgcn_mfma_f32_16x16x32_bf16(
                    af[i], bfr[j], acc[i][j], 0, 0, 0);
    }

    if (!isQ || !q_fp32) {
        float bvj[8];
#pragma unroll
        for (int j = 0; j < 8; ++j)
            bvj[j] = isQ ? bias[n0 + wn * 128 + j * 16 + (lane & 15)] : 0.f;
        unsigned short* Cout = isQ ? (unsigned short*)Q : P;
        epilogue_bf16(acc, bvj, 0, smem, wave, lane, Cout, m0, n0, wm, wn, M, N);
    } else {
        // fp32 Q: scalar stores are 64 B per quarter-wave -> already coalesced
        const int col = lane & 15;
        const int rgrp = (lane >> 4) * 4;
        float* Qf = (float*)Q;
#pragma unroll
        for (int j = 0; j < 8; ++j) {
            int n = n0 + wn * 128 + j * 16 + col;
            float bv = bias[n];
#pragma unroll
            for (int i = 0; i < 4; ++i) {
                int mBase = m0 + wm * 64 + i * 16 + rgrp;
#pragma unroll
                for (int r = 0; r < 4; ++r) {
                    int m = mBase + r;
                    if (m >= M) continue;
                    Qf[(size_t)m * N + n] = acc[i][j][r] + bv;
                }
            }
        }
    }
}

// ---------------------------------------------------------------------------
extern "C" void kernel_launch(void* const* d_in, const int* in_sizes, int n_in,
                              void* d_out, int out_size, void* d_ws, size_t ws_size,
                              hipStream_t stream) {
    const float* x   = (const float*)d_in[0];
    const int*   e   = (const int*)d_in[1];
    const float* Wl0 = (const float*)d_in[2];
    const float* bl0 = (const float*)d_in[3];
    const float* Wr0 = (const float*)d_in[4];
    const float* Wl1 = (const float*)d_in[5];
    const float* bl1 = (const float*)d_in[6];
    const float* Wr1 = (const float*)d_in[7];
    const float* Wl2 = (const float*)d_in[8];
    const float* bl2 = (const float*)d_in[9];
    const float* Wr2 = (const float*)d_in[10];
    float* out = (float*)d_out;

    const int N = in_sizes[0] / 128;           // 50000 nodes
    const int E = in_sizes[1] / 2;             // 800000 edges
    const int Mpad = ((N + 127) / 128) * 128;  // 50048: GEMM staging never OOB

    char* ws = (char*)d_ws;
    size_t off = 0;
    auto alloc = [&](size_t bytes) { size_t o = off; off = align_up(off + bytes, 512); return o; };

    size_t o_nz     = alloc(4);
    size_t o_cnt    = alloc((size_t)N * 4);
    size_t o_cursor = alloc((size_t)N * 4);
    size_t zero_end = off;                       // [0, zero_end) zeroed each call
    size_t o_part   = alloc(1024 * 4);
    size_t o_offs   = alloc((size_t)(N + 1) * 4);
    size_t o_inv    = alloc((size_t)N * 4);
    size_t o_src    = alloc((size_t)E * 4);
    size_t o_dst    = alloc((size_t)E * 4);
    size_t o_sort   = alloc((size_t)E * 4);
    size_t o_xb     = alloc((size_t)Mpad * 128 * 2);   // bf16 x row-major
    size_t o_aggx   = alloc((size_t)Mpad * 128 * 2);   // bf16 agg(x)
    size_t o_h      = alloc((size_t)Mpad * 512 * 2);   // h0, then h1
    size_t o_P      = alloc((size_t)Mpad * 512 * 2);   // P1 (512), then P2 (256)
    size_t o_Q      = alloc((size_t)Mpad * 512 * 2);   // Q1 bf16 (512), then Q2 fp32 (256)
    size_t o_wl0    = alloc((size_t)512 * 128 * 2);
    size_t o_wr0    = alloc((size_t)512 * 128 * 2);
    size_t o_wl1    = alloc((size_t)512 * 512 * 2);
    size_t o_wr1    = alloc((size_t)512 * 512 * 2);
    size_t o_wl2    = alloc((size_t)256 * 512 * 2);
    size_t o_wr2    = alloc((size_t)256 * 512 * 2);
    (void)ws_size; (void)n_in; (void)out_size;

    int*            nz     = (int*)(ws + o_nz);
    int*            cnt    = (int*)(ws + o_cnt);
    int*            cursor = (int*)(ws + o_cursor);
    int*            part   = (int*)(ws + o_part);
    int*            offs   = (int*)(ws + o_offs);
    float*          inv    = (float*)(ws + o_inv);
    int*            src32  = (int*)(ws + o_src);
    int*            dst32  = (int*)(ws + o_dst);
    int*            sorted = (int*)(ws + o_sort);
    unsigned short* xb     = (unsigned short*)(ws + o_xb);
    unsigned short* aggx   = (unsigned short*)(ws + o_aggx);
    unsigned short* hbuf   = (unsigned short*)(ws + o_h);
    unsigned short* Pbuf   = (unsigned short*)(ws + o_P);
    unsigned short* Qbuf   = (unsigned short*)(ws + o_Q);   // bf16 view (layer 1)
    float*          Qf     = (float*)(ws + o_Q);            // fp32 view (layer 2)
    unsigned short* wl0b   = (unsigned short*)(ws + o_wl0);
    unsigned short* wr0b   = (unsigned short*)(ws + o_wr0);
    unsigned short* wl1b   = (unsigned short*)(ws + o_wl1);
    unsigned short* wr1b   = (unsigned short*)(ws + o_wr1);
    unsigned short* wl2b   = (unsigned short*)(ws + o_wl2);
    unsigned short* wr2b   = (unsigned short*)(ws + o_wr2);

    // zero nz/cnt/cursor (ws poisoned 0xAA before every call)
    int zn = (int)(zero_end / 4);
    zero_kernel<<<(zn + 255) / 256, 256, 0, stream>>>((int*)ws, zn);

    int eb = (E + 255) / 256;
    detect_kernel<<<1, 256, 0, stream>>>(e, nz, E);
    conv_count_kernel<<<eb, 256, 0, stream>>>(e, nz, src32, dst32, cnt, E);

    const int C = (N + 1023) / 1024;
    scan1_kernel<<<4, 256, 0, stream>>>(cnt, part, N, C);
    scan2_kernel<<<1, 1024, 0, stream>>>(part);
    scan3_kernel<<<4, 256, 0, stream>>>(cnt, part, offs, N, C, E);
    inv_kernel<<<(N + 255) / 256, 256, 0, stream>>>(cnt, inv, N);
    fill_kernel<<<eb, 256, 0, stream>>>(src32, dst32, offs, cursor, sorted, E);

    // conversions to bf16
    int n4 = N * 128 / 4;
    cvt_bf16_kernel<<<(n4 + 255) / 256, 256, 0, stream>>>(x, xb, n4);
    cvt_bf16_kernel<<<(512 * 128 / 4 + 255) / 256, 256, 0, stream>>>(Wl0, wl0b, 512 * 128 / 4);
    cvt_bf16_kernel<<<(512 * 128 / 4 + 255) / 256, 256, 0, stream>>>(Wr0, wr0b, 512 * 128 / 4);
    cvt_bf16_kernel<<<(512 * 512 / 4 + 255) / 256, 256, 0, stream>>>(Wl1, wl1b, 512 * 512 / 4);
    cvt_bf16_kernel<<<(512 * 512 / 4 + 255) / 256, 256, 0, stream>>>(Wr1, wr1b, 512 * 512 / 4);
    cvt_bf16_kernel<<<(256 * 512 / 4 + 255) / 256, 256, 0, stream>>>(Wl2, wl2b, 256 * 512 / 4);
    cvt_bf16_kernel<<<(256 * 512 / 4 + 255) / 256, 256, 0, stream>>>(Wr2, wr2b, 256 * 512 / 4);

    const int aggBlocks = (N + 3) / 4;
    const int mBlocks = Mpad / 128;

    // Layer 0: agg-then-GEMM (aggregating 128-dim x is the cheap side).
    agg128_kernel<<<aggBlocks, 256, 0, stream>>>(xb, sorted, offs, inv, aggx, N);
    sage_gemm_mfma<<<dim3(2, mBlocks), 256, 0, stream>>>(
        aggx, xb, wl0b, wr0b, bl0, hbuf, N, 512, 128);

    // Layer 1: GEMM-then-agg: P1=h0@Wl1^T, Q1=h0@Wr1^T+bl1;
    // h1 = relu(inv*sum P1[src] + Q1)
    dual_gemm_mfma<<<dim3(4, mBlocks), 256, 0, stream>>>(
        hbuf, wl1b, wr1b, bl1, Pbuf, Qbuf, N, 512, 512, 0);
    aggfuse512_kernel<<<aggBlocks, 256, 0, stream>>>(
        Pbuf, Qbuf, sorted, offs, inv, hbuf, N);

    // Layer 2: GEMM-then-agg at 256-dim (gather halved vs agg-first);
    // out = inv*sum P2[src] + Q2 (fp32, no relu)
    dual_gemm_mfma<<<dim3(2, mBlocks), 256, 0, stream>>>(
        hbuf, wl2b, wr2b, bl2, Pbuf, (void*)Qf, N, 256, 512, 1);
    aggfuse256_kernel<<<aggBlocks, 256, 0, stream>>>(
        Pbuf, Qf, sorted, offs, inv, out, N);
}

// Round 8
// 625.387 us; speedup vs baseline: 1.6978x; 1.0086x over previous
//
#include <hip/hip_runtime.h>
#include <hip/hip_bf16.h>
#include <cstdint>
#include <cstddef>

static inline size_t align_up(size_t x, size_t a) { return (x + a - 1) & ~(a - 1); }

typedef __attribute__((ext_vector_type(4))) float f32x4;
typedef __attribute__((ext_vector_type(4))) unsigned int u32x4;
typedef __attribute__((ext_vector_type(2))) unsigned int u32x2;
typedef __attribute__((ext_vector_type(8))) short bf16x8;

__device__ inline float bf2f(unsigned int u16) {        // low 16 bits hold bf16
    return __uint_as_float(u16 << 16);
}
__device__ inline float bflo(unsigned int v) { return __uint_as_float(v << 16); }
__device__ inline float bfhi(unsigned int v) { return __uint_as_float(v & 0xffff0000u); }
__device__ inline unsigned short f2bf(float f) {        // round-to-nearest-even
    unsigned int u = __float_as_uint(f);
    u = (u + 0x7fffu + ((u >> 16) & 1u)) >> 16;
    return (unsigned short)u;
}

#define GLD_LDS(gp, lp) \
    __builtin_amdgcn_global_load_lds( \
        (const __attribute__((address_space(1))) unsigned int*)(gp), \
        (__attribute__((address_space(3))) unsigned int*)(lp), 16, 0, 0)

// ---------------------------------------------------------------------------
__global__ void zero_kernel(int* __restrict__ p, int n) {
    int i = blockIdx.x * 256 + threadIdx.x;
    if (i < n) p[i] = 0;
}

// Edge-encoding detection, single block, sampled, no atomics.
__global__ void detect_kernel(const int* __restrict__ e, int* __restrict__ nz, int E) {
    int t = threadIdx.x;  // 0..255, one block
    long long stride = (long long)E / 4096;
    if (stride < 1) stride = 1;
    int any = 0;
    for (int k = 0; k < 16; ++k) {
        long long idx = (long long)(t * 16 + k) * stride;
        if (idx < E && e[2 * idx + 1] != 0) any = 1;
    }
    if (any) nz[0] = 1;  // same-value race is benign
}

__global__ void conv_count_kernel(const int* __restrict__ eraw, const int* __restrict__ nz,
                                  int* __restrict__ src32, int* __restrict__ dst32,
                                  int* __restrict__ cnt, int E) {
    int i = blockIdx.x * blockDim.x + threadIdx.x;
    if (i >= E) return;
    int s, d;
    if (*nz == 0) {  // int64 storage
        const long long* e64 = (const long long*)eraw;
        s = (int)e64[i];
        d = (int)e64[i + E];
    } else {         // int32 storage
        s = eraw[i];
        d = eraw[i + E];
    }
    src32[i] = s;
    dst32[i] = d;
    atomicAdd(&cnt[d], 1);
}

// 3-kernel exclusive scan over cnt[0..n) -> offs[0..n]
__global__ void scan1_kernel(const int* __restrict__ cnt, int* __restrict__ partial,
                             int n, int C) {
    int t = blockIdx.x * 256 + threadIdx.x;  // 0..1023
    int s = 0;
    int base = t * C;
    for (int i = 0; i < C; ++i) {
        int idx = base + i;
        if (idx < n) s += cnt[idx];
    }
    partial[t] = s;
}

__global__ void __launch_bounds__(1024) scan2_kernel(int* __restrict__ partial) {
    __shared__ int sh[1024];
    int t = threadIdx.x;
    sh[t] = partial[t];
    __syncthreads();
    for (int off = 1; off < 1024; off <<= 1) {
        int v = (t >= off) ? sh[t - off] : 0;
        __syncthreads();
        sh[t] += v;
        __syncthreads();
    }
    partial[t] = (t == 0) ? 0 : sh[t - 1];  // exclusive
}

__global__ void scan3_kernel(const int* __restrict__ cnt, const int* __restrict__ partial,
                             int* __restrict__ offs, int n, int C, int E) {
    int t = blockIdx.x * 256 + threadIdx.x;
    int run = partial[t];
    int base = t * C;
    for (int i = 0; i < C; ++i) {
        int idx = base + i;
        if (idx < n) {
            offs[idx] = run;
            run += cnt[idx];
        }
    }
    if (t == 0) offs[n] = E;
}

__global__ void inv_kernel(const int* __restrict__ cnt, float* __restrict__ inv, int n) {
    int i = blockIdx.x * 256 + threadIdx.x;
    if (i < n) inv[i] = 1.0f / (float)max(cnt[i], 1);
}

__global__ void fill_kernel(const int* __restrict__ src32, const int* __restrict__ dst32,
                            const int* __restrict__ offs, int* __restrict__ cursor,
                            int* __restrict__ sorted, int E) {
    int i = blockIdx.x * 256 + threadIdx.x;
    if (i >= E) return;
    int d = dst32[i];
    int p = offs[d] + atomicAdd(&cursor[d], 1);
    sorted[p] = src32[i];
}

// fp32 -> bf16, vectorized x4
__global__ void cvt_bf16_kernel(const float* __restrict__ x, unsigned short* __restrict__ xb,
                                int n4) {
    int i = blockIdx.x * 256 + threadIdx.x;
    if (i >= n4) return;
    float4 v = *(const float4*)(x + (size_t)i * 4);
    uint2 o;
    o.x = (unsigned int)f2bf(v.x) | ((unsigned int)f2bf(v.y) << 16);
    o.y = (unsigned int)f2bf(v.z) | ((unsigned int)f2bf(v.w) << 16);
    *(uint2*)(xb + (size_t)i * 4) = o;
}

// ---------------------------------------------------------------------------
// Aggregation kernels (round-8).
// Regime (r0/r6/r7 A/B): gathers are throughput-bound on the beyond-L2 fetch
// path (~3.3-3.8 TB/s); dur tracks FETCH bytes. Hit rate is TEMPORAL: a
// fetched P-row lives ~10us in L2 (4MB / ~410GB/s per XCD); the (deg-1)
// other refs that land in that window hit. r7 measured 58% hit on the 51MB
// table (model: 15*(10/120)=1.25 extra refs -> 55%). Lever: shrink per-launch
// working set. Layer-1 P is stored HALF-SPLIT [2][Mpad][256] (512B rows) and
// gathered in two sequential launches -> lifetime/duration triples -> hit
// ~70-75%. 512B wave-wide requests sustain the same ~6.8TB/s effective rate
// as 1KB (measured: aggfuse256 in this pipeline). Binary 4/2/1 tails (exact
// bytes); single-use streams (Q, out) non-temporal.
// ---------------------------------------------------------------------------
__global__ void __launch_bounds__(256) agg128_kernel(
    const unsigned short* __restrict__ X, const int* __restrict__ srt,
    const int* __restrict__ offs, const float* __restrict__ invc,
    unsigned short* __restrict__ out, int nNodes) {
    int node = blockIdx.x * 4 + (threadIdx.x >> 6);
    if (node >= nNodes) return;
    int lane = threadIdx.x & 63;
    const unsigned short* xp = X + (size_t)lane * 2;
    int beg = offs[node], end = offs[node + 1];
    float sc = invc[node];
    float a0 = 0.f, a1 = 0.f;
    int e = beg;
    for (; e + 8 <= end; e += 8) {
        unsigned int v[8];
#pragma unroll
        for (int u = 0; u < 8; ++u)
            v[u] = *(const unsigned int*)(xp + (size_t)srt[e + u] * 128);
#pragma unroll
        for (int u = 0; u < 8; ++u) {
            a0 += bflo(v[u]);
            a1 += bfhi(v[u]);
        }
    }
    int r = end - e;
    if (r & 4) {
        unsigned int v[4];
#pragma unroll
        for (int u = 0; u < 4; ++u)
            v[u] = *(const unsigned int*)(xp + (size_t)srt[e + u] * 128);
#pragma unroll
        for (int u = 0; u < 4; ++u) { a0 += bflo(v[u]); a1 += bfhi(v[u]); }
        e += 4;
    }
    if (r & 2) {
        unsigned int v[2];
#pragma unroll
        for (int u = 0; u < 2; ++u)
            v[u] = *(const unsigned int*)(xp + (size_t)srt[e + u] * 128);
#pragma unroll
        for (int u = 0; u < 2; ++u) { a0 += bflo(v[u]); a1 += bfhi(v[u]); }
        e += 2;
    }
    if (r & 1) {
        unsigned int v = *(const unsigned int*)(xp + (size_t)srt[e] * 128);
        a0 += bflo(v);
        a1 += bfhi(v);
    }
    unsigned int o = (unsigned int)f2bf(a0 * sc) | ((unsigned int)f2bf(a1 * sc) << 16);
    __builtin_nontemporal_store(o, (unsigned int*)(out + (size_t)node * 128 + lane * 2));
}

// ---------------------------------------------------------------------------
// Layer-1 fused aggregation, HALF-SPLIT: out[dst][h*256+..] =
// relu(inv*sum Ph[src] + Q[dst][h*256+..]). P: [2][Mpad][256] bf16; one wave
// per node, lane owns 4 dims (uint2 = 8 B); 512 B/edge wave-wide.
// ---------------------------------------------------------------------------
__global__ void __launch_bounds__(256) aggfuse512h_kernel(
    const unsigned short* __restrict__ P, const unsigned short* __restrict__ Q,
    const int* __restrict__ srt, const int* __restrict__ offs,
    const float* __restrict__ invc, unsigned short* __restrict__ out,
    int nNodes, int Mpad, int half) {
    int node = blockIdx.x * 4 + (threadIdx.x >> 6);
    if (node >= nNodes) return;
    int lane = threadIdx.x & 63;
    const unsigned short* pp = P + (size_t)half * Mpad * 256 + lane * 4;
    int beg = offs[node], end = offs[node + 1];
    float sc = invc[node];
    float a0 = 0.f, a1 = 0.f, a2 = 0.f, a3 = 0.f;
#define ACC4(v)                              \
    do {                                     \
        a0 += bflo((v).x);                   \
        a1 += bfhi((v).x);                   \
        a2 += bflo((v).y);                   \
        a3 += bfhi((v).y);                   \
    } while (0)
    int e = beg;
    for (; e + 8 <= end; e += 8) {
        uint2 v[8];
#pragma unroll
        for (int u = 0; u < 8; ++u)
            v[u] = *(const uint2*)(pp + (size_t)srt[e + u] * 256);
#pragma unroll
        for (int u = 0; u < 8; ++u) ACC4(v[u]);
    }
    int r = end - e;
    if (r & 4) {
        uint2 v[4];
#pragma unroll
        for (int u = 0; u < 4; ++u)
            v[u] = *(const uint2*)(pp + (size_t)srt[e + u] * 256);
#pragma unroll
        for (int u = 0; u < 4; ++u) ACC4(v[u]);
        e += 4;
    }
    if (r & 2) {
        uint2 v[2];
#pragma unroll
        for (int u = 0; u < 2; ++u)
            v[u] = *(const uint2*)(pp + (size_t)srt[e + u] * 256);
#pragma unroll
        for (int u = 0; u < 2; ++u) ACC4(v[u]);
        e += 2;
    }
    if (r & 1) {
        uint2 v = *(const uint2*)(pp + (size_t)srt[e] * 256);
        ACC4(v);
    }
#undef ACC4
    size_t qo = (size_t)node * 512 + half * 256 + lane * 4;
    u32x2 q = __builtin_nontemporal_load((const u32x2*)(Q + qo));
    float r0 = fmaxf(a0 * sc + bflo(q.x), 0.f);
    float r1 = fmaxf(a1 * sc + bfhi(q.x), 0.f);
    float r2 = fmaxf(a2 * sc + bflo(q.y), 0.f);
    float r3 = fmaxf(a3 * sc + bfhi(q.y), 0.f);
    u32x2 o;
    o.x = (unsigned int)f2bf(r0) | ((unsigned int)f2bf(r1) << 16);
    o.y = (unsigned int)f2bf(r2) | ((unsigned int)f2bf(r3) << 16);
    __builtin_nontemporal_store(o, (u32x2*)(out + qo));
}

// D=256 variant, fp32 Q and fp32 out (final layer, no relu). 8-edge unroll +
// binary tail; nt Q/out.
__global__ void __launch_bounds__(256) aggfuse256_kernel(
    const unsigned short* __restrict__ P, const float* __restrict__ Q,
    const int* __restrict__ srt, const int* __restrict__ offs,
    const float* __restrict__ invc, float* __restrict__ out, int nNodes) {
    int node = blockIdx.x * 4 + (threadIdx.x >> 6);
    if (node >= nNodes) return;
    int lane = threadIdx.x & 63;
    const unsigned short* pp = P + (size_t)lane * 4;
    int beg = offs[node], end = offs[node + 1];
    float sc = invc[node];
    float a0 = 0.f, a1 = 0.f, a2 = 0.f, a3 = 0.f;
#define ACC4(v)                              \
    do {                                     \
        a0 += bflo((v).x);                   \
        a1 += bfhi((v).x);                   \
        a2 += bflo((v).y);                   \
        a3 += bfhi((v).y);                   \
    } while (0)
    int e = beg;
    for (; e + 8 <= end; e += 8) {
        uint2 v[8];
#pragma unroll
        for (int u = 0; u < 8; ++u)
            v[u] = *(const uint2*)(pp + (size_t)srt[e + u] * 256);
#pragma unroll
        for (int u = 0; u < 8; ++u) ACC4(v[u]);
    }
    int r = end - e;
    if (r & 4) {
        uint2 v[4];
#pragma unroll
        for (int u = 0; u < 4; ++u)
            v[u] = *(const uint2*)(pp + (size_t)srt[e + u] * 256);
#pragma unroll
        for (int u = 0; u < 4; ++u) ACC4(v[u]);
        e += 4;
    }
    if (r & 2) {
        uint2 v[2];
#pragma unroll
        for (int u = 0; u < 2; ++u)
            v[u] = *(const uint2*)(pp + (size_t)srt[e + u] * 256);
#pragma unroll
        for (int u = 0; u < 2; ++u) ACC4(v[u]);
        e += 2;
    }
    if (r & 1) {
        uint2 v = *(const uint2*)(pp + (size_t)srt[e] * 256);
        ACC4(v);
    }
#undef ACC4
    f32x4 q = __builtin_nontemporal_load(
        (const f32x4*)(Q + (size_t)node * 256 + lane * 4));
    f32x4 rr;
    rr.x = a0 * sc + q.x;
    rr.y = a1 * sc + q.y;
    rr.z = a2 * sc + q.z;
    rr.w = a3 * sc + q.w;
    __builtin_nontemporal_store(rr, (f32x4*)(out + (size_t)node * 256 + lane * 4));
}

// ---------------------------------------------------------------------------
// Coalesced bf16 epilogue. permM == 0: row-major [m][N]. permM != 0: half-
// split [n>>8][permM rows][256] (uint4 chunk at 8-aligned n never crosses the
// 256-col half boundary).
// ---------------------------------------------------------------------------
__device__ __forceinline__ void epilogue_bf16(
    f32x4 (&acc)[4][8], const float* bvj, int relu, int permM,
    unsigned short* smem, int wave, int lane,
    unsigned short* Cout, int m0, int n0, int wm, int wn, int M, int N) {
    unsigned short* stg = smem + wave * 2304;  // 128 cols * 18 shorts
    const int colc = lane & 15;
    const int rgrp = (lane >> 4) * 4;
    for (int i = 0; i < 4; ++i) {
        __syncthreads();
#pragma unroll
        for (int j = 0; j < 8; ++j) {
            float v0 = acc[i][j][0] + bvj[j];
            float v1 = acc[i][j][1] + bvj[j];
            float v2 = acc[i][j][2] + bvj[j];
            float v3 = acc[i][j][3] + bvj[j];
            if (relu) {
                v0 = fmaxf(v0, 0.f); v1 = fmaxf(v1, 0.f);
                v2 = fmaxf(v2, 0.f); v3 = fmaxf(v3, 0.f);
            }
            int c = j * 16 + colc;
            *(unsigned int*)&stg[c * 18 + rgrp] =
                (unsigned int)f2bf(v0) | ((unsigned int)f2bf(v1) << 16);
            *(unsigned int*)&stg[c * 18 + rgrp + 2] =
                (unsigned int)f2bf(v2) | ((unsigned int)f2bf(v3) << 16);
        }
        __syncthreads();
#pragma unroll
        for (int p = 0; p < 2; ++p) {
            int colg = lane & 15;                  // 8-col group
            int rp = p * 4 + (lane >> 4);          // row pair 0..7
            unsigned int w[8];
#pragma unroll
            for (int t = 0; t < 8; ++t)
                w[t] = *(const unsigned int*)&stg[(colg * 8 + t) * 18 + rp * 2];
            uint4 lo, hi;
            lo.x = (w[0] & 0xffffu) | (w[1] << 16);
            lo.y = (w[2] & 0xffffu) | (w[3] << 16);
            lo.z = (w[4] & 0xffffu) | (w[5] << 16);
            lo.w = (w[6] & 0xffffu) | (w[7] << 16);
            hi.x = (w[0] >> 16) | (w[1] & 0xffff0000u);
            hi.y = (w[2] >> 16) | (w[3] & 0xffff0000u);
            hi.z = (w[4] >> 16) | (w[5] & 0xffff0000u);
            hi.w = (w[6] >> 16) | (w[7] & 0xffff0000u);
            int mlo = m0 + wm * 64 + i * 16 + rp * 2;
            int n = n0 + wn * 128 + colg * 8;
            if (permM) {
                size_t base = (size_t)(n >> 8) * ((size_t)permM * 256) +
                              (size_t)mlo * 256 + (n & 255);
                if (mlo < M)     *(uint4*)&Cout[base] = lo;
                if (mlo + 1 < M) *(uint4*)&Cout[base + 256] = hi;
            } else {
                if (mlo < M)     *(uint4*)&Cout[(size_t)mlo * N + n] = lo;
                if (mlo + 1 < M) *(uint4*)&Cout[(size_t)(mlo + 1) * N + n] = hi;
            }
        }
    }
}

// ---------------------------------------------------------------------------
// MFMA SAGE GEMM (layer 0): C = relu( Aagg @ Wl^T + Aself @ Wr^T + bias )
// Tile 128x256, BK=32, 4 waves of 4x8 frags. Coalesced bf16 epilogue.
// ---------------------------------------------------------------------------
__global__ void __launch_bounds__(256, 2) sage_gemm_mfma(
    const unsigned short* __restrict__ Aagg, const unsigned short* __restrict__ Aself,
    const unsigned short* __restrict__ Wlb, const unsigned short* __restrict__ Wrb,
    const float* __restrict__ bias, unsigned short* __restrict__ Cout,
    int M, int N, int K) {
    __shared__ __attribute__((aligned(16))) unsigned short smem[12288];  // 24 KB
    unsigned short* As = smem;            // 128*32
    unsigned short* Bs = smem + 4096;     // 256*32
    const int tid = threadIdx.x;
    const int lane = tid & 63;
    const int wave = tid >> 6;
    const int wm = wave >> 1, wn = wave & 1;
    const int m0 = blockIdx.y * 128, n0 = blockIdx.x * 256;

    f32x4 acc[4][8];
#pragma unroll
    for (int i = 0; i < 4; ++i)
#pragma unroll
        for (int j = 0; j < 8; ++j) acc[i][j] = (f32x4){0.f, 0.f, 0.f, 0.f};

    const int srow = wave * 16 + (lane >> 2);
    const int kE = (lane & 3) * 8;
    const int frow = lane & 15;
    const int kk = (lane >> 4) * 8;

    for (int pass = 0; pass < 2; ++pass) {
        const unsigned short* A = pass ? Aself : Aagg;
        const unsigned short* W = pass ? Wrb : Wlb;
        for (int k0 = 0; k0 < K; k0 += 32) {
            __syncthreads();
            GLD_LDS(A + (size_t)(m0 + 0 * 64 + srow) * K + k0 + kE, &As[0 * 2048 + wave * 512]);
            GLD_LDS(A + (size_t)(m0 + 1 * 64 + srow) * K + k0 + kE, &As[1 * 2048 + wave * 512]);
            GLD_LDS(W + (size_t)(n0 + 0 * 64 + srow) * K + k0 + kE, &Bs[0 * 2048 + wave * 512]);
            GLD_LDS(W + (size_t)(n0 + 1 * 64 + srow) * K + k0 + kE, &Bs[1 * 2048 + wave * 512]);
            GLD_LDS(W + (size_t)(n0 + 2 * 64 + srow) * K + k0 + kE, &Bs[2 * 2048 + wave * 512]);
            GLD_LDS(W + (size_t)(n0 + 3 * 64 + srow) * K + k0 + kE, &Bs[3 * 2048 + wave * 512]);
            __syncthreads();
            bf16x8 af[4], bfr[8];
#pragma unroll
            for (int t = 0; t < 4; ++t)
                af[t] = *(const bf16x8*)&As[(wm * 64 + t * 16 + frow) * 32 + kk];
#pragma unroll
            for (int t = 0; t < 8; ++t)
                bfr[t] = *(const bf16x8*)&Bs[(wn * 128 + t * 16 + frow) * 32 + kk];
#pragma unroll
            for (int i = 0; i < 4; ++i)
#pragma unroll
                for (int j = 0; j < 8; ++j)
                    acc[i][j] = __builtin_amdgcn_mfma_f32_16x16x32_bf16(
                        af[i], bfr[j], acc[i][j], 0, 0, 0);
        }
    }

    float bvj[8];
#pragma unroll
    for (int j = 0; j < 8; ++j) bvj[j] = bias[n0 + wn * 128 + j * 16 + (lane & 15)];
    epilogue_bf16(acc, bvj, 1, 0, smem, wave, lane, Cout, m0, n0, wm, wn, M, N);
}

// ---------------------------------------------------------------------------
// Dual-output MFMA GEMM (layers 1-2): P = A@Wl^T ; Q = A@Wr^T + bias.
// grid.x covers 2N in 256-col blocks (first half P, second half Q).
// P optionally written half-split [2][permM][256] for the layer-1 gather.
// ---------------------------------------------------------------------------
__global__ void __launch_bounds__(256, 2) dual_gemm_mfma(
    const unsigned short* __restrict__ A,
    const unsigned short* __restrict__ Wlb, const unsigned short* __restrict__ Wrb,
    const float* __restrict__ bias, unsigned short* __restrict__ P,
    void* __restrict__ Q, int M, int N, int K, int q_fp32, int permM) {
    __shared__ __attribute__((aligned(16))) unsigned short smem[12288];  // 24 KB
    unsigned short* As = smem;
    unsigned short* Bs = smem + 4096;
    const int tid = threadIdx.x;
    const int lane = tid & 63;
    const int wave = tid >> 6;
    const int wm = wave >> 1, wn = wave & 1;
    const int m0 = blockIdx.y * 128;
    const int n0s = blockIdx.x * 256;          // in [0, 2N)
    const int isQ = n0s >= N;
    const int n0 = isQ ? n0s - N : n0s;
    const unsigned short* W = isQ ? Wrb : Wlb;

    f32x4 acc[4][8];
#pragma unroll
    for (int i = 0; i < 4; ++i)
#pragma unroll
        for (int j = 0; j < 8; ++j) acc[i][j] = (f32x4){0.f, 0.f, 0.f, 0.f};

    const int srow = wave * 16 + (lane >> 2);
    const int kE = (lane & 3) * 8;
    const int frow = lane & 15;
    const int kk = (lane >> 4) * 8;

    for (int k0 = 0; k0 < K; k0 += 32) {
        __syncthreads();
        GLD_LDS(A + (size_t)(m0 + 0 * 64 + srow) * K + k0 + kE, &As[0 * 2048 + wave * 512]);
        GLD_LDS(A + (size_t)(m0 + 1 * 64 + srow) * K + k0 + kE, &As[1 * 2048 + wave * 512]);
        GLD_LDS(W + (size_t)(n0 + 0 * 64 + srow) * K + k0 + kE, &Bs[0 * 2048 + wave * 512]);
        GLD_LDS(W + (size_t)(n0 + 1 * 64 + srow) * K + k0 + kE, &Bs[1 * 2048 + wave * 512]);
        GLD_LDS(W + (size_t)(n0 + 2 * 64 + srow) * K + k0 + kE, &Bs[2 * 2048 + wave * 512]);
        GLD_LDS(W + (size_t)(n0 + 3 * 64 + srow) * K + k0 + kE, &Bs[3 * 2048 + wave * 512]);
        __syncthreads();
        bf16x8 af[4], bfr[8];
#pragma unroll
        for (int t = 0; t < 4; ++t)
            af[t] = *(const bf16x8*)&As[(wm * 64 + t * 16 + frow) * 32 + kk];
#pragma unroll
        for (int t = 0; t < 8; ++t)
            bfr[t] = *(const bf16x8*)&Bs[(wn * 128 + t * 16 + frow) * 32 + kk];
#pragma unroll
        for (int i = 0; i < 4; ++i)
#pragma unroll
            for (int j = 0; j < 8; ++j)
                acc[i][j] = __builtin_amdgcn_mfma_f32_16x16x32_bf16(
                    af[i], bfr[j], acc[i][j], 0, 0, 0);
    }

    if (!isQ || !q_fp32) {
        float bvj[8];
#pragma unroll
        for (int j = 0; j < 8; ++j)
            bvj[j] = isQ ? bias[n0 + wn * 128 + j * 16 + (lane & 15)] : 0.f;
        unsigned short* Cout = isQ ? (unsigned short*)Q : P;
        epilogue_bf16(acc, bvj, 0, isQ ? 0 : permM, smem, wave, lane,
                      Cout, m0, n0, wm, wn, M, N);
    } else {
        // fp32 Q: scalar stores are 64 B per quarter-wave -> already coalesced
        const int col = lane & 15;
        const int rgrp = (lane >> 4) * 4;
        float* Qf = (float*)Q;
#pragma unroll
        for (int j = 0; j < 8; ++j) {
            int n = n0 + wn * 128 + j * 16 + col;
            float bv = bias[n];
#pragma unroll
            for (int i = 0; i < 4; ++i) {
                int mBase = m0 + wm * 64 + i * 16 + rgrp;
#pragma unroll
                for (int r = 0; r < 4; ++r) {
                    int m = mBase + r;
                    if (m >= M) continue;
                    Qf[(size_t)m * N + n] = acc[i][j][r] + bv;
                }
            }
        }
    }
}

// ---------------------------------------------------------------------------
extern "C" void kernel_launch(void* const* d_in, const int* in_sizes, int n_in,
                              void* d_out, int out_size, void* d_ws, size_t ws_size,
                              hipStream_t stream) {
    const float* x   = (const float*)d_in[0];
    const int*   e   = (const int*)d_in[1];
    const float* Wl0 = (const float*)d_in[2];
    const float* bl0 = (const float*)d_in[3];
    const float* Wr0 = (const float*)d_in[4];
    const float* Wl1 = (const float*)d_in[5];
    const float* bl1 = (const float*)d_in[6];
    const float* Wr1 = (const float*)d_in[7];
    const float* Wl2 = (const float*)d_in[8];
    const float* bl2 = (const float*)d_in[9];
    const float* Wr2 = (const float*)d_in[10];
    float* out = (float*)d_out;

    const int N = in_sizes[0] / 128;           // 50000 nodes
    const int E = in_sizes[1] / 2;             // 800000 edges
    const int Mpad = ((N + 127) / 128) * 128;  // 50048: GEMM staging never OOB

    char* ws = (char*)d_ws;
    size_t off = 0;
    auto alloc = [&](size_t bytes) { size_t o = off; off = align_up(off + bytes, 512); return o; };

    size_t o_nz     = alloc(4);
    size_t o_cnt    = alloc((size_t)N * 4);
    size_t o_cursor = alloc((size_t)N * 4);
    size_t zero_end = off;                       // [0, zero_end) zeroed each call
    size_t o_part   = alloc(1024 * 4);
    size_t o_offs   = alloc((size_t)(N + 1) * 4);
    size_t o_inv    = alloc((size_t)N * 4);
    size_t o_src    = alloc((size_t)E * 4);
    size_t o_dst    = alloc((size_t)E * 4);
    size_t o_sort   = alloc((size_t)E * 4);
    size_t o_xb     = alloc((size_t)Mpad * 128 * 2);   // bf16 x row-major
    size_t o_aggx   = alloc((size_t)Mpad * 128 * 2);   // bf16 agg(x)
    size_t o_h      = alloc((size_t)Mpad * 512 * 2);   // h0, then h1
    size_t o_P      = alloc((size_t)Mpad * 512 * 2);   // P1 [2][Mpad][256], then P2 (256)
    size_t o_Q      = alloc((size_t)Mpad * 512 * 2);   // Q1 bf16 (512), then Q2 fp32 (256)
    size_t o_wl0    = alloc((size_t)512 * 128 * 2);
    size_t o_wr0    = alloc((size_t)512 * 128 * 2);
    size_t o_wl1    = alloc((size_t)512 * 512 * 2);
    size_t o_wr1    = alloc((size_t)512 * 512 * 2);
    size_t o_wl2    = alloc((size_t)256 * 512 * 2);
    size_t o_wr2    = alloc((size_t)256 * 512 * 2);
    (void)ws_size; (void)n_in; (void)out_size;

    int*            nz     = (int*)(ws + o_nz);
    int*            cnt    = (int*)(ws + o_cnt);
    int*            cursor = (int*)(ws + o_cursor);
    int*            part   = (int*)(ws + o_part);
    int*            offs   = (int*)(ws + o_offs);
    float*          inv    = (float*)(ws + o_inv);
    int*            src32  = (int*)(ws + o_src);
    int*            dst32  = (int*)(ws + o_dst);
    int*            sorted = (int*)(ws + o_sort);
    unsigned short* xb     = (unsigned short*)(ws + o_xb);
    unsigned short* aggx   = (unsigned short*)(ws + o_aggx);
    unsigned short* hbuf   = (unsigned short*)(ws + o_h);
    unsigned short* Pbuf   = (unsigned short*)(ws + o_P);
    unsigned short* Qbuf   = (unsigned short*)(ws + o_Q);   // bf16 view (layer 1)
    float*          Qf     = (float*)(ws + o_Q);            // fp32 view (layer 2)
    unsigned short* wl0b   = (unsigned short*)(ws + o_wl0);
    unsigned short* wr0b   = (unsigned short*)(ws + o_wr0);
    unsigned short* wl1b   = (unsigned short*)(ws + o_wl1);
    unsigned short* wr1b   = (unsigned short*)(ws + o_wr1);
    unsigned short* wl2b   = (unsigned short*)(ws + o_wl2);
    unsigned short* wr2b   = (unsigned short*)(ws + o_wr2);

    // zero nz/cnt/cursor (ws poisoned 0xAA before every call)
    int zn = (int)(zero_end / 4);
    zero_kernel<<<(zn + 255) / 256, 256, 0, stream>>>((int*)ws, zn);

    int eb = (E + 255) / 256;
    detect_kernel<<<1, 256, 0, stream>>>(e, nz, E);
    conv_count_kernel<<<eb, 256, 0, stream>>>(e, nz, src32, dst32, cnt, E);

    const int C = (N + 1023) / 1024;
    scan1_kernel<<<4, 256, 0, stream>>>(cnt, part, N, C);
    scan2_kernel<<<1, 1024, 0, stream>>>(part);
    scan3_kernel<<<4, 256, 0, stream>>>(cnt, part, offs, N, C, E);
    inv_kernel<<<(N + 255) / 256, 256, 0, stream>>>(cnt, inv, N);
    fill_kernel<<<eb, 256, 0, stream>>>(src32, dst32, offs, cursor, sorted, E);

    // conversions to bf16
    int n4 = N * 128 / 4;
    cvt_bf16_kernel<<<(n4 + 255) / 256, 256, 0, stream>>>(x, xb, n4);
    cvt_bf16_kernel<<<(512 * 128 / 4 + 255) / 256, 256, 0, stream>>>(Wl0, wl0b, 512 * 128 / 4);
    cvt_bf16_kernel<<<(512 * 128 / 4 + 255) / 256, 256, 0, stream>>>(Wr0, wr0b, 512 * 128 / 4);
    cvt_bf16_kernel<<<(512 * 512 / 4 + 255) / 256, 256, 0, stream>>>(Wl1, wl1b, 512 * 512 / 4);
    cvt_bf16_kernel<<<(512 * 512 / 4 + 255) / 256, 256, 0, stream>>>(Wr1, wr1b, 512 * 512 / 4);
    cvt_bf16_kernel<<<(256 * 512 / 4 + 255) / 256, 256, 0, stream>>>(Wl2, wl2b, 256 * 512 / 4);
    cvt_bf16_kernel<<<(256 * 512 / 4 + 255) / 256, 256, 0, stream>>>(Wr2, wr2b, 256 * 512 / 4);

    const int aggBlocks = (N + 3) / 4;
    const int mBlocks = Mpad / 128;

    // Layer 0: agg-then-GEMM (aggregating 128-dim x is the cheap side).
    agg128_kernel<<<aggBlocks, 256, 0, stream>>>(xb, sorted, offs, inv, aggx, N);
    sage_gemm_mfma<<<dim3(2, mBlocks), 256, 0, stream>>>(
        aggx, xb, wl0b, wr0b, bl0, hbuf, N, 512, 128);

    // Layer 1: GEMM-then-agg: P1=h0@Wl1^T (half-split [2][Mpad][256]),
    // Q1=h0@Wr1^T+bl1 (row-major); h1 = relu(inv*sum P1[src] + Q1) in two
    // sequential half-launches (25.6 MB working set each -> higher L2 hit).
    dual_gemm_mfma<<<dim3(4, mBlocks), 256, 0, stream>>>(
        hbuf, wl1b, wr1b, bl1, Pbuf, Qbuf, N, 512, 512, 0, Mpad);
    aggfuse512h_kernel<<<aggBlocks, 256, 0, stream>>>(
        Pbuf, Qbuf, sorted, offs, inv, hbuf, N, Mpad, 0);
    aggfuse512h_kernel<<<aggBlocks, 256, 0, stream>>>(
        Pbuf, Qbuf, sorted, offs, inv, hbuf, N, Mpad, 1);

    // Layer 2: GEMM-then-agg at 256-dim (row-major P2);
    // out = inv*sum P2[src] + Q2 (fp32, no relu)
    dual_gemm_mfma<<<dim3(2, mBlocks), 256, 0, stream>>>(
        hbuf, wl2b, wr2b, bl2, Pbuf, (void*)Qf, N, 256, 512, 1, 0);
    aggfuse256_kernel<<<aggBlocks, 256, 0, stream>>>(
        Pbuf, Qf, sorted, offs, inv, out, N);
}

// Round 9
// 614.599 us; speedup vs baseline: 1.7276x; 1.0176x over previous
//
#include <hip/hip_runtime.h>
#include <hip/hip_bf16.h>
#include <cstdint>
#include <cstddef>

static inline size_t align_up(size_t x, size_t a) { return (x + a - 1) & ~(a - 1); }

typedef __attribute__((ext_vector_type(4))) float f32x4;
typedef __attribute__((ext_vector_type(4))) unsigned int u32x4;
typedef __attribute__((ext_vector_type(2))) unsigned int u32x2;
typedef __attribute__((ext_vector_type(8))) short bf16x8;

__device__ inline float bf2f(unsigned int u16) {        // low 16 bits hold bf16
    return __uint_as_float(u16 << 16);
}
__device__ inline float bflo(unsigned int v) { return __uint_as_float(v << 16); }
__device__ inline float bfhi(unsigned int v) { return __uint_as_float(v & 0xffff0000u); }
__device__ inline unsigned short f2bf(float f) {        // round-to-nearest-even
    unsigned int u = __float_as_uint(f);
    u = (u + 0x7fffu + ((u >> 16) & 1u)) >> 16;
    return (unsigned short)u;
}

#define GLD_LDS(gp, lp) \
    __builtin_amdgcn_global_load_lds( \
        (const __attribute__((address_space(1))) unsigned int*)(gp), \
        (__attribute__((address_space(3))) unsigned int*)(lp), 16, 0, 0)

// ---------------------------------------------------------------------------
__global__ void zero_kernel(int* __restrict__ p, int n) {
    int i = blockIdx.x * 256 + threadIdx.x;
    if (i < n) p[i] = 0;
}

// Edge-encoding detection, single block, sampled, no atomics.
__global__ void detect_kernel(const int* __restrict__ e, int* __restrict__ nz, int E) {
    int t = threadIdx.x;  // 0..255, one block
    long long stride = (long long)E / 4096;
    if (stride < 1) stride = 1;
    int any = 0;
    for (int k = 0; k < 16; ++k) {
        long long idx = (long long)(t * 16 + k) * stride;
        if (idx < E && e[2 * idx + 1] != 0) any = 1;
    }
    if (any) nz[0] = 1;  // same-value race is benign
}

__global__ void conv_count_kernel(const int* __restrict__ eraw, const int* __restrict__ nz,
                                  int* __restrict__ src32, int* __restrict__ dst32,
                                  int* __restrict__ cnt, int E) {
    int i = blockIdx.x * blockDim.x + threadIdx.x;
    if (i >= E) return;
    int s, d;
    if (*nz == 0) {  // int64 storage
        const long long* e64 = (const long long*)eraw;
        s = (int)e64[i];
        d = (int)e64[i + E];
    } else {         // int32 storage
        s = eraw[i];
        d = eraw[i + E];
    }
    src32[i] = s;
    dst32[i] = d;
    atomicAdd(&cnt[d], 1);
}

// 3-kernel exclusive scan over cnt[0..n) -> offs[0..n]
__global__ void scan1_kernel(const int* __restrict__ cnt, int* __restrict__ partial,
                             int n, int C) {
    int t = blockIdx.x * 256 + threadIdx.x;  // 0..1023
    int s = 0;
    int base = t * C;
    for (int i = 0; i < C; ++i) {
        int idx = base + i;
        if (idx < n) s += cnt[idx];
    }
    partial[t] = s;
}

__global__ void __launch_bounds__(1024) scan2_kernel(int* __restrict__ partial) {
    __shared__ int sh[1024];
    int t = threadIdx.x;
    sh[t] = partial[t];
    __syncthreads();
    for (int off = 1; off < 1024; off <<= 1) {
        int v = (t >= off) ? sh[t - off] : 0;
        __syncthreads();
        sh[t] += v;
        __syncthreads();
    }
    partial[t] = (t == 0) ? 0 : sh[t - 1];  // exclusive
}

__global__ void scan3_kernel(const int* __restrict__ cnt, const int* __restrict__ partial,
                             int* __restrict__ offs, int n, int C, int E) {
    int t = blockIdx.x * 256 + threadIdx.x;
    int run = partial[t];
    int base = t * C;
    for (int i = 0; i < C; ++i) {
        int idx = base + i;
        if (idx < n) {
            offs[idx] = run;
            run += cnt[idx];
        }
    }
    if (t == 0) offs[n] = E;
}

__global__ void inv_kernel(const int* __restrict__ cnt, float* __restrict__ inv, int n) {
    int i = blockIdx.x * 256 + threadIdx.x;
    if (i < n) inv[i] = 1.0f / (float)max(cnt[i], 1);
}

__global__ void fill_kernel(const int* __restrict__ src32, const int* __restrict__ dst32,
                            const int* __restrict__ offs, int* __restrict__ cursor,
                            int* __restrict__ sorted, int E) {
    int i = blockIdx.x * 256 + threadIdx.x;
    if (i >= E) return;
    int d = dst32[i];
    int p = offs[d] + atomicAdd(&cursor[d], 1);
    sorted[p] = src32[i];
}

// fp32 -> bf16, vectorized x4
__global__ void cvt_bf16_kernel(const float* __restrict__ x, unsigned short* __restrict__ xb,
                                int n4) {
    int i = blockIdx.x * 256 + threadIdx.x;
    if (i >= n4) return;
    float4 v = *(const float4*)(x + (size_t)i * 4);
    uint2 o;
    o.x = (unsigned int)f2bf(v.x) | ((unsigned int)f2bf(v.y) << 16);
    o.y = (unsigned int)f2bf(v.z) | ((unsigned int)f2bf(v.w) << 16);
    *(uint2*)(xb + (size_t)i * 4) = o;
}

// ---------------------------------------------------------------------------
// Aggregation kernels (unchanged from round-8 best).
// Regime: gathers throughput-bound on the beyond-L2 fetch path (~3.3-3.8
// TB/s); dur tracks FETCH bytes; hit rate is temporal. Layer-1 P half-split
// [2][Mpad][256], two sequential launches. Binary 4/2/1 tails; single-use
// streams (Q, out) non-temporal.
// ---------------------------------------------------------------------------
__global__ void __launch_bounds__(256) agg128_kernel(
    const unsigned short* __restrict__ X, const int* __restrict__ srt,
    const int* __restrict__ offs, const float* __restrict__ invc,
    unsigned short* __restrict__ out, int nNodes) {
    int node = blockIdx.x * 4 + (threadIdx.x >> 6);
    if (node >= nNodes) return;
    int lane = threadIdx.x & 63;
    const unsigned short* xp = X + (size_t)lane * 2;
    int beg = offs[node], end = offs[node + 1];
    float sc = invc[node];
    float a0 = 0.f, a1 = 0.f;
    int e = beg;
    for (; e + 8 <= end; e += 8) {
        unsigned int v[8];
#pragma unroll
        for (int u = 0; u < 8; ++u)
            v[u] = *(const unsigned int*)(xp + (size_t)srt[e + u] * 128);
#pragma unroll
        for (int u = 0; u < 8; ++u) {
            a0 += bflo(v[u]);
            a1 += bfhi(v[u]);
        }
    }
    int r = end - e;
    if (r & 4) {
        unsigned int v[4];
#pragma unroll
        for (int u = 0; u < 4; ++u)
            v[u] = *(const unsigned int*)(xp + (size_t)srt[e + u] * 128);
#pragma unroll
        for (int u = 0; u < 4; ++u) { a0 += bflo(v[u]); a1 += bfhi(v[u]); }
        e += 4;
    }
    if (r & 2) {
        unsigned int v[2];
#pragma unroll
        for (int u = 0; u < 2; ++u)
            v[u] = *(const unsigned int*)(xp + (size_t)srt[e + u] * 128);
#pragma unroll
        for (int u = 0; u < 2; ++u) { a0 += bflo(v[u]); a1 += bfhi(v[u]); }
        e += 2;
    }
    if (r & 1) {
        unsigned int v = *(const unsigned int*)(xp + (size_t)srt[e] * 128);
        a0 += bflo(v);
        a1 += bfhi(v);
    }
    unsigned int o = (unsigned int)f2bf(a0 * sc) | ((unsigned int)f2bf(a1 * sc) << 16);
    __builtin_nontemporal_store(o, (unsigned int*)(out + (size_t)node * 128 + lane * 2));
}

// Layer-1 fused aggregation, HALF-SPLIT: out[dst][h*256+..] =
// relu(inv*sum Ph[src] + Q[dst][h*256+..]). P: [2][Mpad][256] bf16.
__global__ void __launch_bounds__(256) aggfuse512h_kernel(
    const unsigned short* __restrict__ P, const unsigned short* __restrict__ Q,
    const int* __restrict__ srt, const int* __restrict__ offs,
    const float* __restrict__ invc, unsigned short* __restrict__ out,
    int nNodes, int Mpad, int half) {
    int node = blockIdx.x * 4 + (threadIdx.x >> 6);
    if (node >= nNodes) return;
    int lane = threadIdx.x & 63;
    const unsigned short* pp = P + (size_t)half * Mpad * 256 + lane * 4;
    int beg = offs[node], end = offs[node + 1];
    float sc = invc[node];
    float a0 = 0.f, a1 = 0.f, a2 = 0.f, a3 = 0.f;
#define ACC4(v)                              \
    do {                                     \
        a0 += bflo((v).x);                   \
        a1 += bfhi((v).x);                   \
        a2 += bflo((v).y);                   \
        a3 += bfhi((v).y);                   \
    } while (0)
    int e = beg;
    for (; e + 8 <= end; e += 8) {
        uint2 v[8];
#pragma unroll
        for (int u = 0; u < 8; ++u)
            v[u] = *(const uint2*)(pp + (size_t)srt[e + u] * 256);
#pragma unroll
        for (int u = 0; u < 8; ++u) ACC4(v[u]);
    }
    int r = end - e;
    if (r & 4) {
        uint2 v[4];
#pragma unroll
        for (int u = 0; u < 4; ++u)
            v[u] = *(const uint2*)(pp + (size_t)srt[e + u] * 256);
#pragma unroll
        for (int u = 0; u < 4; ++u) ACC4(v[u]);
        e += 4;
    }
    if (r & 2) {
        uint2 v[2];
#pragma unroll
        for (int u = 0; u < 2; ++u)
            v[u] = *(const uint2*)(pp + (size_t)srt[e + u] * 256);
#pragma unroll
        for (int u = 0; u < 2; ++u) ACC4(v[u]);
        e += 2;
    }
    if (r & 1) {
        uint2 v = *(const uint2*)(pp + (size_t)srt[e] * 256);
        ACC4(v);
    }
#undef ACC4
    size_t qo = (size_t)node * 512 + half * 256 + lane * 4;
    u32x2 q = __builtin_nontemporal_load((const u32x2*)(Q + qo));
    float r0 = fmaxf(a0 * sc + bflo(q.x), 0.f);
    float r1 = fmaxf(a1 * sc + bfhi(q.x), 0.f);
    float r2 = fmaxf(a2 * sc + bflo(q.y), 0.f);
    float r3 = fmaxf(a3 * sc + bfhi(q.y), 0.f);
    u32x2 o;
    o.x = (unsigned int)f2bf(r0) | ((unsigned int)f2bf(r1) << 16);
    o.y = (unsigned int)f2bf(r2) | ((unsigned int)f2bf(r3) << 16);
    __builtin_nontemporal_store(o, (u32x2*)(out + qo));
}

// D=256 variant, fp32 Q and fp32 out (final layer, no relu).
__global__ void __launch_bounds__(256) aggfuse256_kernel(
    const unsigned short* __restrict__ P, const float* __restrict__ Q,
    const int* __restrict__ srt, const int* __restrict__ offs,
    const float* __restrict__ invc, float* __restrict__ out, int nNodes) {
    int node = blockIdx.x * 4 + (threadIdx.x >> 6);
    if (node >= nNodes) return;
    int lane = threadIdx.x & 63;
    const unsigned short* pp = P + (size_t)lane * 4;
    int beg = offs[node], end = offs[node + 1];
    float sc = invc[node];
    float a0 = 0.f, a1 = 0.f, a2 = 0.f, a3 = 0.f;
#define ACC4(v)                              \
    do {                                     \
        a0 += bflo((v).x);                   \
        a1 += bfhi((v).x);                   \
        a2 += bflo((v).y);                   \
        a3 += bfhi((v).y);                   \
    } while (0)
    int e = beg;
    for (; e + 8 <= end; e += 8) {
        uint2 v[8];
#pragma unroll
        for (int u = 0; u < 8; ++u)
            v[u] = *(const uint2*)(pp + (size_t)srt[e + u] * 256);
#pragma unroll
        for (int u = 0; u < 8; ++u) ACC4(v[u]);
    }
    int r = end - e;
    if (r & 4) {
        uint2 v[4];
#pragma unroll
        for (int u = 0; u < 4; ++u)
            v[u] = *(const uint2*)(pp + (size_t)srt[e + u] * 256);
#pragma unroll
        for (int u = 0; u < 4; ++u) ACC4(v[u]);
        e += 4;
    }
    if (r & 2) {
        uint2 v[2];
#pragma unroll
        for (int u = 0; u < 2; ++u)
            v[u] = *(const uint2*)(pp + (size_t)srt[e + u] * 256);
#pragma unroll
        for (int u = 0; u < 2; ++u) ACC4(v[u]);
        e += 2;
    }
    if (r & 1) {
        uint2 v = *(const uint2*)(pp + (size_t)srt[e] * 256);
        ACC4(v);
    }
#undef ACC4
    f32x4 q = __builtin_nontemporal_load(
        (const f32x4*)(Q + (size_t)node * 256 + lane * 4));
    f32x4 rr;
    rr.x = a0 * sc + q.x;
    rr.y = a1 * sc + q.y;
    rr.z = a2 * sc + q.z;
    rr.w = a3 * sc + q.w;
    __builtin_nontemporal_store(rr, (f32x4*)(out + (size_t)node * 256 + lane * 4));
}

// ---------------------------------------------------------------------------
// Coalesced bf16 epilogue. permM == 0: row-major [m][N]. permM != 0: half-
// split [n>>8][permM rows][256].
// ---------------------------------------------------------------------------
__device__ __forceinline__ void epilogue_bf16(
    f32x4 (&acc)[4][8], const float* bvj, int relu, int permM,
    unsigned short* smem, int wave, int lane,
    unsigned short* Cout, int m0, int n0, int wm, int wn, int M, int N) {
    unsigned short* stg = smem + wave * 2304;  // 128 cols * 18 shorts
    const int colc = lane & 15;
    const int rgrp = (lane >> 4) * 4;
    for (int i = 0; i < 4; ++i) {
        __syncthreads();
#pragma unroll
        for (int j = 0; j < 8; ++j) {
            float v0 = acc[i][j][0] + bvj[j];
            float v1 = acc[i][j][1] + bvj[j];
            float v2 = acc[i][j][2] + bvj[j];
            float v3 = acc[i][j][3] + bvj[j];
            if (relu) {
                v0 = fmaxf(v0, 0.f); v1 = fmaxf(v1, 0.f);
                v2 = fmaxf(v2, 0.f); v3 = fmaxf(v3, 0.f);
            }
            int c = j * 16 + colc;
            *(unsigned int*)&stg[c * 18 + rgrp] =
                (unsigned int)f2bf(v0) | ((unsigned int)f2bf(v1) << 16);
            *(unsigned int*)&stg[c * 18 + rgrp + 2] =
                (unsigned int)f2bf(v2) | ((unsigned int)f2bf(v3) << 16);
        }
        __syncthreads();
#pragma unroll
        for (int p = 0; p < 2; ++p) {
            int colg = lane & 15;                  // 8-col group
            int rp = p * 4 + (lane >> 4);          // row pair 0..7
            unsigned int w[8];
#pragma unroll
            for (int t = 0; t < 8; ++t)
                w[t] = *(const unsigned int*)&stg[(colg * 8 + t) * 18 + rp * 2];
            uint4 lo, hi;
            lo.x = (w[0] & 0xffffu) | (w[1] << 16);
            lo.y = (w[2] & 0xffffu) | (w[3] << 16);
            lo.z = (w[4] & 0xffffu) | (w[5] << 16);
            lo.w = (w[6] & 0xffffu) | (w[7] << 16);
            hi.x = (w[0] >> 16) | (w[1] & 0xffff0000u);
            hi.y = (w[2] >> 16) | (w[3] & 0xffff0000u);
            hi.z = (w[4] >> 16) | (w[5] & 0xffff0000u);
            hi.w = (w[6] >> 16) | (w[7] & 0xffff0000u);
            int mlo = m0 + wm * 64 + i * 16 + rp * 2;
            int n = n0 + wn * 128 + colg * 8;
            if (permM) {
                size_t base = (size_t)(n >> 8) * ((size_t)permM * 256) +
                              (size_t)mlo * 256 + (n & 255);
                if (mlo < M)     *(uint4*)&Cout[base] = lo;
                if (mlo + 1 < M) *(uint4*)&Cout[base + 256] = hi;
            } else {
                if (mlo < M)     *(uint4*)&Cout[(size_t)mlo * N + n] = lo;
                if (mlo + 1 < M) *(uint4*)&Cout[(size_t)(mlo + 1) * N + n] = hi;
            }
        }
    }
}

// ---------------------------------------------------------------------------
// MFMA SAGE GEMM (layer 0): C = relu( Aagg @ Wl^T + Aself @ Wr^T + bias )
// Round-9: double-buffered LDS pipeline (T3-minimum). Old loop paid a serial
// vmcnt(0)+barrier drain of COLD A loads every K-step (counters: MfmaUtil 21,
// VALU 19, HBM 27, Occ 17 -> latency-bound, no pipe saturated). New loop:
// stage(next buf) BEFORE compute(current); single barrier/step whose drain
// overlaps the ~900-cyc load latency with ds_read+MFMA of the current step.
// 2 passes flattened into one 8-step pipeline (acc persists).
// ---------------------------------------------------------------------------
__global__ void __launch_bounds__(256, 2) sage_gemm_mfma(
    const unsigned short* __restrict__ Aagg, const unsigned short* __restrict__ Aself,
    const unsigned short* __restrict__ Wlb, const unsigned short* __restrict__ Wrb,
    const float* __restrict__ bias, unsigned short* __restrict__ Cout,
    int M, int N, int K) {
    __shared__ __attribute__((aligned(16))) unsigned short smem[24576];  // 48 KB, 2 bufs
    const int tid = threadIdx.x;
    const int lane = tid & 63;
    const int wave = tid >> 6;
    const int wm = wave >> 1, wn = wave & 1;
    const int m0 = blockIdx.y * 128, n0 = blockIdx.x * 256;

    f32x4 acc[4][8];
#pragma unroll
    for (int i = 0; i < 4; ++i)
#pragma unroll
        for (int j = 0; j < 8; ++j) acc[i][j] = (f32x4){0.f, 0.f, 0.f, 0.f};

    const int srow = wave * 16 + (lane >> 2);
    const int kE = (lane & 3) * 8;
    const int frow = lane & 15;
    const int kk = (lane >> 4) * 8;

    const int kSteps = K / 32;          // per pass
    const int steps = kSteps * 2;       // two passes (agg, self)

    auto stage = [&](int buf, int t) {
        const unsigned short* A = (t >= kSteps) ? Aself : Aagg;
        const unsigned short* W = (t >= kSteps) ? Wrb : Wlb;
        int k0 = (t >= kSteps ? t - kSteps : t) * 32;
        unsigned short* As = smem + buf * 12288;
        unsigned short* Bs = As + 4096;
        GLD_LDS(A + (size_t)(m0 + 0 * 64 + srow) * K + k0 + kE, &As[0 * 2048 + wave * 512]);
        GLD_LDS(A + (size_t)(m0 + 1 * 64 + srow) * K + k0 + kE, &As[1 * 2048 + wave * 512]);
        GLD_LDS(W + (size_t)(n0 + 0 * 64 + srow) * K + k0 + kE, &Bs[0 * 2048 + wave * 512]);
        GLD_LDS(W + (size_t)(n0 + 1 * 64 + srow) * K + k0 + kE, &Bs[1 * 2048 + wave * 512]);
        GLD_LDS(W + (size_t)(n0 + 2 * 64 + srow) * K + k0 + kE, &Bs[2 * 2048 + wave * 512]);
        GLD_LDS(W + (size_t)(n0 + 3 * 64 + srow) * K + k0 + kE, &Bs[3 * 2048 + wave * 512]);
    };

    stage(0, 0);
    __syncthreads();
    int cur = 0;
    for (int t = 0; t < steps; ++t) {
        if (t + 1 < steps) stage(cur ^ 1, t + 1);
        unsigned short* As = smem + cur * 12288;
        unsigned short* Bs = As + 4096;
        bf16x8 af[4], bfr[8];
#pragma unroll
        for (int u = 0; u < 4; ++u)
            af[u] = *(const bf16x8*)&As[(wm * 64 + u * 16 + frow) * 32 + kk];
#pragma unroll
        for (int u = 0; u < 8; ++u)
            bfr[u] = *(const bf16x8*)&Bs[(wn * 128 + u * 16 + frow) * 32 + kk];
#pragma unroll
        for (int i = 0; i < 4; ++i)
#pragma unroll
            for (int j = 0; j < 8; ++j)
                acc[i][j] = __builtin_amdgcn_mfma_f32_16x16x32_bf16(
                    af[i], bfr[j], acc[i][j], 0, 0, 0);
        __syncthreads();
        cur ^= 1;
    }

    float bvj[8];
#pragma unroll
    for (int j = 0; j < 8; ++j) bvj[j] = bias[n0 + wn * 128 + j * 16 + (lane & 15)];
    epilogue_bf16(acc, bvj, 1, 0, smem, wave, lane, Cout, m0, n0, wm, wn, M, N);
}

// ---------------------------------------------------------------------------
// Dual-output MFMA GEMM (layers 1-2): P = A@Wl^T ; Q = A@Wr^T + bias.
// Round-9: same double-buffered pipeline as sage_gemm (see comment there).
// grid.x covers 2N in 256-col blocks (first half P, second half Q).
// P optionally written half-split [2][permM][256] for the layer-1 gather.
// ---------------------------------------------------------------------------
__global__ void __launch_bounds__(256, 2) dual_gemm_mfma(
    const unsigned short* __restrict__ A,
    const unsigned short* __restrict__ Wlb, const unsigned short* __restrict__ Wrb,
    const float* __restrict__ bias, unsigned short* __restrict__ P,
    void* __restrict__ Q, int M, int N, int K, int q_fp32, int permM) {
    __shared__ __attribute__((aligned(16))) unsigned short smem[24576];  // 48 KB, 2 bufs
    const int tid = threadIdx.x;
    const int lane = tid & 63;
    const int wave = tid >> 6;
    const int wm = wave >> 1, wn = wave & 1;
    const int m0 = blockIdx.y * 128;
    const int n0s = blockIdx.x * 256;          // in [0, 2N)
    const int isQ = n0s >= N;
    const int n0 = isQ ? n0s - N : n0s;
    const unsigned short* W = isQ ? Wrb : Wlb;

    f32x4 acc[4][8];
#pragma unroll
    for (int i = 0; i < 4; ++i)
#pragma unroll
        for (int j = 0; j < 8; ++j) acc[i][j] = (f32x4){0.f, 0.f, 0.f, 0.f};

    const int srow = wave * 16 + (lane >> 2);
    const int kE = (lane & 3) * 8;
    const int frow = lane & 15;
    const int kk = (lane >> 4) * 8;

    const int steps = K / 32;

    auto stage = [&](int buf, int t) {
        int k0 = t * 32;
        unsigned short* As = smem + buf * 12288;
        unsigned short* Bs = As + 4096;
        GLD_LDS(A + (size_t)(m0 + 0 * 64 + srow) * K + k0 + kE, &As[0 * 2048 + wave * 512]);
        GLD_LDS(A + (size_t)(m0 + 1 * 64 + srow) * K + k0 + kE, &As[1 * 2048 + wave * 512]);
        GLD_LDS(W + (size_t)(n0 + 0 * 64 + srow) * K + k0 + kE, &Bs[0 * 2048 + wave * 512]);
        GLD_LDS(W + (size_t)(n0 + 1 * 64 + srow) * K + k0 + kE, &Bs[1 * 2048 + wave * 512]);
        GLD_LDS(W + (size_t)(n0 + 2 * 64 + srow) * K + k0 + kE, &Bs[2 * 2048 + wave * 512]);
        GLD_LDS(W + (size_t)(n0 + 3 * 64 + srow) * K + k0 + kE, &Bs[3 * 2048 + wave * 512]);
    };

    stage(0, 0);
    __syncthreads();
    int cur = 0;
    for (int t = 0; t < steps; ++t) {
        if (t + 1 < steps) stage(cur ^ 1, t + 1);
        unsigned short* As = smem + cur * 12288;
        unsigned short* Bs = As + 4096;
        bf16x8 af[4], bfr[8];
#pragma unroll
        for (int u = 0; u < 4; ++u)
            af[u] = *(const bf16x8*)&As[(wm * 64 + u * 16 + frow) * 32 + kk];
#pragma unroll
        for (int u = 0; u < 8; ++u)
            bfr[u] = *(const bf16x8*)&Bs[(wn * 128 + u * 16 + frow) * 32 + kk];
#pragma unroll
        for (int i = 0; i < 4; ++i)
#pragma unroll
            for (int j = 0; j < 8; ++j)
                acc[i][j] = __builtin_amdgcn_mfma_f32_16x16x32_bf16(
                    af[i], bfr[j], acc[i][j], 0, 0, 0);
        __syncthreads();
        cur ^= 1;
    }

    if (!isQ || !q_fp32) {
        float bvj[8];
#pragma unroll
        for (int j = 0; j < 8; ++j)
            bvj[j] = isQ ? bias[n0 + wn * 128 + j * 16 + (lane & 15)] : 0.f;
        unsigned short* Cout = isQ ? (unsigned short*)Q : P;
        epilogue_bf16(acc, bvj, 0, isQ ? 0 : permM, smem, wave, lane,
                      Cout, m0, n0, wm, wn, M, N);
    } else {
        // fp32 Q: scalar stores are 64 B per quarter-wave -> already coalesced
        const int col = lane & 15;
        const int rgrp = (lane >> 4) * 4;
        float* Qf = (float*)Q;
#pragma unroll
        for (int j = 0; j < 8; ++j) {
            int n = n0 + wn * 128 + j * 16 + col;
            float bv = bias[n];
#pragma unroll
            for (int i = 0; i < 4; ++i) {
                int mBase = m0 + wm * 64 + i * 16 + rgrp;
#pragma unroll
                for (int r = 0; r < 4; ++r) {
                    int m = mBase + r;
                    if (m >= M) continue;
                    Qf[(size_t)m * N + n] = acc[i][j][r] + bv;
                }
            }
        }
    }
}

// ---------------------------------------------------------------------------
extern "C" void kernel_launch(void* const* d_in, const int* in_sizes, int n_in,
                              void* d_out, int out_size, void* d_ws, size_t ws_size,
                              hipStream_t stream) {
    const float* x   = (const float*)d_in[0];
    const int*   e   = (const int*)d_in[1];
    const float* Wl0 = (const float*)d_in[2];
    const float* bl0 = (const float*)d_in[3];
    const float* Wr0 = (const float*)d_in[4];
    const float* Wl1 = (const float*)d_in[5];
    const float* bl1 = (const float*)d_in[6];
    const float* Wr1 = (const float*)d_in[7];
    const float* Wl2 = (const float*)d_in[8];
    const float* bl2 = (const float*)d_in[9];
    const float* Wr2 = (const float*)d_in[10];
    float* out = (float*)d_out;

    const int N = in_sizes[0] / 128;           // 50000 nodes
    const int E = in_sizes[1] / 2;             // 800000 edges
    const int Mpad = ((N + 127) / 128) * 128;  // 50048: GEMM staging never OOB

    char* ws = (char*)d_ws;
    size_t off = 0;
    auto alloc = [&](size_t bytes) { size_t o = off; off = align_up(off + bytes, 512); return o; };

    size_t o_nz     = alloc(4);
    size_t o_cnt    = alloc((size_t)N * 4);
    size_t o_cursor = alloc((size_t)N * 4);
    size_t zero_end = off;                       // [0, zero_end) zeroed each call
    size_t o_part   = alloc(1024 * 4);
    size_t o_offs   = alloc((size_t)(N + 1) * 4);
    size_t o_inv    = alloc((size_t)N * 4);
    size_t o_src    = alloc((size_t)E * 4);
    size_t o_dst    = alloc((size_t)E * 4);
    size_t o_sort   = alloc((size_t)E * 4);
    size_t o_xb     = alloc((size_t)Mpad * 128 * 2);   // bf16 x row-major
    size_t o_aggx   = alloc((size_t)Mpad * 128 * 2);   // bf16 agg(x)
    size_t o_h      = alloc((size_t)Mpad * 512 * 2);   // h0, then h1
    size_t o_P      = alloc((size_t)Mpad * 512 * 2);   // P1 [2][Mpad][256], then P2 (256)
    size_t o_Q      = alloc((size_t)Mpad * 512 * 2);   // Q1 bf16 (512), then Q2 fp32 (256)
    size_t o_wl0    = alloc((size_t)512 * 128 * 2);
    size_t o_wr0    = alloc((size_t)512 * 128 * 2);
    size_t o_wl1    = alloc((size_t)512 * 512 * 2);
    size_t o_wr1    = alloc((size_t)512 * 512 * 2);
    size_t o_wl2    = alloc((size_t)256 * 512 * 2);
    size_t o_wr2    = alloc((size_t)256 * 512 * 2);
    (void)ws_size; (void)n_in; (void)out_size;

    int*            nz     = (int*)(ws + o_nz);
    int*            cnt    = (int*)(ws + o_cnt);
    int*            cursor = (int*)(ws + o_cursor);
    int*            part   = (int*)(ws + o_part);
    int*            offs   = (int*)(ws + o_offs);
    float*          inv    = (float*)(ws + o_inv);
    int*            src32  = (int*)(ws + o_src);
    int*            dst32  = (int*)(ws + o_dst);
    int*            sorted = (int*)(ws + o_sort);
    unsigned short* xb     = (unsigned short*)(ws + o_xb);
    unsigned short* aggx   = (unsigned short*)(ws + o_aggx);
    unsigned short* hbuf   = (unsigned short*)(ws + o_h);
    unsigned short* Pbuf   = (unsigned short*)(ws + o_P);
    unsigned short* Qbuf   = (unsigned short*)(ws + o_Q);   // bf16 view (layer 1)
    float*          Qf     = (float*)(ws + o_Q);            // fp32 view (layer 2)
    unsigned short* wl0b   = (unsigned short*)(ws + o_wl0);
    unsigned short* wr0b   = (unsigned short*)(ws + o_wr0);
    unsigned short* wl1b   = (unsigned short*)(ws + o_wl1);
    unsigned short* wr1b   = (unsigned short*)(ws + o_wr1);
    unsigned short* wl2b   = (unsigned short*)(ws + o_wl2);
    unsigned short* wr2b   = (unsigned short*)(ws + o_wr2);

    // zero nz/cnt/cursor (ws poisoned 0xAA before every call)
    int zn = (int)(zero_end / 4);
    zero_kernel<<<(zn + 255) / 256, 256, 0, stream>>>((int*)ws, zn);

    int eb = (E + 255) / 256;
    detect_kernel<<<1, 256, 0, stream>>>(e, nz, E);
    conv_count_kernel<<<eb, 256, 0, stream>>>(e, nz, src32, dst32, cnt, E);

    const int C = (N + 1023) / 1024;
    scan1_kernel<<<4, 256, 0, stream>>>(cnt, part, N, C);
    scan2_kernel<<<1, 1024, 0, stream>>>(part);
    scan3_kernel<<<4, 256, 0, stream>>>(cnt, part, offs, N, C, E);
    inv_kernel<<<(N + 255) / 256, 256, 0, stream>>>(cnt, inv, N);
    fill_kernel<<<eb, 256, 0, stream>>>(src32, dst32, offs, cursor, sorted, E);

    // conversions to bf16
    int n4 = N * 128 / 4;
    cvt_bf16_kernel<<<(n4 + 255) / 256, 256, 0, stream>>>(x, xb, n4);
    cvt_bf16_kernel<<<(512 * 128 / 4 + 255) / 256, 256, 0, stream>>>(Wl0, wl0b, 512 * 128 / 4);
    cvt_bf16_kernel<<<(512 * 128 / 4 + 255) / 256, 256, 0, stream>>>(Wr0, wr0b, 512 * 128 / 4);
    cvt_bf16_kernel<<<(512 * 512 / 4 + 255) / 256, 256, 0, stream>>>(Wl1, wl1b, 512 * 512 / 4);
    cvt_bf16_kernel<<<(512 * 512 / 4 + 255) / 256, 256, 0, stream>>>(Wr1, wr1b, 512 * 512 / 4);
    cvt_bf16_kernel<<<(256 * 512 / 4 + 255) / 256, 256, 0, stream>>>(Wl2, wl2b, 256 * 512 / 4);
    cvt_bf16_kernel<<<(256 * 512 / 4 + 255) / 256, 256, 0, stream>>>(Wr2, wr2b, 256 * 512 / 4);

    const int aggBlocks = (N + 3) / 4;
    const int mBlocks = Mpad / 128;

    // Layer 0: agg-then-GEMM (aggregating 128-dim x is the cheap side).
    agg128_kernel<<<aggBlocks, 256, 0, stream>>>(xb, sorted, offs, inv, aggx, N);
    sage_gemm_mfma<<<dim3(2, mBlocks), 256, 0, stream>>>(
        aggx, xb, wl0b, wr0b, bl0, hbuf, N, 512, 128);

    // Layer 1: GEMM-then-agg: P1=h0@Wl1^T (half-split [2][Mpad][256]),
    // Q1=h0@Wr1^T+bl1 (row-major); h1 = relu(inv*sum P1[src] + Q1) in two
    // sequential half-launches (25.6 MB working set each -> higher L2 hit).
    dual_gemm_mfma<<<dim3(4, mBlocks), 256, 0, stream>>>(
        hbuf, wl1b, wr1b, bl1, Pbuf, Qbuf, N, 512, 512, 0, Mpad);
    aggfuse512h_kernel<<<aggBlocks, 256, 0, stream>>>(
        Pbuf, Qbuf, sorted, offs, inv, hbuf, N, Mpad, 0);
    aggfuse512h_kernel<<<aggBlocks, 256, 0, stream>>>(
        Pbuf, Qbuf, sorted, offs, inv, hbuf, N, Mpad, 1);

    // Layer 2: GEMM-then-agg at 256-dim (row-major P2);
    // out = inv*sum P2[src] + Q2 (fp32, no relu)
    dual_gemm_mfma<<<dim3(2, mBlocks), 256, 0, stream>>>(
        hbuf, wl2b, wr2b, bl2, Pbuf, (void*)Qf, N, 256, 512, 1, 0);
    aggfuse256_kernel<<<aggBlocks, 256, 0, stream>>>(
        Pbuf, Qf, sorted, offs, inv, out, N);
}

// Round 10
// 608.895 us; speedup vs baseline: 1.7438x; 1.0094x over previous
//
#include <hip/hip_runtime.h>
#include <hip/hip_bf16.h>
#include <cstdint>
#include <cstddef>

static inline size_t align_up(size_t x, size_t a) { return (x + a - 1) & ~(a - 1); }

typedef __attribute__((ext_vector_type(4))) float f32x4;
typedef __attribute__((ext_vector_type(4))) unsigned int u32x4;
typedef __attribute__((ext_vector_type(2))) unsigned int u32x2;
typedef __attribute__((ext_vector_type(8))) short bf16x8;

__device__ inline float bf2f(unsigned int u16) {        // low 16 bits hold bf16
    return __uint_as_float(u16 << 16);
}
__device__ inline float bflo(unsigned int v) { return __uint_as_float(v << 16); }
__device__ inline float bfhi(unsigned int v) { return __uint_as_float(v & 0xffff0000u); }
__device__ inline unsigned short f2bf(float f) {        // round-to-nearest-even
    unsigned int u = __float_as_uint(f);
    u = (u + 0x7fffu + ((u >> 16) & 1u)) >> 16;
    return (unsigned short)u;
}

// Bijective XCD-chunk swizzle (m204): blockIdx round-robins xcd = id%8; give
// each XCD a CONTIGUOUS wgid chunk so consecutive blocks on one XCD share
// operand panels in its private L2.
__device__ inline int xcd_swizzle(int id, int nwg) {
    int q = nwg >> 3, r8 = nwg & 7;
    int xcd = id & 7, pos = id >> 3;
    int base = (xcd < r8) ? xcd * (q + 1) : r8 * (q + 1) + (xcd - r8) * q;
    return base + pos;
}

#define GLD_LDS(gp, lp) \
    __builtin_amdgcn_global_load_lds( \
        (const __attribute__((address_space(1))) unsigned int*)(gp), \
        (__attribute__((address_space(3))) unsigned int*)(lp), 16, 0, 0)

// ---------------------------------------------------------------------------
__global__ void zero_kernel(int* __restrict__ p, int n) {
    int i = blockIdx.x * 256 + threadIdx.x;
    if (i < n) p[i] = 0;
}

// Edge-encoding detection, single block, sampled, no atomics.
__global__ void detect_kernel(const int* __restrict__ e, int* __restrict__ nz, int E) {
    int t = threadIdx.x;  // 0..255, one block
    long long stride = (long long)E / 4096;
    if (stride < 1) stride = 1;
    int any = 0;
    for (int k = 0; k < 16; ++k) {
        long long idx = (long long)(t * 16 + k) * stride;
        if (idx < E && e[2 * idx + 1] != 0) any = 1;
    }
    if (any) nz[0] = 1;  // same-value race is benign
}

__global__ void conv_count_kernel(const int* __restrict__ eraw, const int* __restrict__ nz,
                                  int* __restrict__ src32, int* __restrict__ dst32,
                                  int* __restrict__ cnt, int E) {
    int i = blockIdx.x * blockDim.x + threadIdx.x;
    if (i >= E) return;
    int s, d;
    if (*nz == 0) {  // int64 storage
        const long long* e64 = (const long long*)eraw;
        s = (int)e64[i];
        d = (int)e64[i + E];
    } else {         // int32 storage
        s = eraw[i];
        d = eraw[i + E];
    }
    src32[i] = s;
    dst32[i] = d;
    atomicAdd(&cnt[d], 1);
}

// 3-kernel exclusive scan over cnt[0..n) -> offs[0..n]
__global__ void scan1_kernel(const int* __restrict__ cnt, int* __restrict__ partial,
                             int n, int C) {
    int t = blockIdx.x * 256 + threadIdx.x;  // 0..1023
    int s = 0;
    int base = t * C;
    for (int i = 0; i < C; ++i) {
        int idx = base + i;
        if (idx < n) s += cnt[idx];
    }
    partial[t] = s;
}

__global__ void __launch_bounds__(1024) scan2_kernel(int* __restrict__ partial) {
    __shared__ int sh[1024];
    int t = threadIdx.x;
    sh[t] = partial[t];
    __syncthreads();
    for (int off = 1; off < 1024; off <<= 1) {
        int v = (t >= off) ? sh[t - off] : 0;
        __syncthreads();
        sh[t] += v;
        __syncthreads();
    }
    partial[t] = (t == 0) ? 0 : sh[t - 1];  // exclusive
}

__global__ void scan3_kernel(const int* __restrict__ cnt, const int* __restrict__ partial,
                             int* __restrict__ offs, int n, int C, int E) {
    int t = blockIdx.x * 256 + threadIdx.x;
    int run = partial[t];
    int base = t * C;
    for (int i = 0; i < C; ++i) {
        int idx = base + i;
        if (idx < n) {
            offs[idx] = run;
            run += cnt[idx];
        }
    }
    if (t == 0) offs[n] = E;
}

__global__ void inv_kernel(const int* __restrict__ cnt, float* __restrict__ inv, int n) {
    int i = blockIdx.x * 256 + threadIdx.x;
    if (i < n) inv[i] = 1.0f / (float)max(cnt[i], 1);
}

__global__ void fill_kernel(const int* __restrict__ src32, const int* __restrict__ dst32,
                            const int* __restrict__ offs, int* __restrict__ cursor,
                            int* __restrict__ sorted, int E) {
    int i = blockIdx.x * 256 + threadIdx.x;
    if (i >= E) return;
    int d = dst32[i];
    int p = offs[d] + atomicAdd(&cursor[d], 1);
    sorted[p] = src32[i];
}

// fp32 -> bf16, vectorized x4
__global__ void cvt_bf16_kernel(const float* __restrict__ x, unsigned short* __restrict__ xb,
                                int n4) {
    int i = blockIdx.x * 256 + threadIdx.x;
    if (i >= n4) return;
    float4 v = *(const float4*)(x + (size_t)i * 4);
    uint2 o;
    o.x = (unsigned int)f2bf(v.x) | ((unsigned int)f2bf(v.y) << 16);
    o.y = (unsigned int)f2bf(v.z) | ((unsigned int)f2bf(v.w) << 16);
    *(uint2*)(xb + (size_t)i * 4) = o;
}

// ---------------------------------------------------------------------------
// Aggregation kernels (unchanged from round-9 best).
// Regime: gathers throughput-bound on the beyond-L2 fetch path (~3.3-3.8
// TB/s); dur tracks FETCH bytes; hit rate is temporal. Layer-1 P half-split
// [2][Mpad][256], two sequential launches. Binary 4/2/1 tails; single-use
// streams (Q, out) non-temporal.
// ---------------------------------------------------------------------------
__global__ void __launch_bounds__(256) agg128_kernel(
    const unsigned short* __restrict__ X, const int* __restrict__ srt,
    const int* __restrict__ offs, const float* __restrict__ invc,
    unsigned short* __restrict__ out, int nNodes) {
    int node = blockIdx.x * 4 + (threadIdx.x >> 6);
    if (node >= nNodes) return;
    int lane = threadIdx.x & 63;
    const unsigned short* xp = X + (size_t)lane * 2;
    int beg = offs[node], end = offs[node + 1];
    float sc = invc[node];
    float a0 = 0.f, a1 = 0.f;
    int e = beg;
    for (; e + 8 <= end; e += 8) {
        unsigned int v[8];
#pragma unroll
        for (int u = 0; u < 8; ++u)
            v[u] = *(const unsigned int*)(xp + (size_t)srt[e + u] * 128);
#pragma unroll
        for (int u = 0; u < 8; ++u) {
            a0 += bflo(v[u]);
            a1 += bfhi(v[u]);
        }
    }
    int r = end - e;
    if (r & 4) {
        unsigned int v[4];
#pragma unroll
        for (int u = 0; u < 4; ++u)
            v[u] = *(const unsigned int*)(xp + (size_t)srt[e + u] * 128);
#pragma unroll
        for (int u = 0; u < 4; ++u) { a0 += bflo(v[u]); a1 += bfhi(v[u]); }
        e += 4;
    }
    if (r & 2) {
        unsigned int v[2];
#pragma unroll
        for (int u = 0; u < 2; ++u)
            v[u] = *(const unsigned int*)(xp + (size_t)srt[e + u] * 128);
#pragma unroll
        for (int u = 0; u < 2; ++u) { a0 += bflo(v[u]); a1 += bfhi(v[u]); }
        e += 2;
    }
    if (r & 1) {
        unsigned int v = *(const unsigned int*)(xp + (size_t)srt[e] * 128);
        a0 += bflo(v);
        a1 += bfhi(v);
    }
    unsigned int o = (unsigned int)f2bf(a0 * sc) | ((unsigned int)f2bf(a1 * sc) << 16);
    __builtin_nontemporal_store(o, (unsigned int*)(out + (size_t)node * 128 + lane * 2));
}

// Layer-1 fused aggregation, HALF-SPLIT: out[dst][h*256+..] =
// relu(inv*sum Ph[src] + Q[dst][h*256+..]). P: [2][Mpad][256] bf16.
__global__ void __launch_bounds__(256) aggfuse512h_kernel(
    const unsigned short* __restrict__ P, const unsigned short* __restrict__ Q,
    const int* __restrict__ srt, const int* __restrict__ offs,
    const float* __restrict__ invc, unsigned short* __restrict__ out,
    int nNodes, int Mpad, int half) {
    int node = blockIdx.x * 4 + (threadIdx.x >> 6);
    if (node >= nNodes) return;
    int lane = threadIdx.x & 63;
    const unsigned short* pp = P + (size_t)half * Mpad * 256 + lane * 4;
    int beg = offs[node], end = offs[node + 1];
    float sc = invc[node];
    float a0 = 0.f, a1 = 0.f, a2 = 0.f, a3 = 0.f;
#define ACC4(v)                              \
    do {                                     \
        a0 += bflo((v).x);                   \
        a1 += bfhi((v).x);                   \
        a2 += bflo((v).y);                   \
        a3 += bfhi((v).y);                   \
    } while (0)
    int e = beg;
    for (; e + 8 <= end; e += 8) {
        uint2 v[8];
#pragma unroll
        for (int u = 0; u < 8; ++u)
            v[u] = *(const uint2*)(pp + (size_t)srt[e + u] * 256);
#pragma unroll
        for (int u = 0; u < 8; ++u) ACC4(v[u]);
    }
    int r = end - e;
    if (r & 4) {
        uint2 v[4];
#pragma unroll
        for (int u = 0; u < 4; ++u)
            v[u] = *(const uint2*)(pp + (size_t)srt[e + u] * 256);
#pragma unroll
        for (int u = 0; u < 4; ++u) ACC4(v[u]);
        e += 4;
    }
    if (r & 2) {
        uint2 v[2];
#pragma unroll
        for (int u = 0; u < 2; ++u)
            v[u] = *(const uint2*)(pp + (size_t)srt[e + u] * 256);
#pragma unroll
        for (int u = 0; u < 2; ++u) ACC4(v[u]);
        e += 2;
    }
    if (r & 1) {
        uint2 v = *(const uint2*)(pp + (size_t)srt[e] * 256);
        ACC4(v);
    }
#undef ACC4
    size_t qo = (size_t)node * 512 + half * 256 + lane * 4;
    u32x2 q = __builtin_nontemporal_load((const u32x2*)(Q + qo));
    float r0 = fmaxf(a0 * sc + bflo(q.x), 0.f);
    float r1 = fmaxf(a1 * sc + bfhi(q.x), 0.f);
    float r2 = fmaxf(a2 * sc + bflo(q.y), 0.f);
    float r3 = fmaxf(a3 * sc + bfhi(q.y), 0.f);
    u32x2 o;
    o.x = (unsigned int)f2bf(r0) | ((unsigned int)f2bf(r1) << 16);
    o.y = (unsigned int)f2bf(r2) | ((unsigned int)f2bf(r3) << 16);
    __builtin_nontemporal_store(o, (u32x2*)(out + qo));
}

// D=256 variant, fp32 Q and fp32 out (final layer, no relu).
__global__ void __launch_bounds__(256) aggfuse256_kernel(
    const unsigned short* __restrict__ P, const float* __restrict__ Q,
    const int* __restrict__ srt, const int* __restrict__ offs,
    const float* __restrict__ invc, float* __restrict__ out, int nNodes) {
    int node = blockIdx.x * 4 + (threadIdx.x >> 6);
    if (node >= nNodes) return;
    int lane = threadIdx.x & 63;
    const unsigned short* pp = P + (size_t)lane * 4;
    int beg = offs[node], end = offs[node + 1];
    float sc = invc[node];
    float a0 = 0.f, a1 = 0.f, a2 = 0.f, a3 = 0.f;
#define ACC4(v)                              \
    do {                                     \
        a0 += bflo((v).x);                   \
        a1 += bfhi((v).x);                   \
        a2 += bflo((v).y);                   \
        a3 += bfhi((v).y);                   \
    } while (0)
    int e = beg;
    for (; e + 8 <= end; e += 8) {
        uint2 v[8];
#pragma unroll
        for (int u = 0; u < 8; ++u)
            v[u] = *(const uint2*)(pp + (size_t)srt[e + u] * 256);
#pragma unroll
        for (int u = 0; u < 8; ++u) ACC4(v[u]);
    }
    int r = end - e;
    if (r & 4) {
        uint2 v[4];
#pragma unroll
        for (int u = 0; u < 4; ++u)
            v[u] = *(const uint2*)(pp + (size_t)srt[e + u] * 256);
#pragma unroll
        for (int u = 0; u < 4; ++u) ACC4(v[u]);
        e += 4;
    }
    if (r & 2) {
        uint2 v[2];
#pragma unroll
        for (int u = 0; u < 2; ++u)
            v[u] = *(const uint2*)(pp + (size_t)srt[e + u] * 256);
#pragma unroll
        for (int u = 0; u < 2; ++u) ACC4(v[u]);
        e += 2;
    }
    if (r & 1) {
        uint2 v = *(const uint2*)(pp + (size_t)srt[e] * 256);
        ACC4(v);
    }
#undef ACC4
    f32x4 q = __builtin_nontemporal_load(
        (const f32x4*)(Q + (size_t)node * 256 + lane * 4));
    f32x4 rr;
    rr.x = a0 * sc + q.x;
    rr.y = a1 * sc + q.y;
    rr.z = a2 * sc + q.z;
    rr.w = a3 * sc + q.w;
    __builtin_nontemporal_store(rr, (f32x4*)(out + (size_t)node * 256 + lane * 4));
}

// ---------------------------------------------------------------------------
// Coalesced bf16 epilogue. permM == 0: row-major [m][N]. permM != 0: half-
// split [n>>8][permM rows][256].
// ---------------------------------------------------------------------------
__device__ __forceinline__ void epilogue_bf16(
    f32x4 (&acc)[4][8], const float* bvj, int relu, int permM,
    unsigned short* smem, int wave, int lane,
    unsigned short* Cout, int m0, int n0, int wm, int wn, int M, int N) {
    unsigned short* stg = smem + wave * 2304;  // 128 cols * 18 shorts
    const int colc = lane & 15;
    const int rgrp = (lane >> 4) * 4;
    for (int i = 0; i < 4; ++i) {
        __syncthreads();
#pragma unroll
        for (int j = 0; j < 8; ++j) {
            float v0 = acc[i][j][0] + bvj[j];
            float v1 = acc[i][j][1] + bvj[j];
            float v2 = acc[i][j][2] + bvj[j];
            float v3 = acc[i][j][3] + bvj[j];
            if (relu) {
                v0 = fmaxf(v0, 0.f); v1 = fmaxf(v1, 0.f);
                v2 = fmaxf(v2, 0.f); v3 = fmaxf(v3, 0.f);
            }
            int c = j * 16 + colc;
            *(unsigned int*)&stg[c * 18 + rgrp] =
                (unsigned int)f2bf(v0) | ((unsigned int)f2bf(v1) << 16);
            *(unsigned int*)&stg[c * 18 + rgrp + 2] =
                (unsigned int)f2bf(v2) | ((unsigned int)f2bf(v3) << 16);
        }
        __syncthreads();
#pragma unroll
        for (int p = 0; p < 2; ++p) {
            int colg = lane & 15;                  // 8-col group
            int rp = p * 4 + (lane >> 4);          // row pair 0..7
            unsigned int w[8];
#pragma unroll
            for (int t = 0; t < 8; ++t)
                w[t] = *(const unsigned int*)&stg[(colg * 8 + t) * 18 + rp * 2];
            uint4 lo, hi;
            lo.x = (w[0] & 0xffffu) | (w[1] << 16);
            lo.y = (w[2] & 0xffffu) | (w[3] << 16);
            lo.z = (w[4] & 0xffffu) | (w[5] << 16);
            lo.w = (w[6] & 0xffffu) | (w[7] << 16);
            hi.x = (w[0] >> 16) | (w[1] & 0xffff0000u);
            hi.y = (w[2] >> 16) | (w[3] & 0xffff0000u);
            hi.z = (w[4] >> 16) | (w[5] & 0xffff0000u);
            hi.w = (w[6] >> 16) | (w[7] & 0xffff0000u);
            int mlo = m0 + wm * 64 + i * 16 + rp * 2;
            int n = n0 + wn * 128 + colg * 8;
            if (permM) {
                size_t base = (size_t)(n >> 8) * ((size_t)permM * 256) +
                              (size_t)mlo * 256 + (n & 255);
                if (mlo < M)     *(uint4*)&Cout[base] = lo;
                if (mlo + 1 < M) *(uint4*)&Cout[base + 256] = hi;
            } else {
                if (mlo < M)     *(uint4*)&Cout[(size_t)mlo * N + n] = lo;
                if (mlo + 1 < M) *(uint4*)&Cout[(size_t)(mlo + 1) * N + n] = hi;
            }
        }
    }
}

// ---------------------------------------------------------------------------
// MFMA SAGE GEMM (layer 0): C = relu( Aagg @ Wl^T + Aself @ Wr^T + bias )
// Round-9 dbuf pipeline + round-10 XCD swizzle: 1D grid; bijective chunk
// remap puts blocks sharing the same A-row panel on the SAME XCD (default
// x-fastest round-robin spread them over different XCDs -> A refetched per
// XCD; dual-L1 counters showed 104 MB fetch vs 51 MB unique A).
// ---------------------------------------------------------------------------
__global__ void __launch_bounds__(256, 2) sage_gemm_mfma(
    const unsigned short* __restrict__ Aagg, const unsigned short* __restrict__ Aself,
    const unsigned short* __restrict__ Wlb, const unsigned short* __restrict__ Wrb,
    const float* __restrict__ bias, unsigned short* __restrict__ Cout,
    int M, int N, int K) {
    __shared__ __attribute__((aligned(16))) unsigned short smem[24576];  // 48 KB, 2 bufs
    const int tid = threadIdx.x;
    const int lane = tid & 63;
    const int wave = tid >> 6;
    const int wm = wave >> 1, wn = wave & 1;
    const int xB = N / 256;
    const int wgid = xcd_swizzle(blockIdx.x, gridDim.x);
    const int m0 = (wgid / xB) * 128, n0 = (wgid % xB) * 256;

    f32x4 acc[4][8];
#pragma unroll
    for (int i = 0; i < 4; ++i)
#pragma unroll
        for (int j = 0; j < 8; ++j) acc[i][j] = (f32x4){0.f, 0.f, 0.f, 0.f};

    const int srow = wave * 16 + (lane >> 2);
    const int kE = (lane & 3) * 8;
    const int frow = lane & 15;
    const int kk = (lane >> 4) * 8;

    const int kSteps = K / 32;          // per pass
    const int steps = kSteps * 2;       // two passes (agg, self)

    auto stage = [&](int buf, int t) {
        const unsigned short* A = (t >= kSteps) ? Aself : Aagg;
        const unsigned short* W = (t >= kSteps) ? Wrb : Wlb;
        int k0 = (t >= kSteps ? t - kSteps : t) * 32;
        unsigned short* As = smem + buf * 12288;
        unsigned short* Bs = As + 4096;
        GLD_LDS(A + (size_t)(m0 + 0 * 64 + srow) * K + k0 + kE, &As[0 * 2048 + wave * 512]);
        GLD_LDS(A + (size_t)(m0 + 1 * 64 + srow) * K + k0 + kE, &As[1 * 2048 + wave * 512]);
        GLD_LDS(W + (size_t)(n0 + 0 * 64 + srow) * K + k0 + kE, &Bs[0 * 2048 + wave * 512]);
        GLD_LDS(W + (size_t)(n0 + 1 * 64 + srow) * K + k0 + kE, &Bs[1 * 2048 + wave * 512]);
        GLD_LDS(W + (size_t)(n0 + 2 * 64 + srow) * K + k0 + kE, &Bs[2 * 2048 + wave * 512]);
        GLD_LDS(W + (size_t)(n0 + 3 * 64 + srow) * K + k0 + kE, &Bs[3 * 2048 + wave * 512]);
    };

    stage(0, 0);
    __syncthreads();
    int cur = 0;
    for (int t = 0; t < steps; ++t) {
        if (t + 1 < steps) stage(cur ^ 1, t + 1);
        unsigned short* As = smem + cur * 12288;
        unsigned short* Bs = As + 4096;
        bf16x8 af[4], bfr[8];
#pragma unroll
        for (int u = 0; u < 4; ++u)
            af[u] = *(const bf16x8*)&As[(wm * 64 + u * 16 + frow) * 32 + kk];
#pragma unroll
        for (int u = 0; u < 8; ++u)
            bfr[u] = *(const bf16x8*)&Bs[(wn * 128 + u * 16 + frow) * 32 + kk];
#pragma unroll
        for (int i = 0; i < 4; ++i)
#pragma unroll
            for (int j = 0; j < 8; ++j)
                acc[i][j] = __builtin_amdgcn_mfma_f32_16x16x32_bf16(
                    af[i], bfr[j], acc[i][j], 0, 0, 0);
        __syncthreads();
        cur ^= 1;
    }

    float bvj[8];
#pragma unroll
    for (int j = 0; j < 8; ++j) bvj[j] = bias[n0 + wn * 128 + j * 16 + (lane & 15)];
    epilogue_bf16(acc, bvj, 1, 0, smem, wave, lane, Cout, m0, n0, wm, wn, M, N);
}

// ---------------------------------------------------------------------------
// Dual-output MFMA GEMM (layers 1-2): P = A@Wl^T ; Q = A@Wr^T + bias.
// Round-9 dbuf pipeline + round-10 XCD swizzle (see sage comment). 1D grid
// covers (2N/256) * (Mpad/128) blocks; wgid%xB = column (first N/256 = P,
// rest = Q), wgid/xB = row-block -> consecutive wgid on one XCD share A.
// P optionally written half-split [2][permM][256] for the layer-1 gather.
// ---------------------------------------------------------------------------
__global__ void __launch_bounds__(256, 2) dual_gemm_mfma(
    const unsigned short* __restrict__ A,
    const unsigned short* __restrict__ Wlb, const unsigned short* __restrict__ Wrb,
    const float* __restrict__ bias, unsigned short* __restrict__ P,
    void* __restrict__ Q, int M, int N, int K, int q_fp32, int permM) {
    __shared__ __attribute__((aligned(16))) unsigned short smem[24576];  // 48 KB, 2 bufs
    const int tid = threadIdx.x;
    const int lane = tid & 63;
    const int wave = tid >> 6;
    const int wm = wave >> 1, wn = wave & 1;
    const int xB = 2 * N / 256;
    const int wgid = xcd_swizzle(blockIdx.x, gridDim.x);
    const int m0 = (wgid / xB) * 128;
    const int n0s = (wgid % xB) * 256;         // in [0, 2N)
    const int isQ = n0s >= N;
    const int n0 = isQ ? n0s - N : n0s;
    const unsigned short* W = isQ ? Wrb : Wlb;

    f32x4 acc[4][8];
#pragma unroll
    for (int i = 0; i < 4; ++i)
#pragma unroll
        for (int j = 0; j < 8; ++j) acc[i][j] = (f32x4){0.f, 0.f, 0.f, 0.f};

    const int srow = wave * 16 + (lane >> 2);
    const int kE = (lane & 3) * 8;
    const int frow = lane & 15;
    const int kk = (lane >> 4) * 8;

    const int steps = K / 32;

    auto stage = [&](int buf, int t) {
        int k0 = t * 32;
        unsigned short* As = smem + buf * 12288;
        unsigned short* Bs = As + 4096;
        GLD_LDS(A + (size_t)(m0 + 0 * 64 + srow) * K + k0 + kE, &As[0 * 2048 + wave * 512]);
        GLD_LDS(A + (size_t)(m0 + 1 * 64 + srow) * K + k0 + kE, &As[1 * 2048 + wave * 512]);
        GLD_LDS(W + (size_t)(n0 + 0 * 64 + srow) * K + k0 + kE, &Bs[0 * 2048 + wave * 512]);
        GLD_LDS(W + (size_t)(n0 + 1 * 64 + srow) * K + k0 + kE, &Bs[1 * 2048 + wave * 512]);
        GLD_LDS(W + (size_t)(n0 + 2 * 64 + srow) * K + k0 + kE, &Bs[2 * 2048 + wave * 512]);
        GLD_LDS(W + (size_t)(n0 + 3 * 64 + srow) * K + k0 + kE, &Bs[3 * 2048 + wave * 512]);
    };

    stage(0, 0);
    __syncthreads();
    int cur = 0;
    for (int t = 0; t < steps; ++t) {
        if (t + 1 < steps) stage(cur ^ 1, t + 1);
        unsigned short* As = smem + cur * 12288;
        unsigned short* Bs = As + 4096;
        bf16x8 af[4], bfr[8];
#pragma unroll
        for (int u = 0; u < 4; ++u)
            af[u] = *(const bf16x8*)&As[(wm * 64 + u * 16 + frow) * 32 + kk];
#pragma unroll
        for (int u = 0; u < 8; ++u)
            bfr[u] = *(const bf16x8*)&Bs[(wn * 128 + u * 16 + frow) * 32 + kk];
#pragma unroll
        for (int i = 0; i < 4; ++i)
#pragma unroll
            for (int j = 0; j < 8; ++j)
                acc[i][j] = __builtin_amdgcn_mfma_f32_16x16x32_bf16(
                    af[i], bfr[j], acc[i][j], 0, 0, 0);
        __syncthreads();
        cur ^= 1;
    }

    if (!isQ || !q_fp32) {
        float bvj[8];
#pragma unroll
        for (int j = 0; j < 8; ++j)
            bvj[j] = isQ ? bias[n0 + wn * 128 + j * 16 + (lane & 15)] : 0.f;
        unsigned short* Cout = isQ ? (unsigned short*)Q : P;
        epilogue_bf16(acc, bvj, 0, isQ ? 0 : permM, smem, wave, lane,
                      Cout, m0, n0, wm, wn, M, N);
    } else {
        // fp32 Q: scalar stores are 64 B per quarter-wave -> already coalesced
        const int col = lane & 15;
        const int rgrp = (lane >> 4) * 4;
        float* Qf = (float*)Q;
#pragma unroll
        for (int j = 0; j < 8; ++j) {
            int n = n0 + wn * 128 + j * 16 + col;
            float bv = bias[n];
#pragma unroll
            for (int i = 0; i < 4; ++i) {
                int mBase = m0 + wm * 64 + i * 16 + rgrp;
#pragma unroll
                for (int r = 0; r < 4; ++r) {
                    int m = mBase + r;
                    if (m >= M) continue;
                    Qf[(size_t)m * N + n] = acc[i][j][r] + bv;
                }
            }
        }
    }
}

// ---------------------------------------------------------------------------
extern "C" void kernel_launch(void* const* d_in, const int* in_sizes, int n_in,
                              void* d_out, int out_size, void* d_ws, size_t ws_size,
                              hipStream_t stream) {
    const float* x   = (const float*)d_in[0];
    const int*   e   = (const int*)d_in[1];
    const float* Wl0 = (const float*)d_in[2];
    const float* bl0 = (const float*)d_in[3];
    const float* Wr0 = (const float*)d_in[4];
    const float* Wl1 = (const float*)d_in[5];
    const float* bl1 = (const float*)d_in[6];
    const float* Wr1 = (const float*)d_in[7];
    const float* Wl2 = (const float*)d_in[8];
    const float* bl2 = (const float*)d_in[9];
    const float* Wr2 = (const float*)d_in[10];
    float* out = (float*)d_out;

    const int N = in_sizes[0] / 128;           // 50000 nodes
    const int E = in_sizes[1] / 2;             // 800000 edges
    const int Mpad = ((N + 127) / 128) * 128;  // 50048: GEMM staging never OOB

    char* ws = (char*)d_ws;
    size_t off = 0;
    auto alloc = [&](size_t bytes) { size_t o = off; off = align_up(off + bytes, 512); return o; };

    size_t o_nz     = alloc(4);
    size_t o_cnt    = alloc((size_t)N * 4);
    size_t o_cursor = alloc((size_t)N * 4);
    size_t zero_end = off;                       // [0, zero_end) zeroed each call
    size_t o_part   = alloc(1024 * 4);
    size_t o_offs   = alloc((size_t)(N + 1) * 4);
    size_t o_inv    = alloc((size_t)N * 4);
    size_t o_src    = alloc((size_t)E * 4);
    size_t o_dst    = alloc((size_t)E * 4);
    size_t o_sort   = alloc((size_t)E * 4);
    size_t o_xb     = alloc((size_t)Mpad * 128 * 2);   // bf16 x row-major
    size_t o_aggx   = alloc((size_t)Mpad * 128 * 2);   // bf16 agg(x)
    size_t o_h      = alloc((size_t)Mpad * 512 * 2);   // h0, then h1
    size_t o_P      = alloc((size_t)Mpad * 512 * 2);   // P1 [2][Mpad][256], then P2 (256)
    size_t o_Q      = alloc((size_t)Mpad * 512 * 2);   // Q1 bf16 (512), then Q2 fp32 (256)
    size_t o_wl0    = alloc((size_t)512 * 128 * 2);
    size_t o_wr0    = alloc((size_t)512 * 128 * 2);
    size_t o_wl1    = alloc((size_t)512 * 512 * 2);
    size_t o_wr1    = alloc((size_t)512 * 512 * 2);
    size_t o_wl2    = alloc((size_t)256 * 512 * 2);
    size_t o_wr2    = alloc((size_t)256 * 512 * 2);
    (void)ws_size; (void)n_in; (void)out_size;

    int*            nz     = (int*)(ws + o_nz);
    int*            cnt    = (int*)(ws + o_cnt);
    int*            cursor = (int*)(ws + o_cursor);
    int*            part   = (int*)(ws + o_part);
    int*            offs   = (int*)(ws + o_offs);
    float*          inv    = (float*)(ws + o_inv);
    int*            src32  = (int*)(ws + o_src);
    int*            dst32  = (int*)(ws + o_dst);
    int*            sorted = (int*)(ws + o_sort);
    unsigned short* xb     = (unsigned short*)(ws + o_xb);
    unsigned short* aggx   = (unsigned short*)(ws + o_aggx);
    unsigned short* hbuf   = (unsigned short*)(ws + o_h);
    unsigned short* Pbuf   = (unsigned short*)(ws + o_P);
    unsigned short* Qbuf   = (unsigned short*)(ws + o_Q);   // bf16 view (layer 1)
    float*          Qf     = (float*)(ws + o_Q);            // fp32 view (layer 2)
    unsigned short* wl0b   = (unsigned short*)(ws + o_wl0);
    unsigned short* wr0b   = (unsigned short*)(ws + o_wr0);
    unsigned short* wl1b   = (unsigned short*)(ws + o_wl1);
    unsigned short* wr1b   = (unsigned short*)(ws + o_wr1);
    unsigned short* wl2b   = (unsigned short*)(ws + o_wl2);
    unsigned short* wr2b   = (unsigned short*)(ws + o_wr2);

    // zero nz/cnt/cursor (ws poisoned 0xAA before every call)
    int zn = (int)(zero_end / 4);
    zero_kernel<<<(zn + 255) / 256, 256, 0, stream>>>((int*)ws, zn);

    int eb = (E + 255) / 256;
    detect_kernel<<<1, 256, 0, stream>>>(e, nz, E);
    conv_count_kernel<<<eb, 256, 0, stream>>>(e, nz, src32, dst32, cnt, E);

    const int C = (N + 1023) / 1024;
    scan1_kernel<<<4, 256, 0, stream>>>(cnt, part, N, C);
    scan2_kernel<<<1, 1024, 0, stream>>>(part);
    scan3_kernel<<<4, 256, 0, stream>>>(cnt, part, offs, N, C, E);
    inv_kernel<<<(N + 255) / 256, 256, 0, stream>>>(cnt, inv, N);
    fill_kernel<<<eb, 256, 0, stream>>>(src32, dst32, offs, cursor, sorted, E);

    // conversions to bf16
    int n4 = N * 128 / 4;
    cvt_bf16_kernel<<<(n4 + 255) / 256, 256, 0, stream>>>(x, xb, n4);
    cvt_bf16_kernel<<<(512 * 128 / 4 + 255) / 256, 256, 0, stream>>>(Wl0, wl0b, 512 * 128 / 4);
    cvt_bf16_kernel<<<(512 * 128 / 4 + 255) / 256, 256, 0, stream>>>(Wr0, wr0b, 512 * 128 / 4);
    cvt_bf16_kernel<<<(512 * 512 / 4 + 255) / 256, 256, 0, stream>>>(Wl1, wl1b, 512 * 512 / 4);
    cvt_bf16_kernel<<<(512 * 512 / 4 + 255) / 256, 256, 0, stream>>>(Wr1, wr1b, 512 * 512 / 4);
    cvt_bf16_kernel<<<(256 * 512 / 4 + 255) / 256, 256, 0, stream>>>(Wl2, wl2b, 256 * 512 / 4);
    cvt_bf16_kernel<<<(256 * 512 / 4 + 255) / 256, 256, 0, stream>>>(Wr2, wr2b, 256 * 512 / 4);

    const int aggBlocks = (N + 3) / 4;
    const int mBlocks = Mpad / 128;

    // Layer 0: agg-then-GEMM (aggregating 128-dim x is the cheap side).
    agg128_kernel<<<aggBlocks, 256, 0, stream>>>(xb, sorted, offs, inv, aggx, N);
    sage_gemm_mfma<<<2 * mBlocks, 256, 0, stream>>>(
        aggx, xb, wl0b, wr0b, bl0, hbuf, N, 512, 128);

    // Layer 1: GEMM-then-agg: P1=h0@Wl1^T (half-split [2][Mpad][256]),
    // Q1=h0@Wr1^T+bl1 (row-major); h1 = relu(inv*sum P1[src] + Q1) in two
    // sequential half-launches (25.6 MB working set each -> higher L2 hit).
    dual_gemm_mfma<<<4 * mBlocks, 256, 0, stream>>>(
        hbuf, wl1b, wr1b, bl1, Pbuf, Qbuf, N, 512, 512, 0, Mpad);
    aggfuse512h_kernel<<<aggBlocks, 256, 0, stream>>>(
        Pbuf, Qbuf, sorted, offs, inv, hbuf, N, Mpad, 0);
    aggfuse512h_kernel<<<aggBlocks, 256, 0, stream>>>(
        Pbuf, Qbuf, sorted, offs, inv, hbuf, N, Mpad, 1);

    // Layer 2: GEMM-then-agg at 256-dim (row-major P2);
    // out = inv*sum P2[src] + Q2 (fp32, no relu)
    dual_gemm_mfma<<<2 * mBlocks, 256, 0, stream>>>(
        hbuf, wl2b, wr2b, bl2, Pbuf, (void*)Qf, N, 256, 512, 1, 0);
    aggfuse256_kernel<<<aggBlocks, 256, 0, stream>>>(
        Pbuf, Qf, sorted, offs, inv, out, N);
}

// Round 11
// 606.247 us; speedup vs baseline: 1.7514x; 1.0044x over previous
//
#include <hip/hip_runtime.h>
#include <hip/hip_bf16.h>
#include <cstdint>
#include <cstddef>

static inline size_t align_up(size_t x, size_t a) { return (x + a - 1) & ~(a - 1); }

typedef __attribute__((ext_vector_type(4))) float f32x4;
typedef __attribute__((ext_vector_type(4))) unsigned int u32x4;
typedef __attribute__((ext_vector_type(2))) unsigned int u32x2;
typedef __attribute__((ext_vector_type(8))) short bf16x8;

__device__ inline float bf2f(unsigned int u16) {        // low 16 bits hold bf16
    return __uint_as_float(u16 << 16);
}
__device__ inline float bflo(unsigned int v) { return __uint_as_float(v << 16); }
__device__ inline float bfhi(unsigned int v) { return __uint_as_float(v & 0xffff0000u); }
__device__ inline unsigned short f2bf(float f) {        // round-to-nearest-even
    unsigned int u = __float_as_uint(f);
    u = (u + 0x7fffu + ((u >> 16) & 1u)) >> 16;
    return (unsigned short)u;
}

// Bijective XCD-chunk swizzle (m204): blockIdx round-robins xcd = id%8; give
// each XCD a CONTIGUOUS wgid chunk so consecutive blocks on one XCD share
// operand panels in its private L2.
__device__ inline int xcd_swizzle(int id, int nwg) {
    int q = nwg >> 3, r8 = nwg & 7;
    int xcd = id & 7, pos = id >> 3;
    int base = (xcd < r8) ? xcd * (q + 1) : r8 * (q + 1) + (xcd - r8) * q;
    return base + pos;
}

#define GLD_LDS(gp, lp) \
    __builtin_amdgcn_global_load_lds( \
        (const __attribute__((address_space(1))) unsigned int*)(gp), \
        (__attribute__((address_space(3))) unsigned int*)(lp), 16, 0, 0)

// ---------------------------------------------------------------------------
__global__ void zero_kernel(int* __restrict__ p, int n) {
    int i = blockIdx.x * 256 + threadIdx.x;
    if (i < n) p[i] = 0;
}

// Edge-encoding detection, single block, sampled, no atomics.
__global__ void detect_kernel(const int* __restrict__ e, int* __restrict__ nz, int E) {
    int t = threadIdx.x;  // 0..255, one block
    long long stride = (long long)E / 4096;
    if (stride < 1) stride = 1;
    int any = 0;
    for (int k = 0; k < 16; ++k) {
        long long idx = (long long)(t * 16 + k) * stride;
        if (idx < E && e[2 * idx + 1] != 0) any = 1;
    }
    if (any) nz[0] = 1;  // same-value race is benign
}

__global__ void conv_count_kernel(const int* __restrict__ eraw, const int* __restrict__ nz,
                                  int* __restrict__ src32, int* __restrict__ dst32,
                                  int* __restrict__ cnt, int E) {
    int i = blockIdx.x * blockDim.x + threadIdx.x;
    if (i >= E) return;
    int s, d;
    if (*nz == 0) {  // int64 storage
        const long long* e64 = (const long long*)eraw;
        s = (int)e64[i];
        d = (int)e64[i + E];
    } else {         // int32 storage
        s = eraw[i];
        d = eraw[i + E];
    }
    src32[i] = s;
    dst32[i] = d;
    atomicAdd(&cnt[d], 1);
}

// 3-kernel exclusive scan over cnt[0..n) -> offs[0..n]
__global__ void scan1_kernel(const int* __restrict__ cnt, int* __restrict__ partial,
                             int n, int C) {
    int t = blockIdx.x * 256 + threadIdx.x;  // 0..1023
    int s = 0;
    int base = t * C;
    for (int i = 0; i < C; ++i) {
        int idx = base + i;
        if (idx < n) s += cnt[idx];
    }
    partial[t] = s;
}

__global__ void __launch_bounds__(1024) scan2_kernel(int* __restrict__ partial) {
    __shared__ int sh[1024];
    int t = threadIdx.x;
    sh[t] = partial[t];
    __syncthreads();
    for (int off = 1; off < 1024; off <<= 1) {
        int v = (t >= off) ? sh[t - off] : 0;
        __syncthreads();
        sh[t] += v;
        __syncthreads();
    }
    partial[t] = (t == 0) ? 0 : sh[t - 1];  // exclusive
}

__global__ void scan3_kernel(const int* __restrict__ cnt, const int* __restrict__ partial,
                             int* __restrict__ offs, int n, int C, int E) {
    int t = blockIdx.x * 256 + threadIdx.x;
    int run = partial[t];
    int base = t * C;
    for (int i = 0; i < C; ++i) {
        int idx = base + i;
        if (idx < n) {
            offs[idx] = run;
            run += cnt[idx];
        }
    }
    if (t == 0) offs[n] = E;
}

__global__ void inv_kernel(const int* __restrict__ cnt, float* __restrict__ inv, int n) {
    int i = blockIdx.x * 256 + threadIdx.x;
    if (i < n) inv[i] = 1.0f / (float)max(cnt[i], 1);
}

__global__ void fill_kernel(const int* __restrict__ src32, const int* __restrict__ dst32,
                            const int* __restrict__ offs, int* __restrict__ cursor,
                            int* __restrict__ sorted, int E) {
    int i = blockIdx.x * 256 + threadIdx.x;
    if (i >= E) return;
    int d = dst32[i];
    int p = offs[d] + atomicAdd(&cursor[d], 1);
    sorted[p] = src32[i];
}

// fp32 -> bf16, vectorized x4
__global__ void cvt_bf16_kernel(const float* __restrict__ x, unsigned short* __restrict__ xb,
                                int n4) {
    int i = blockIdx.x * 256 + threadIdx.x;
    if (i >= n4) return;
    float4 v = *(const float4*)(x + (size_t)i * 4);
    uint2 o;
    o.x = (unsigned int)f2bf(v.x) | ((unsigned int)f2bf(v.y) << 16);
    o.y = (unsigned int)f2bf(v.z) | ((unsigned int)f2bf(v.w) << 16);
    *(uint2*)(xb + (size_t)i * 4) = o;
}

// ---------------------------------------------------------------------------
// Aggregation kernels (unchanged from round-10 best).
// Regime: gathers throughput-bound on the beyond-L2 fetch path (~3.3-3.8
// TB/s); dur tracks FETCH bytes; hit rate is temporal. Layer-1 P half-split
// [2][Mpad][256], two sequential launches. Binary 4/2/1 tails; single-use
// streams (Q, out) non-temporal.
// ---------------------------------------------------------------------------
__global__ void __launch_bounds__(256) agg128_kernel(
    const unsigned short* __restrict__ X, const int* __restrict__ srt,
    const int* __restrict__ offs, const float* __restrict__ invc,
    unsigned short* __restrict__ out, int nNodes) {
    int node = blockIdx.x * 4 + (threadIdx.x >> 6);
    if (node >= nNodes) return;
    int lane = threadIdx.x & 63;
    const unsigned short* xp = X + (size_t)lane * 2;
    int beg = offs[node], end = offs[node + 1];
    float sc = invc[node];
    float a0 = 0.f, a1 = 0.f;
    int e = beg;
    for (; e + 8 <= end; e += 8) {
        unsigned int v[8];
#pragma unroll
        for (int u = 0; u < 8; ++u)
            v[u] = *(const unsigned int*)(xp + (size_t)srt[e + u] * 128);
#pragma unroll
        for (int u = 0; u < 8; ++u) {
            a0 += bflo(v[u]);
            a1 += bfhi(v[u]);
        }
    }
    int r = end - e;
    if (r & 4) {
        unsigned int v[4];
#pragma unroll
        for (int u = 0; u < 4; ++u)
            v[u] = *(const unsigned int*)(xp + (size_t)srt[e + u] * 128);
#pragma unroll
        for (int u = 0; u < 4; ++u) { a0 += bflo(v[u]); a1 += bfhi(v[u]); }
        e += 4;
    }
    if (r & 2) {
        unsigned int v[2];
#pragma unroll
        for (int u = 0; u < 2; ++u)
            v[u] = *(const unsigned int*)(xp + (size_t)srt[e + u] * 128);
#pragma unroll
        for (int u = 0; u < 2; ++u) { a0 += bflo(v[u]); a1 += bfhi(v[u]); }
        e += 2;
    }
    if (r & 1) {
        unsigned int v = *(const unsigned int*)(xp + (size_t)srt[e] * 128);
        a0 += bflo(v);
        a1 += bfhi(v);
    }
    unsigned int o = (unsigned int)f2bf(a0 * sc) | ((unsigned int)f2bf(a1 * sc) << 16);
    __builtin_nontemporal_store(o, (unsigned int*)(out + (size_t)node * 128 + lane * 2));
}

// Layer-1 fused aggregation, HALF-SPLIT: out[dst][h*256+..] =
// relu(inv*sum Ph[src] + Q[dst][h*256+..]). P: [2][Mpad][256] bf16.
__global__ void __launch_bounds__(256) aggfuse512h_kernel(
    const unsigned short* __restrict__ P, const unsigned short* __restrict__ Q,
    const int* __restrict__ srt, const int* __restrict__ offs,
    const float* __restrict__ invc, unsigned short* __restrict__ out,
    int nNodes, int Mpad, int half) {
    int node = blockIdx.x * 4 + (threadIdx.x >> 6);
    if (node >= nNodes) return;
    int lane = threadIdx.x & 63;
    const unsigned short* pp = P + (size_t)half * Mpad * 256 + lane * 4;
    int beg = offs[node], end = offs[node + 1];
    float sc = invc[node];
    float a0 = 0.f, a1 = 0.f, a2 = 0.f, a3 = 0.f;
#define ACC4(v)                              \
    do {                                     \
        a0 += bflo((v).x);                   \
        a1 += bfhi((v).x);                   \
        a2 += bflo((v).y);                   \
        a3 += bfhi((v).y);                   \
    } while (0)
    int e = beg;
    for (; e + 8 <= end; e += 8) {
        uint2 v[8];
#pragma unroll
        for (int u = 0; u < 8; ++u)
            v[u] = *(const uint2*)(pp + (size_t)srt[e + u] * 256);
#pragma unroll
        for (int u = 0; u < 8; ++u) ACC4(v[u]);
    }
    int r = end - e;
    if (r & 4) {
        uint2 v[4];
#pragma unroll
        for (int u = 0; u < 4; ++u)
            v[u] = *(const uint2*)(pp + (size_t)srt[e + u] * 256);
#pragma unroll
        for (int u = 0; u < 4; ++u) ACC4(v[u]);
        e += 4;
    }
    if (r & 2) {
        uint2 v[2];
#pragma unroll
        for (int u = 0; u < 2; ++u)
            v[u] = *(const uint2*)(pp + (size_t)srt[e + u] * 256);
#pragma unroll
        for (int u = 0; u < 2; ++u) ACC4(v[u]);
        e += 2;
    }
    if (r & 1) {
        uint2 v = *(const uint2*)(pp + (size_t)srt[e] * 256);
        ACC4(v);
    }
#undef ACC4
    size_t qo = (size_t)node * 512 + half * 256 + lane * 4;
    u32x2 q = __builtin_nontemporal_load((const u32x2*)(Q + qo));
    float r0 = fmaxf(a0 * sc + bflo(q.x), 0.f);
    float r1 = fmaxf(a1 * sc + bfhi(q.x), 0.f);
    float r2 = fmaxf(a2 * sc + bflo(q.y), 0.f);
    float r3 = fmaxf(a3 * sc + bfhi(q.y), 0.f);
    u32x2 o;
    o.x = (unsigned int)f2bf(r0) | ((unsigned int)f2bf(r1) << 16);
    o.y = (unsigned int)f2bf(r2) | ((unsigned int)f2bf(r3) << 16);
    __builtin_nontemporal_store(o, (u32x2*)(out + qo));
}

// D=256 variant, fp32 Q and fp32 out (final layer, no relu).
__global__ void __launch_bounds__(256) aggfuse256_kernel(
    const unsigned short* __restrict__ P, const float* __restrict__ Q,
    const int* __restrict__ srt, const int* __restrict__ offs,
    const float* __restrict__ invc, float* __restrict__ out, int nNodes) {
    int node = blockIdx.x * 4 + (threadIdx.x >> 6);
    if (node >= nNodes) return;
    int lane = threadIdx.x & 63;
    const unsigned short* pp = P + (size_t)lane * 4;
    int beg = offs[node], end = offs[node + 1];
    float sc = invc[node];
    float a0 = 0.f, a1 = 0.f, a2 = 0.f, a3 = 0.f;
#define ACC4(v)                              \
    do {                                     \
        a0 += bflo((v).x);                   \
        a1 += bfhi((v).x);                   \
        a2 += bflo((v).y);                   \
        a3 += bfhi((v).y);                   \
    } while (0)
    int e = beg;
    for (; e + 8 <= end; e += 8) {
        uint2 v[8];
#pragma unroll
        for (int u = 0; u < 8; ++u)
            v[u] = *(const uint2*)(pp + (size_t)srt[e + u] * 256);
#pragma unroll
        for (int u = 0; u < 8; ++u) ACC4(v[u]);
    }
    int r = end - e;
    if (r & 4) {
        uint2 v[4];
#pragma unroll
        for (int u = 0; u < 4; ++u)
            v[u] = *(const uint2*)(pp + (size_t)srt[e + u] * 256);
#pragma unroll
        for (int u = 0; u < 4; ++u) ACC4(v[u]);
        e += 4;
    }
    if (r & 2) {
        uint2 v[2];
#pragma unroll
        for (int u = 0; u < 2; ++u)
            v[u] = *(const uint2*)(pp + (size_t)srt[e + u] * 256);
#pragma unroll
        for (int u = 0; u < 2; ++u) ACC4(v[u]);
        e += 2;
    }
    if (r & 1) {
        uint2 v = *(const uint2*)(pp + (size_t)srt[e] * 256);
        ACC4(v);
    }
#undef ACC4
    f32x4 q = __builtin_nontemporal_load(
        (const f32x4*)(Q + (size_t)node * 256 + lane * 4));
    f32x4 rr;
    rr.x = a0 * sc + q.x;
    rr.y = a1 * sc + q.y;
    rr.z = a2 * sc + q.z;
    rr.w = a3 * sc + q.w;
    __builtin_nontemporal_store(rr, (f32x4*)(out + (size_t)node * 256 + lane * 4));
}

// ---------------------------------------------------------------------------
// Coalesced bf16 epilogue. permM == 0: row-major [m][N]. permM != 0: half-
// split [n>>8][permM rows][256].
// ---------------------------------------------------------------------------
__device__ __forceinline__ void epilogue_bf16(
    f32x4 (&acc)[4][8], const float* bvj, int relu, int permM,
    unsigned short* smem, int wave, int lane,
    unsigned short* Cout, int m0, int n0, int wm, int wn, int M, int N) {
    unsigned short* stg = smem + wave * 2304;  // 128 cols * 18 shorts
    const int colc = lane & 15;
    const int rgrp = (lane >> 4) * 4;
    for (int i = 0; i < 4; ++i) {
        __syncthreads();
#pragma unroll
        for (int j = 0; j < 8; ++j) {
            float v0 = acc[i][j][0] + bvj[j];
            float v1 = acc[i][j][1] + bvj[j];
            float v2 = acc[i][j][2] + bvj[j];
            float v3 = acc[i][j][3] + bvj[j];
            if (relu) {
                v0 = fmaxf(v0, 0.f); v1 = fmaxf(v1, 0.f);
                v2 = fmaxf(v2, 0.f); v3 = fmaxf(v3, 0.f);
            }
            int c = j * 16 + colc;
            *(unsigned int*)&stg[c * 18 + rgrp] =
                (unsigned int)f2bf(v0) | ((unsigned int)f2bf(v1) << 16);
            *(unsigned int*)&stg[c * 18 + rgrp + 2] =
                (unsigned int)f2bf(v2) | ((unsigned int)f2bf(v3) << 16);
        }
        __syncthreads();
#pragma unroll
        for (int p = 0; p < 2; ++p) {
            int colg = lane & 15;                  // 8-col group
            int rp = p * 4 + (lane >> 4);          // row pair 0..7
            unsigned int w[8];
#pragma unroll
            for (int t = 0; t < 8; ++t)
                w[t] = *(const unsigned int*)&stg[(colg * 8 + t) * 18 + rp * 2];
            uint4 lo, hi;
            lo.x = (w[0] & 0xffffu) | (w[1] << 16);
            lo.y = (w[2] & 0xffffu) | (w[3] << 16);
            lo.z = (w[4] & 0xffffu) | (w[5] << 16);
            lo.w = (w[6] & 0xffffu) | (w[7] << 16);
            hi.x = (w[0] >> 16) | (w[1] & 0xffff0000u);
            hi.y = (w[2] >> 16) | (w[3] & 0xffff0000u);
            hi.z = (w[4] >> 16) | (w[5] & 0xffff0000u);
            hi.w = (w[6] >> 16) | (w[7] & 0xffff0000u);
            int mlo = m0 + wm * 64 + i * 16 + rp * 2;
            int n = n0 + wn * 128 + colg * 8;
            if (permM) {
                size_t base = (size_t)(n >> 8) * ((size_t)permM * 256) +
                              (size_t)mlo * 256 + (n & 255);
                if (mlo < M)     *(uint4*)&Cout[base] = lo;
                if (mlo + 1 < M) *(uint4*)&Cout[base + 256] = hi;
            } else {
                if (mlo < M)     *(uint4*)&Cout[(size_t)mlo * N + n] = lo;
                if (mlo + 1 < M) *(uint4*)&Cout[(size_t)(mlo + 1) * N + n] = hi;
            }
        }
    }
}

// ---------------------------------------------------------------------------
// MFMA SAGE GEMM (layer 0): C = relu( Aagg @ Wl^T + Aself @ Wr^T + bias )
// Round-9 dbuf pipeline + round-10 XCD swizzle + round-11 LDS k-chunk XOR
// swizzle (T2). The 64 B-row LDS tile made every 16-lane fragment read an
// 8-way bank conflict (bank base (row&1)*16, fixed chunk -> 2 bank-groups;
// SQ_LDS_BANK_CONFLICT 8.0M cyc/dispatch ~ 15% of time). Fix per rule #21
// (global_load_lds writes linearly): pre-swizzle the GLOBAL k-chunk on stage
// (kE) and XOR the same function on read (kk): chunk ^= (row>>1)&3. Half-wave
// then covers all 8 (row-parity x chunk) combos = b128 delivery floor.
// ---------------------------------------------------------------------------
__global__ void __launch_bounds__(256, 2) sage_gemm_mfma(
    const unsigned short* __restrict__ Aagg, const unsigned short* __restrict__ Aself,
    const unsigned short* __restrict__ Wlb, const unsigned short* __restrict__ Wrb,
    const float* __restrict__ bias, unsigned short* __restrict__ Cout,
    int M, int N, int K) {
    __shared__ __attribute__((aligned(16))) unsigned short smem[24576];  // 48 KB, 2 bufs
    const int tid = threadIdx.x;
    const int lane = tid & 63;
    const int wave = tid >> 6;
    const int wm = wave >> 1, wn = wave & 1;
    const int xB = N / 256;
    const int wgid = xcd_swizzle(blockIdx.x, gridDim.x);
    const int m0 = (wgid / xB) * 128, n0 = (wgid % xB) * 256;

    f32x4 acc[4][8];
#pragma unroll
    for (int i = 0; i < 4; ++i)
#pragma unroll
        for (int j = 0; j < 8; ++j) acc[i][j] = (f32x4){0.f, 0.f, 0.f, 0.f};

    const int srow = wave * 16 + (lane >> 2);
    // stage-side swizzle: LDS chunk (lane&3) at row (lane>>2) receives global
    // k-chunk (lane&3) ^ ((row>>1)&3) = (lane&3) ^ ((lane>>3)&3)
    const int kE = ((lane & 3) ^ ((lane >> 3) & 3)) * 8;
    const int frow = lane & 15;
    // read-side swizzle: desired global chunk (lane>>4) lives at LDS chunk
    // (lane>>4) ^ ((frow>>1)&3); ((lane>>1)&3) == ((frow>>1)&3) for frow=lane&15
    const int kk = (((lane >> 4) ^ ((lane >> 1) & 3)) & 3) * 8;

    const int kSteps = K / 32;          // per pass
    const int steps = kSteps * 2;       // two passes (agg, self)

    auto stage = [&](int buf, int t) {
        const unsigned short* A = (t >= kSteps) ? Aself : Aagg;
        const unsigned short* W = (t >= kSteps) ? Wrb : Wlb;
        int k0 = (t >= kSteps ? t - kSteps : t) * 32;
        unsigned short* As = smem + buf * 12288;
        unsigned short* Bs = As + 4096;
        GLD_LDS(A + (size_t)(m0 + 0 * 64 + srow) * K + k0 + kE, &As[0 * 2048 + wave * 512]);
        GLD_LDS(A + (size_t)(m0 + 1 * 64 + srow) * K + k0 + kE, &As[1 * 2048 + wave * 512]);
        GLD_LDS(W + (size_t)(n0 + 0 * 64 + srow) * K + k0 + kE, &Bs[0 * 2048 + wave * 512]);
        GLD_LDS(W + (size_t)(n0 + 1 * 64 + srow) * K + k0 + kE, &Bs[1 * 2048 + wave * 512]);
        GLD_LDS(W + (size_t)(n0 + 2 * 64 + srow) * K + k0 + kE, &Bs[2 * 2048 + wave * 512]);
        GLD_LDS(W + (size_t)(n0 + 3 * 64 + srow) * K + k0 + kE, &Bs[3 * 2048 + wave * 512]);
    };

    stage(0, 0);
    __syncthreads();
    int cur = 0;
    for (int t = 0; t < steps; ++t) {
        if (t + 1 < steps) stage(cur ^ 1, t + 1);
        unsigned short* As = smem + cur * 12288;
        unsigned short* Bs = As + 4096;
        bf16x8 af[4], bfr[8];
#pragma unroll
        for (int u = 0; u < 4; ++u)
            af[u] = *(const bf16x8*)&As[(wm * 64 + u * 16 + frow) * 32 + kk];
#pragma unroll
        for (int u = 0; u < 8; ++u)
            bfr[u] = *(const bf16x8*)&Bs[(wn * 128 + u * 16 + frow) * 32 + kk];
#pragma unroll
        for (int i = 0; i < 4; ++i)
#pragma unroll
            for (int j = 0; j < 8; ++j)
                acc[i][j] = __builtin_amdgcn_mfma_f32_16x16x32_bf16(
                    af[i], bfr[j], acc[i][j], 0, 0, 0);
        __syncthreads();
        cur ^= 1;
    }

    float bvj[8];
#pragma unroll
    for (int j = 0; j < 8; ++j) bvj[j] = bias[n0 + wn * 128 + j * 16 + (lane & 15)];
    epilogue_bf16(acc, bvj, 1, 0, smem, wave, lane, Cout, m0, n0, wm, wn, M, N);
}

// ---------------------------------------------------------------------------
// Dual-output MFMA GEMM (layers 1-2): P = A@Wl^T ; Q = A@Wr^T + bias.
// Round-9 dbuf + round-10 XCD swizzle + round-11 LDS k-chunk XOR swizzle
// (see sage comment). 1D grid covers (2N/256)*(Mpad/128) blocks.
// P optionally written half-split [2][permM][256] for the layer-1 gather.
// ---------------------------------------------------------------------------
__global__ void __launch_bounds__(256, 2) dual_gemm_mfma(
    const unsigned short* __restrict__ A,
    const unsigned short* __restrict__ Wlb, const unsigned short* __restrict__ Wrb,
    const float* __restrict__ bias, unsigned short* __restrict__ P,
    void* __restrict__ Q, int M, int N, int K, int q_fp32, int permM) {
    __shared__ __attribute__((aligned(16))) unsigned short smem[24576];  // 48 KB, 2 bufs
    const int tid = threadIdx.x;
    const int lane = tid & 63;
    const int wave = tid >> 6;
    const int wm = wave >> 1, wn = wave & 1;
    const int xB = 2 * N / 256;
    const int wgid = xcd_swizzle(blockIdx.x, gridDim.x);
    const int m0 = (wgid / xB) * 128;
    const int n0s = (wgid % xB) * 256;         // in [0, 2N)
    const int isQ = n0s >= N;
    const int n0 = isQ ? n0s - N : n0s;
    const unsigned short* W = isQ ? Wrb : Wlb;

    f32x4 acc[4][8];
#pragma unroll
    for (int i = 0; i < 4; ++i)
#pragma unroll
        for (int j = 0; j < 8; ++j) acc[i][j] = (f32x4){0.f, 0.f, 0.f, 0.f};

    const int srow = wave * 16 + (lane >> 2);
    const int kE = ((lane & 3) ^ ((lane >> 3) & 3)) * 8;   // stage swizzle
    const int frow = lane & 15;
    const int kk = (((lane >> 4) ^ ((lane >> 1) & 3)) & 3) * 8;  // read swizzle

    const int steps = K / 32;

    auto stage = [&](int buf, int t) {
        int k0 = t * 32;
        unsigned short* As = smem + buf * 12288;
        unsigned short* Bs = As + 4096;
        GLD_LDS(A + (size_t)(m0 + 0 * 64 + srow) * K + k0 + kE, &As[0 * 2048 + wave * 512]);
        GLD_LDS(A + (size_t)(m0 + 1 * 64 + srow) * K + k0 + kE, &As[1 * 2048 + wave * 512]);
        GLD_LDS(W + (size_t)(n0 + 0 * 64 + srow) * K + k0 + kE, &Bs[0 * 2048 + wave * 512]);
        GLD_LDS(W + (size_t)(n0 + 1 * 64 + srow) * K + k0 + kE, &Bs[1 * 2048 + wave * 512]);
        GLD_LDS(W + (size_t)(n0 + 2 * 64 + srow) * K + k0 + kE, &Bs[2 * 2048 + wave * 512]);
        GLD_LDS(W + (size_t)(n0 + 3 * 64 + srow) * K + k0 + kE, &Bs[3 * 2048 + wave * 512]);
    };

    stage(0, 0);
    __syncthreads();
    int cur = 0;
    for (int t = 0; t < steps; ++t) {
        if (t + 1 < steps) stage(cur ^ 1, t + 1);
        unsigned short* As = smem + cur * 12288;
        unsigned short* Bs = As + 4096;
        bf16x8 af[4], bfr[8];
#pragma unroll
        for (int u = 0; u < 4; ++u)
            af[u] = *(const bf16x8*)&As[(wm * 64 + u * 16 + frow) * 32 + kk];
#pragma unroll
        for (int u = 0; u < 8; ++u)
            bfr[u] = *(const bf16x8*)&Bs[(wn * 128 + u * 16 + frow) * 32 + kk];
#pragma unroll
        for (int i = 0; i < 4; ++i)
#pragma unroll
            for (int j = 0; j < 8; ++j)
                acc[i][j] = __builtin_amdgcn_mfma_f32_16x16x32_bf16(
                    af[i], bfr[j], acc[i][j], 0, 0, 0);
        __syncthreads();
        cur ^= 1;
    }

    if (!isQ || !q_fp32) {
        float bvj[8];
#pragma unroll
        for (int j = 0; j < 8; ++j)
            bvj[j] = isQ ? bias[n0 + wn * 128 + j * 16 + (lane & 15)] : 0.f;
        unsigned short* Cout = isQ ? (unsigned short*)Q : P;
        epilogue_bf16(acc, bvj, 0, isQ ? 0 : permM, smem, wave, lane,
                      Cout, m0, n0, wm, wn, M, N);
    } else {
        // fp32 Q: scalar stores are 64 B per quarter-wave -> already coalesced
        const int col = lane & 15;
        const int rgrp = (lane >> 4) * 4;
        float* Qf = (float*)Q;
#pragma unroll
        for (int j = 0; j < 8; ++j) {
            int n = n0 + wn * 128 + j * 16 + col;
            float bv = bias[n];
#pragma unroll
            for (int i = 0; i < 4; ++i) {
                int mBase = m0 + wm * 64 + i * 16 + rgrp;
#pragma unroll
                for (int r = 0; r < 4; ++r) {
                    int m = mBase + r;
                    if (m >= M) continue;
                    Qf[(size_t)m * N + n] = acc[i][j][r] + bv;
                }
            }
        }
    }
}

// ---------------------------------------------------------------------------
extern "C" void kernel_launch(void* const* d_in, const int* in_sizes, int n_in,
                              void* d_out, int out_size, void* d_ws, size_t ws_size,
                              hipStream_t stream) {
    const float* x   = (const float*)d_in[0];
    const int*   e   = (const int*)d_in[1];
    const float* Wl0 = (const float*)d_in[2];
    const float* bl0 = (const float*)d_in[3];
    const float* Wr0 = (const float*)d_in[4];
    const float* Wl1 = (const float*)d_in[5];
    const float* bl1 = (const float*)d_in[6];
    const float* Wr1 = (const float*)d_in[7];
    const float* Wl2 = (const float*)d_in[8];
    const float* bl2 = (const float*)d_in[9];
    const float* Wr2 = (const float*)d_in[10];
    float* out = (float*)d_out;

    const int N = in_sizes[0] / 128;           // 50000 nodes
    const int E = in_sizes[1] / 2;             // 800000 edges
    const int Mpad = ((N + 127) / 128) * 128;  // 50048: GEMM staging never OOB

    char* ws = (char*)d_ws;
    size_t off = 0;
    auto alloc = [&](size_t bytes) { size_t o = off; off = align_up(off + bytes, 512); return o; };

    size_t o_nz     = alloc(4);
    size_t o_cnt    = alloc((size_t)N * 4);
    size_t o_cursor = alloc((size_t)N * 4);
    size_t zero_end = off;                       // [0, zero_end) zeroed each call
    size_t o_part   = alloc(1024 * 4);
    size_t o_offs   = alloc((size_t)(N + 1) * 4);
    size_t o_inv    = alloc((size_t)N * 4);
    size_t o_src    = alloc((size_t)E * 4);
    size_t o_dst    = alloc((size_t)E * 4);
    size_t o_sort   = alloc((size_t)E * 4);
    size_t o_xb     = alloc((size_t)Mpad * 128 * 2);   // bf16 x row-major
    size_t o_aggx   = alloc((size_t)Mpad * 128 * 2);   // bf16 agg(x)
    size_t o_h      = alloc((size_t)Mpad * 512 * 2);   // h0, then h1
    size_t o_P      = alloc((size_t)Mpad * 512 * 2);   // P1 [2][Mpad][256], then P2 (256)
    size_t o_Q      = alloc((size_t)Mpad * 512 * 2);   // Q1 bf16 (512), then Q2 fp32 (256)
    size_t o_wl0    = alloc((size_t)512 * 128 * 2);
    size_t o_wr0    = alloc((size_t)512 * 128 * 2);
    size_t o_wl1    = alloc((size_t)512 * 512 * 2);
    size_t o_wr1    = alloc((size_t)512 * 512 * 2);
    size_t o_wl2    = alloc((size_t)256 * 512 * 2);
    size_t o_wr2    = alloc((size_t)256 * 512 * 2);
    (void)ws_size; (void)n_in; (void)out_size;

    int*            nz     = (int*)(ws + o_nz);
    int*            cnt    = (int*)(ws + o_cnt);
    int*            cursor = (int*)(ws + o_cursor);
    int*            part   = (int*)(ws + o_part);
    int*            offs   = (int*)(ws + o_offs);
    float*          inv    = (float*)(ws + o_inv);
    int*            src32  = (int*)(ws + o_src);
    int*            dst32  = (int*)(ws + o_dst);
    int*            sorted = (int*)(ws + o_sort);
    unsigned short* xb     = (unsigned short*)(ws + o_xb);
    unsigned short* aggx   = (unsigned short*)(ws + o_aggx);
    unsigned short* hbuf   = (unsigned short*)(ws + o_h);
    unsigned short* Pbuf   = (unsigned short*)(ws + o_P);
    unsigned short* Qbuf   = (unsigned short*)(ws + o_Q);   // bf16 view (layer 1)
    float*          Qf     = (float*)(ws + o_Q);            // fp32 view (layer 2)
    unsigned short* wl0b   = (unsigned short*)(ws + o_wl0);
    unsigned short* wr0b   = (unsigned short*)(ws + o_wr0);
    unsigned short* wl1b   = (unsigned short*)(ws + o_wl1);
    unsigned short* wr1b   = (unsigned short*)(ws + o_wr1);
    unsigned short* wl2b   = (unsigned short*)(ws + o_wl2);
    unsigned short* wr2b   = (unsigned short*)(ws + o_wr2);

    // zero nz/cnt/cursor (ws poisoned 0xAA before every call)
    int zn = (int)(zero_end / 4);
    zero_kernel<<<(zn + 255) / 256, 256, 0, stream>>>((int*)ws, zn);

    int eb = (E + 255) / 256;
    detect_kernel<<<1, 256, 0, stream>>>(e, nz, E);
    conv_count_kernel<<<eb, 256, 0, stream>>>(e, nz, src32, dst32, cnt, E);

    const int C = (N + 1023) / 1024;
    scan1_kernel<<<4, 256, 0, stream>>>(cnt, part, N, C);
    scan2_kernel<<<1, 1024, 0, stream>>>(part);
    scan3_kernel<<<4, 256, 0, stream>>>(cnt, part, offs, N, C, E);
    inv_kernel<<<(N + 255) / 256, 256, 0, stream>>>(cnt, inv, N);
    fill_kernel<<<eb, 256, 0, stream>>>(src32, dst32, offs, cursor, sorted, E);

    // conversions to bf16
    int n4 = N * 128 / 4;
    cvt_bf16_kernel<<<(n4 + 255) / 256, 256, 0, stream>>>(x, xb, n4);
    cvt_bf16_kernel<<<(512 * 128 / 4 + 255) / 256, 256, 0, stream>>>(Wl0, wl0b, 512 * 128 / 4);
    cvt_bf16_kernel<<<(512 * 128 / 4 + 255) / 256, 256, 0, stream>>>(Wr0, wr0b, 512 * 128 / 4);
    cvt_bf16_kernel<<<(512 * 512 / 4 + 255) / 256, 256, 0, stream>>>(Wl1, wl1b, 512 * 512 / 4);
    cvt_bf16_kernel<<<(512 * 512 / 4 + 255) / 256, 256, 0, stream>>>(Wr1, wr1b, 512 * 512 / 4);
    cvt_bf16_kernel<<<(256 * 512 / 4 + 255) / 256, 256, 0, stream>>>(Wl2, wl2b, 256 * 512 / 4);
    cvt_bf16_kernel<<<(256 * 512 / 4 + 255) / 256, 256, 0, stream>>>(Wr2, wr2b, 256 * 512 / 4);

    const int aggBlocks = (N + 3) / 4;
    const int mBlocks = Mpad / 128;

    // Layer 0: agg-then-GEMM (aggregating 128-dim x is the cheap side).
    agg128_kernel<<<aggBlocks, 256, 0, stream>>>(xb, sorted, offs, inv, aggx, N);
    sage_gemm_mfma<<<2 * mBlocks, 256, 0, stream>>>(
        aggx, xb, wl0b, wr0b, bl0, hbuf, N, 512, 128);

    // Layer 1: GEMM-then-agg: P1=h0@Wl1^T (half-split [2][Mpad][256]),
    // Q1=h0@Wr1^T+bl1 (row-major); h1 = relu(inv*sum P1[src] + Q1) in two
    // sequential half-launches (25.6 MB working set each -> higher L2 hit).
    dual_gemm_mfma<<<4 * mBlocks, 256, 0, stream>>>(
        hbuf, wl1b, wr1b, bl1, Pbuf, Qbuf, N, 512, 512, 0, Mpad);
    aggfuse512h_kernel<<<aggBlocks, 256, 0, stream>>>(
        Pbuf, Qbuf, sorted, offs, inv, hbuf, N, Mpad, 0);
    aggfuse512h_kernel<<<aggBlocks, 256, 0, stream>>>(
        Pbuf, Qbuf, sorted, offs, inv, hbuf, N, Mpad, 1);

    // Layer 2: GEMM-then-agg at 256-dim (row-major P2);
    // out = inv*sum P2[src] + Q2 (fp32, no relu)
    dual_gemm_mfma<<<2 * mBlocks, 256, 0, stream>>>(
        hbuf, wl2b, wr2b, bl2, Pbuf, (void*)Qf, N, 256, 512, 1, 0);
    aggfuse256_kernel<<<aggBlocks, 256, 0, stream>>>(
        Pbuf, Qf, sorted, offs, inv, out, N);
}